// Round 17
// baseline (276.378 us; speedup 1.0000x reference)
//
#include <hip/hip_runtime.h>

#define B_ 4
#define C_ 192
#define H_ 128
#define W_ 128
#define N_ (H_*W_)      // 16384
#define K_ 2048
#define HEADS_ 3
#define HD_ 64
#define HID_ 768
#define NC_ 8           // attention split-K chunks
#define KC_ (K_/NC_)    // 256

typedef __attribute__((ext_vector_type(4))) float f32x4;
typedef __attribute__((ext_vector_type(8))) short bf16x8;

__device__ __forceinline__ unsigned short f2bf(float f){
  unsigned int u = __float_as_uint(f);
  u += 0x7FFFu + ((u >> 16) & 1u);
  return (unsigned short)(u >> 16);
}
__device__ __forceinline__ float bf2f(unsigned short s){
  return __uint_as_float(((unsigned int)s) << 16);
}
__device__ __forceinline__ unsigned cvtpk(float lo, float hi){
  unsigned r;
  asm("v_cvt_pk_bf16_f32 %0, %1, %2" : "=v"(r) : "v"(lo), "v"(hi));
  return r;
}
// tanh-form GELU; t = 1 - 2/(1+e^{2y}) is overflow-safe for both signs
__device__ __forceinline__ float gelu_fast(float x){
  float y = 0.7978845608f*x*(1.f + 0.044715f*x*x);
  float e = __expf(2.f*y);
  float t = 1.f - 2.f/(1.f + e);
  return 0.5f*x*(1.f + t);
}

__device__ __forceinline__ int load_idx(const unsigned* __restrict__ ip, int pos){
  bool is64 = (ip[1]==0u) & (ip[3]==0u) & (ip[5]==0u) & (ip[7]==0u);
  int v = is64 ? (int)ip[2*pos] : (int)ip[pos];
  return min(max(v, 0), N_-1);
}

// ---------------- LN1: x (B,C,N) -> y bf16 (nb,N,C) ----------------
__global__ __launch_bounds__(256) void k_ln1(const float* __restrict__ x,
    const float* __restrict__ w, const float* __restrict__ bias,
    unsigned short* __restrict__ y, int b_off){
  int blk = blockIdx.x;
  int bl = blk >> 8;
  int b  = b_off + bl;
  int n0 = (blk & 255) * 64;
  int t  = threadIdx.x;
  int tok = t & 63, q = t >> 6;
  __shared__ float tile[64][C_+1];
  __shared__ float red[8][64];
  __shared__ float wls[C_], bls[C_];
  if (t < C_){ wls[t] = w[t]; bls[t] = bias[t]; }
  const float* xb = x + (size_t)b*C_*N_ + n0;
  float sum = 0.f, sq = 0.f;
#pragma unroll
  for (int i = 0; i < 48; ++i){
    int c = q + 4*i;
    float v = xb[(size_t)c*N_ + tok];
    tile[tok][c] = v;
    sum += v; sq += v*v;
  }
  red[q][tok] = sum; red[4+q][tok] = sq;
  __syncthreads();
  if (q == 0){
    float s  = red[0][tok]+red[1][tok]+red[2][tok]+red[3][tok];
    float s2 = red[4][tok]+red[5][tok]+red[6][tok]+red[7][tok];
    float mu = s*(1.f/C_);
    float rstd = rsqrtf(s2*(1.f/C_) - mu*mu + 1e-5f);
    red[0][tok] = mu; red[1][tok] = rstd;
  }
  __syncthreads();
  unsigned* yb = reinterpret_cast<unsigned*>(y + ((size_t)bl*N_ + n0)*C_);
#pragma unroll
  for (int i = 0; i < 24; ++i){
    int li = t + 256*i;                 // 6144 u32
    int tk = li / 96, c2 = li % 96;
    int c = 2*c2;
    float v0 = (tile[tk][c]  -red[0][tk])*red[1][tk]*wls[c]   + bls[c];
    float v1 = (tile[tk][c+1]-red[0][tk])*red[1][tk]*wls[c+1] + bls[c+1];
    yb[li] = (unsigned)f2bf(v0) | ((unsigned)f2bf(v1) << 16);
  }
}

// ---------------- QKV MFMA GEMM with gather: y bf16 -> qkv bf16 ----------------
__global__ __launch_bounds__(256) void k_qkv(const unsigned short* __restrict__ y,
    const unsigned* __restrict__ idx, const float* __restrict__ wq,
    unsigned short* __restrict__ qkv, int b_off){
  const int NT = (3*C_)/64;  // 9
  int bid = blockIdx.x;
  int bl  = bid / (16*NT);
  int rem = bid % (16*NT);
  int m0  = (rem / NT) * 128;
  int n0  = (rem % NT) * 64;
  int t = threadIdx.x, lane = t & 63;
  int wv = t >> 6, wm = wv & 1, wn = wv >> 1;
  __shared__ unsigned short Al[128][40];
  __shared__ unsigned short Bl[64][40];
  __shared__ int rows[128];
  if (t < 128) rows[t] = load_idx(idx, (b_off+bl)*K_ + m0 + t);
  __syncthreads();
  f32x4 acc[4][2] = {};
  int l15 = lane & 15, lhi = lane >> 4;
  for (int k0 = 0; k0 < C_; k0 += 32){
    {
      int m = t >> 1;
      const unsigned short* src = y + ((size_t)bl*N_ + rows[m])*C_ + k0;
#pragma unroll
      for (int i = 0; i < 4; ++i){
        int kq = (t & 1) + 2*i;
        *reinterpret_cast<ushort4*>(&Al[m][4*kq]) =
            *reinterpret_cast<const ushort4*>(src + 4*kq);
      }
      int n = t >> 2;
      const float* bsrc = wq + (size_t)(n0+n)*C_ + k0;
#pragma unroll
      for (int i = 0; i < 2; ++i){
        int q = (t & 3) + 4*i;
        float4 v = *reinterpret_cast<const float4*>(bsrc + 4*q);
        ushort4 p; p.x=f2bf(v.x); p.y=f2bf(v.y); p.z=f2bf(v.z); p.w=f2bf(v.w);
        *reinterpret_cast<ushort4*>(&Bl[n][4*q]) = p;
      }
    }
    __syncthreads();
    bf16x8 af[4], bfr[2];
#pragma unroll
    for (int mf = 0; mf < 4; ++mf)
      af[mf] = *reinterpret_cast<const bf16x8*>(&Al[wm*64 + mf*16 + l15][lhi*8]);
#pragma unroll
    for (int nf = 0; nf < 2; ++nf)
      bfr[nf] = *reinterpret_cast<const bf16x8*>(&Bl[wn*32 + nf*16 + l15][lhi*8]);
#pragma unroll
    for (int mf = 0; mf < 4; ++mf)
#pragma unroll
      for (int nf = 0; nf < 2; ++nf)
        acc[mf][nf] = __builtin_amdgcn_mfma_f32_16x16x32_bf16(af[mf], bfr[nf], acc[mf][nf], 0,0,0);
    __syncthreads();
  }
#pragma unroll
  for (int mf = 0; mf < 4; ++mf){
    int mb = m0 + wm*64 + mf*16 + lhi*4;
#pragma unroll
    for (int nf = 0; nf < 2; ++nf){
      int n = n0 + wn*32 + nf*16 + l15;
#pragma unroll
      for (int r = 0; r < 4; ++r)
        qkv[((size_t)bl*K_ + mb + r)*(3*C_) + n] = f2bf(acc[mf][nf][r]);
    }
  }
}

// ------- attention split-K (NC=8), swapped QK^T, defer-max, cvt_pk -------
__global__ __launch_bounds__(256) void k_attn(const unsigned short* __restrict__ qkv,
    float* __restrict__ po, float* __restrict__ pml, int nb){
  int bid = blockIdx.x;
  int c   = bid & (NC_-1);
  int qt  = (bid >> 3) & 31;
  int bh  = bid >> 8;
  int h = bh % HEADS_, bl = bh / HEADS_;
  int q0 = qt*64;
  int t = threadIdx.x, lane = t & 63, wv = t >> 6;
  int l15 = lane & 15, lhi = lane >> 4;
  const unsigned short* base = qkv + (size_t)bl*K_*(3*C_) + h*HD_;
  __shared__ unsigned short Ql[64][72];
  __shared__ unsigned short Kl[64][72];
  __shared__ unsigned short Vt[64][72];
  __shared__ unsigned short Pl[4][16][72];
  {
    int r = t >> 2, d0 = (t & 3) * 16;
    const uint4* src = reinterpret_cast<const uint4*>(base + (size_t)(q0+r)*(3*C_) + d0);
    *reinterpret_cast<uint4*>(&Ql[r][d0])   = src[0];
    *reinterpret_cast<uint4*>(&Ql[r][d0+8]) = src[1];
  }
  __syncthreads();
  float m_q = -1e30f, l_q = 0.f;
  f32x4 o[4] = {};
  for (int kt0 = c*KC_; kt0 < c*KC_ + KC_; kt0 += 64){
    {
      int r = t >> 2, d0 = (t & 3) * 16;
      const uint4* src = reinterpret_cast<const uint4*>(base + (size_t)(kt0+r)*(3*C_) + C_ + d0);
      *reinterpret_cast<uint4*>(&Kl[r][d0])   = src[0];
      *reinterpret_cast<uint4*>(&Kl[r][d0+8]) = src[1];
      int kp = t & 31, vd0 = (t >> 5) * 8, k = 2*kp;
      const ushort4* v0 = reinterpret_cast<const ushort4*>(base + (size_t)(kt0+k)*(3*C_)   + 2*C_ + vd0);
      const ushort4* v1 = reinterpret_cast<const ushort4*>(base + (size_t)(kt0+k+1)*(3*C_) + 2*C_ + vd0);
      ushort4 a0 = v0[0], a1 = v0[1], b0 = v1[0], b1 = v1[1];
      unsigned short va[8] = {a0.x,a0.y,a0.z,a0.w,a1.x,a1.y,a1.z,a1.w};
      unsigned short vb[8] = {b0.x,b0.y,b0.z,b0.w,b1.x,b1.y,b1.z,b1.w};
#pragma unroll
      for (int j = 0; j < 8; ++j){
        unsigned u = (unsigned)va[j] | ((unsigned)vb[j] << 16);
        *reinterpret_cast<unsigned*>(&Vt[vd0+j][k]) = u;
      }
    }
    __syncthreads();
    f32x4 s[4] = {};
    __builtin_amdgcn_s_setprio(1);
#pragma unroll
    for (int kt = 0; kt < 2; ++kt){
      bf16x8 qf = *reinterpret_cast<const bf16x8*>(&Ql[wv*16 + l15][kt*32 + lhi*8]);
#pragma unroll
      for (int nt = 0; nt < 4; ++nt){
        bf16x8 kf = *reinterpret_cast<const bf16x8*>(&Kl[nt*16 + l15][kt*32 + lhi*8]);
        s[nt] = __builtin_amdgcn_mfma_f32_16x16x32_bf16(kf, qf, s[nt], 0,0,0);
      }
    }
    __builtin_amdgcn_s_setprio(0);
    float mx = s[0][0];
#pragma unroll
    for (int nt = 0; nt < 4; ++nt)
#pragma unroll
      for (int reg = 0; reg < 4; ++reg) mx = fmaxf(mx, s[nt][reg]);
    mx = fmaxf(mx, __shfl_xor(mx, 16));
    mx = fmaxf(mx, __shfl_xor(mx, 32));
    mx *= 0.125f;
    bool skip = __all(mx <= m_q + 8.f);
    if (!skip){
      float mn = fmaxf(m_q, mx);
      float corr = __expf(m_q - mn);
      l_q *= corr;
      float cr[4];
#pragma unroll
      for (int reg = 0; reg < 4; ++reg) cr[reg] = __shfl(corr, lhi*4 + reg);
#pragma unroll
      for (int nt = 0; nt < 4; ++nt)
#pragma unroll
        for (int reg = 0; reg < 4; ++reg) o[nt][reg] *= cr[reg];
      m_q = mn;
    }
    float ls = 0.f;
#pragma unroll
    for (int nt = 0; nt < 4; ++nt){
      float p0 = __expf(fmaf(s[nt][0], 0.125f, -m_q));
      float p1 = __expf(fmaf(s[nt][1], 0.125f, -m_q));
      float p2 = __expf(fmaf(s[nt][2], 0.125f, -m_q));
      float p3 = __expf(fmaf(s[nt][3], 0.125f, -m_q));
      ls += (p0 + p1) + (p2 + p3);
      uint2 uu;
      uu.x = cvtpk(p0, p1);
      uu.y = cvtpk(p2, p3);
      *reinterpret_cast<uint2*>(&Pl[wv][l15][nt*16 + lhi*4]) = uu;
    }
    ls += __shfl_xor(ls, 16);
    ls += __shfl_xor(ls, 32);
    l_q += ls;
    __threadfence_block();
    __builtin_amdgcn_s_setprio(1);
#pragma unroll
    for (int kt = 0; kt < 2; ++kt){
      bf16x8 pa = *reinterpret_cast<const bf16x8*>(&Pl[wv][l15][kt*32 + lhi*8]);
#pragma unroll
      for (int nt = 0; nt < 4; ++nt){
        bf16x8 vb = *reinterpret_cast<const bf16x8*>(&Vt[nt*16 + l15][kt*32 + lhi*8]);
        o[nt] = __builtin_amdgcn_mfma_f32_16x16x32_bf16(pa, vb, o[nt], 0,0,0);
      }
    }
    __builtin_amdgcn_s_setprio(0);
    __syncthreads();
  }
  int R = nb*HEADS_*K_;
  int rowb = (bl*HEADS_ + h)*K_;
#pragma unroll
  for (int reg = 0; reg < 4; ++reg){
    int rq = rowb + q0 + wv*16 + lhi*4 + reg;
#pragma unroll
    for (int nt = 0; nt < 4; ++nt)
      po[((size_t)c*R + rq)*HD_ + nt*16 + l15] = o[nt][reg];
  }
  if (lhi == 0){
    int rq = rowb + q0 + wv*16 + l15;
    *reinterpret_cast<float2*>(pml + 2*((size_t)c*R + rq)) = make_float2(m_q, l_q);
  }
}

// ---------------- merge split-K partials -> ao bf16 (bl,K,C) ----------------
__global__ __launch_bounds__(256) void k_amerge(const float* __restrict__ po,
    const float* __restrict__ pml, unsigned short* __restrict__ ao, int nb){
  int R = nb*HEADS_*K_;
  int row = blockIdx.x*4 + (threadIdx.x >> 6);
  int lane = threadIdx.x & 63;
  float m[NC_], l[NC_];
#pragma unroll
  for (int cc = 0; cc < NC_; ++cc){
    float2 v = *reinterpret_cast<const float2*>(pml + 2*((size_t)cc*R + row));
    m[cc] = v.x; l[cc] = v.y;
  }
  float M = m[0];
#pragma unroll
  for (int cc = 1; cc < NC_; ++cc) M = fmaxf(M, m[cc]);
  float L = 0.f, o = 0.f;
#pragma unroll
  for (int cc = 0; cc < NC_; ++cc){
    float e = __expf(m[cc] - M);
    L += l[cc]*e;
    o += e * po[((size_t)cc*R + row)*HD_ + lane];
  }
  o /= L;
  int q = row & (K_-1);
  int bh = row >> 11;
  int h = bh % HEADS_, bl = bh / HEADS_;
  ao[((size_t)bl*K_ + q)*C_ + h*HD_ + lane] = f2bf(o);
}

// ---------------- proj MFMA GEMM + scatter into y (bf16) ----------------
__global__ __launch_bounds__(256) void k_proj(const unsigned short* __restrict__ ain,
    const unsigned* __restrict__ idx, const float* __restrict__ pw,
    const float* __restrict__ pb, unsigned short* __restrict__ y, int b_off){
  const int NT = C_/64;   // 3
  int bid = blockIdx.x;
  int bl  = bid / (16*NT);
  int rem = bid % (16*NT);
  int m0  = (rem / NT) * 128;
  int n0  = (rem % NT) * 64;
  int t = threadIdx.x, lane = t & 63;
  int wv = t >> 6, wm = wv & 1, wn = wv >> 1;
  __shared__ unsigned short Al[128][40];
  __shared__ unsigned short Bl[64][40];
  __shared__ int rows[128];
  if (t < 128) rows[t] = load_idx(idx, (b_off+bl)*K_ + m0 + t);
  __syncthreads();
  f32x4 acc[4][2] = {};
  int l15 = lane & 15, lhi = lane >> 4;
  for (int k0 = 0; k0 < C_; k0 += 32){
    {
      int m = t >> 1;
      const unsigned short* src = ain + ((size_t)bl*K_ + m0 + m)*C_ + k0;
#pragma unroll
      for (int i = 0; i < 4; ++i){
        int kq = (t & 1) + 2*i;
        *reinterpret_cast<ushort4*>(&Al[m][4*kq]) =
            *reinterpret_cast<const ushort4*>(src + 4*kq);
      }
      int n = t >> 2;
      const float* bsrc = pw + (size_t)(n0+n)*C_ + k0;
#pragma unroll
      for (int i = 0; i < 2; ++i){
        int q = (t & 3) + 4*i;
        float4 v = *reinterpret_cast<const float4*>(bsrc + 4*q);
        ushort4 p; p.x=f2bf(v.x); p.y=f2bf(v.y); p.z=f2bf(v.z); p.w=f2bf(v.w);
        *reinterpret_cast<ushort4*>(&Bl[n][4*q]) = p;
      }
    }
    __syncthreads();
    bf16x8 af[4], bfr[2];
#pragma unroll
    for (int mf = 0; mf < 4; ++mf)
      af[mf] = *reinterpret_cast<const bf16x8*>(&Al[wm*64 + mf*16 + l15][lhi*8]);
#pragma unroll
    for (int nf = 0; nf < 2; ++nf)
      bfr[nf] = *reinterpret_cast<const bf16x8*>(&Bl[wn*32 + nf*16 + l15][lhi*8]);
#pragma unroll
    for (int mf = 0; mf < 4; ++mf)
#pragma unroll
      for (int nf = 0; nf < 2; ++nf)
        acc[mf][nf] = __builtin_amdgcn_mfma_f32_16x16x32_bf16(af[mf], bfr[nf], acc[mf][nf], 0,0,0);
    __syncthreads();
  }
#pragma unroll
  for (int mf = 0; mf < 4; ++mf){
    int mb = wm*64 + mf*16 + lhi*4;
#pragma unroll
    for (int nf = 0; nf < 2; ++nf){
      int n = n0 + wn*32 + nf*16 + l15;
      float bv = pb[n];
#pragma unroll
      for (int r = 0; r < 4; ++r)
        y[((size_t)bl*N_ + rows[mb + r])*C_ + n] = f2bf(acc[mf][nf][r] + bv);
    }
  }
}

// ---------------- residual + LN2 -> ln2t (B,C,N) [== d_out] ----------------
__global__ __launch_bounds__(256) void k_ln2(const float* __restrict__ x,
    const unsigned short* __restrict__ y, const float* __restrict__ w,
    const float* __restrict__ bias, float* __restrict__ ln2t, int b_off){
  int blk = blockIdx.x;
  int bl = blk >> 8;
  int b  = b_off + bl;
  int n0 = (blk & 255) * 64;
  int t  = threadIdx.x;
  int tok = t & 63, q = t >> 6;
  __shared__ float tile[64][C_+1];
  __shared__ float red[8][64];
  __shared__ float wls[C_], bls[C_];
  if (t < C_){ wls[t] = w[t]; bls[t] = bias[t]; }
  const unsigned* yb = reinterpret_cast<const unsigned*>(y + ((size_t)bl*N_ + n0)*C_);
#pragma unroll
  for (int i = 0; i < 24; ++i){
    int li = t + 256*i;
    unsigned u = yb[li];
    int tk = li / 96, c2 = li % 96;
    tile[tk][2*c2]   = bf2f((unsigned short)(u & 0xffffu));
    tile[tk][2*c2+1] = bf2f((unsigned short)(u >> 16));
  }
  __syncthreads();
  const float* xb = x + (size_t)b*C_*N_ + n0;
  float sum = 0.f, sq = 0.f;
#pragma unroll
  for (int i = 0; i < 48; ++i){
    int c = q + 4*i;
    float v = xb[(size_t)c*N_ + tok] + tile[tok][c];
    tile[tok][c] = v;
    sum += v; sq += v*v;
  }
  red[q][tok] = sum; red[4+q][tok] = sq;
  __syncthreads();
  if (q == 0){
    float s  = red[0][tok]+red[1][tok]+red[2][tok]+red[3][tok];
    float s2 = red[4][tok]+red[5][tok]+red[6][tok]+red[7][tok];
    float mu = s*(1.f/C_);
    float rstd = rsqrtf(s2*(1.f/C_) - mu*mu + 1e-5f);
    red[0][tok] = mu; red[1][tok] = rstd;
  }
  __syncthreads();
  float* ob = ln2t + (size_t)b*C_*N_ + n0;
  float mu = red[0][tok], rstd = red[1][tok];
#pragma unroll
  for (int i = 0; i < 48; ++i){
    int c = q + 4*i;
    ob[(size_t)c*N_ + tok] = (tile[tok][c]-mu)*rstd*wls[c] + bls[c];
  }
}

// ------- fc1 MFMA: block = 128-token m-tile x 384-hid half, loop 6 n-tiles -------
__global__ __launch_bounds__(256) void k_fc1(const float* __restrict__ ln2t,
    const float* __restrict__ wgt, const float* __restrict__ bias,
    unsigned short* __restrict__ h1, int b_off){
  int bid = blockIdx.x;
  int bl  = bid >> 8;                  // slot-local batch
  int rem = bid & 255;
  int m0  = (rem >> 1) * 128;
  int nh  = (rem & 1) * 6;             // n-tile half
  int t = threadIdx.x, lane = t & 63;
  int wv = t >> 6, wm = wv & 1, wn = wv >> 1;
  int l15 = lane & 15, lhi = lane >> 4;
  __shared__ unsigned short Al[128][200];
  __shared__ unsigned short Bl[64][200];
  const float* a = ln2t + (size_t)(b_off+bl)*C_*N_ + m0;
  unsigned short* hb = h1 + (size_t)bl*HID_*N_;
  {
    int m = t & 127, half = t >> 7;
#pragma unroll
    for (int i = 0; i < 48; ++i){
      int p = half + 2*i;                    // 0..95
      float v0 = a[(size_t)(2*p)*N_ + m];
      float v1 = a[(size_t)(2*p+1)*N_ + m];
      unsigned u = (unsigned)f2bf(v0) | ((unsigned)f2bf(v1) << 16);
      *reinterpret_cast<unsigned*>(&Al[m][2*p]) = u;
    }
  }
  for (int nt = 0; nt < 6; ++nt){
    int n0 = (nh + nt)*64;
    __syncthreads();
    {
      int n = t >> 2;
      const float* bsrc = wgt + (size_t)(n0+n)*C_;
#pragma unroll
      for (int i = 0; i < 12; ++i){
        int q = (t & 3) + 4*i;               // 0..47 float4 segs
        float4 v = *reinterpret_cast<const float4*>(bsrc + 4*q);
        ushort4 p; p.x=f2bf(v.x); p.y=f2bf(v.y); p.z=f2bf(v.z); p.w=f2bf(v.w);
        *reinterpret_cast<ushort4*>(&Bl[n][4*q]) = p;
      }
    }
    __syncthreads();
    f32x4 acc[4][2] = {};
#pragma unroll
    for (int ks = 0; ks < 6; ++ks){
      bf16x8 af[4], bfr[2];
#pragma unroll
      for (int mf = 0; mf < 4; ++mf)
        af[mf] = *reinterpret_cast<const bf16x8*>(&Al[wm*64 + mf*16 + l15][ks*32 + lhi*8]);
#pragma unroll
      for (int nf = 0; nf < 2; ++nf)
        bfr[nf] = *reinterpret_cast<const bf16x8*>(&Bl[wn*32 + nf*16 + l15][ks*32 + lhi*8]);
#pragma unroll
      for (int mf = 0; mf < 4; ++mf)
#pragma unroll
        for (int nf = 0; nf < 2; ++nf)
          acc[mf][nf] = __builtin_amdgcn_mfma_f32_16x16x32_bf16(af[mf], bfr[nf], acc[mf][nf], 0,0,0);
    }
#pragma unroll
    for (int mf = 0; mf < 4; ++mf){
      int mb = m0 + wm*64 + mf*16 + lhi*4;
#pragma unroll
      for (int nf = 0; nf < 2; ++nf){
        int n = n0 + wn*32 + nf*16 + l15;
        float bv = bias[n];
        ushort4 pk;
        pk.x = f2bf(acc[mf][nf][0] + bv);
        pk.y = f2bf(acc[mf][nf][1] + bv);
        pk.z = f2bf(acc[mf][nf][2] + bv);
        pk.w = f2bf(acc[mf][nf][3] + bv);
        *reinterpret_cast<ushort4*>(&hb[(size_t)n*N_ + mb]) = pk;
      }
    }
  }
}

// ------- fused depthwise3x3+GELU+fc2+residual: block = 64-token half-row x 192 ch -------
// 512 thr, 37.4KB LDS -> 4 blocks/CU; grid nb*256 = 1024; single Ht buffer,
// 2 barriers/chunk, reg-prefetched h1, u32-aligned conv reads
__global__ __launch_bounds__(512) void k_fc2f(const unsigned short* __restrict__ h1,
    const float* __restrict__ dw, const float* __restrict__ wgt,
    const float* __restrict__ bias, float* __restrict__ out, int b_off){
  int nwg = gridDim.x;
  int cpx = nwg >> 3;
  int bid = (blockIdx.x & 7)*cpx + (blockIdx.x >> 3);  // contiguous work per XCD
  int bl  = bid >> 8;            // slot-local batch
  int rem = bid & 255;
  int r   = rem >> 1;            // image row
  int c0  = (rem & 1) * 64;      // half-row col base
  int b   = b_off + bl;
  int t = threadIdx.x, lane = t & 63, wv = t >> 6;
  int wm = wv & 1, wn = wv >> 1;   // 32-token half, 48-ch quarter
  int l15 = lane & 15, lhi = lane >> 4;
  __shared__ unsigned short Ht[32][3][88];      // 16.5KB; cols 0..79 = image c0-8..c0+71
  __shared__ unsigned short Alc[64][40];        // 5.1KB
  __shared__ unsigned short Bl[192][40];        // 15.4KB
  const unsigned short* h1b = h1 + (size_t)bl*HID_*N_;
  f32x4 acc[2][3] = {};
  int cch = t & 31, grp = t >> 5;               // conv: channel, 4-col group (0..15)
  // ---- hoisted per-thread staging state (960 uint4 slots over 512 thr) ----
  const unsigned short* gp[2]; unsigned short* lp[2]; bool gok[2];
#pragma unroll
  for (int i = 0; i < 2; ++i){
    int li = t + 512*i;
    bool act = (li < 960);
    int ch = act ? li/30 : 0, rm = act ? li%30 : 0;
    int dy = rm/10, s = rm%10;
    int rr = r - 1 + dy;
    int colst = c0 - 8 + 8*s;
    gok[i] = act && (rr >= 0) && (rr < H_) && (colst >= 0) && (colst < W_);
    gp[i] = h1b + (size_t)ch*N_ + (gok[i] ? (rr*W_ + colst) : 0);
    lp[i] = act ? &Ht[ch][dy][8*s] : 0;
  }
  const float* wgp[3]; unsigned short* blp[3];
#pragma unroll
  for (int i = 0; i < 3; ++i){
    int row = (t >> 3) + 64*i, seg = t & 7;
    wgp[i] = wgt + (size_t)row*HID_ + seg*4;
    blp[i] = &Bl[row][seg*4];
  }
  const float* dwp = dw + (size_t)cch*9;        // +288 per chunk
  uint4 hr[2];
  auto hload = [&](){
#pragma unroll
    for (int i = 0; i < 2; ++i)
      hr[i] = gok[i] ? *reinterpret_cast<const uint4*>(gp[i]) : make_uint4(0u,0u,0u,0u);
#pragma unroll
    for (int i = 0; i < 2; ++i) gp[i] += 32*N_;
  };
  auto hwrite = [&](){
#pragma unroll
    for (int i = 0; i < 2; ++i)
      if (lp[i]) *reinterpret_cast<uint4*>(lp[i]) = hr[i];
  };
  // prologue: chunk 0 into Ht, prefetch chunk 1 into regs
  hload(); hwrite(); hload();
  for (int c24 = 0; c24 < 24; ++c24){
    __syncthreads();                  // A: Ht(c) visible; prev MFMA done
    // stage Bl direct from global (L2-hot weights)
#pragma unroll
    for (int i = 0; i < 3; ++i){
      float4 v = *reinterpret_cast<const float4*>(wgp[i]);
      wgp[i] += 32;
      ushort4 p; p.x=f2bf(v.x); p.y=f2bf(v.y); p.z=f2bf(v.z); p.w=f2bf(v.w);
      *reinterpret_cast<ushort4*>(blp[i]) = p;
    }
    // conv 3x3 + fast GELU: thread = 1 ch x 4 cols; u32-aligned LDS reads
    {
      float w9[9];
#pragma unroll
      for (int i = 0; i < 9; ++i) w9[i] = dwp[i];
      dwp += 288;
      // output local cols grp*4..grp*4+3 (image c0+grp*4+..), staged cols 8+grp*4+{-1..4}
      // read staged u32s at index 3+2*grp .. 6+2*grp (cols 6+4g..13+4g)
      const unsigned* hpu = reinterpret_cast<const unsigned*>(&Ht[cch][0][0]) + 3 + 2*grp;
      float s4[4] = {0.f,0.f,0.f,0.f};
#pragma unroll
      for (int dy = 0; dy < 3; ++dy){
        unsigned u0 = hpu[dy*44], u1 = hpu[dy*44+1], u2 = hpu[dy*44+2], u3 = hpu[dy*44+3];
        float v[8];
        v[0] = bf2f((unsigned short)(u0 & 0xffffu)); v[1] = bf2f((unsigned short)(u0 >> 16));
        v[2] = bf2f((unsigned short)(u1 & 0xffffu)); v[3] = bf2f((unsigned short)(u1 >> 16));
        v[4] = bf2f((unsigned short)(u2 & 0xffffu)); v[5] = bf2f((unsigned short)(u2 >> 16));
        v[6] = bf2f((unsigned short)(u3 & 0xffffu)); v[7] = bf2f((unsigned short)(u3 >> 16));
        // staged col 6+4g+k = v[k]; output col j needs staged 7+4g+j..9+4g+j = v[1+j..3+j]
        float wa = w9[3*dy], wb = w9[3*dy+1], wc = w9[3*dy+2];
#pragma unroll
        for (int j = 0; j < 4; ++j)
          s4[j] += v[1+j]*wa + v[2+j]*wb + v[3+j]*wc;
      }
#pragma unroll
      for (int j = 0; j < 4; ++j)
        Alc[grp*4 + j][cch] = f2bf(gelu_fast(s4[j]));
    }
    __syncthreads();                  // B: Alc+Bl visible; Ht reads complete
    // write prefetched chunk c+1 into Ht (dead now); prefetch c+2
    if (c24 < 23){
      hwrite();
      if (c24 < 22) hload();
    }
    // MFMA: wave = 32-tok half (wm) x 48-ch quarter (wn)
    bf16x8 af[2], bfr[3];
#pragma unroll
    for (int mf = 0; mf < 2; ++mf)
      af[mf] = *reinterpret_cast<const bf16x8*>(&Alc[wm*32 + mf*16 + l15][lhi*8]);
#pragma unroll
    for (int nf = 0; nf < 3; ++nf)
      bfr[nf] = *reinterpret_cast<const bf16x8*>(&Bl[wn*48 + nf*16 + l15][lhi*8]);
    __builtin_amdgcn_s_setprio(1);
#pragma unroll
    for (int mf = 0; mf < 2; ++mf)
#pragma unroll
      for (int nf = 0; nf < 3; ++nf)
        acc[mf][nf] = __builtin_amdgcn_mfma_f32_16x16x32_bf16(af[mf], bfr[nf], acc[mf][nf], 0,0,0);
    __builtin_amdgcn_s_setprio(0);
  }
  // epilogue: += bias + residual (out holds ln2t)
#pragma unroll
  for (int mf = 0; mf < 2; ++mf){
    int tok = r*W_ + c0 + wm*32 + mf*16 + lhi*4;
#pragma unroll
    for (int nf = 0; nf < 3; ++nf){
      int oc = wn*48 + nf*16 + l15;
      float bv = bias[oc];
      size_t off = ((size_t)b*C_ + oc)*N_ + tok;
      float4 rr = *reinterpret_cast<const float4*>(out + off);
      float4 v = make_float4(rr.x + acc[mf][nf][0] + bv, rr.y + acc[mf][nf][1] + bv,
                             rr.z + acc[mf][nf][2] + bv, rr.w + acc[mf][nf][3] + bv);
      *reinterpret_cast<float4*>(out + off) = v;
    }
  }
}

extern "C" void kernel_launch(void* const* d_in, const int* in_sizes, int n_in,
                              void* d_out, int out_size, void* d_ws, size_t ws_size,
                              hipStream_t stream) {
  const float*    x      = (const float*)d_in[0];
  const unsigned* idx    = (const unsigned*)d_in[1];
  const float*    ln1_w  = (const float*)d_in[2];
  const float*    ln1_b  = (const float*)d_in[3];
  const float*    qkv_w  = (const float*)d_in[4];
  const float*    proj_w = (const float*)d_in[5];
  const float*    proj_b = (const float*)d_in[6];
  const float*    ln2_w  = (const float*)d_in[7];
  const float*    ln2_b  = (const float*)d_in[8];
  const float*    fc1_w  = (const float*)d_in[9];
  const float*    fc1_b  = (const float*)d_in[10];
  const float*    dw_w   = (const float*)d_in[11];
  const float*    fc2_w  = (const float*)d_in[12];
  const float*    fc2_b  = (const float*)d_in[13];
  float* out = (float*)d_out;          // doubles as ln2t (B,C,N) f32

  const size_t SZY = (size_t)N_*C_*2;              // y bf16: 6.29 MB/batch
  const size_t SZQ = (size_t)K_*3*C_*2;            // 2.36
  const size_t SZA = (size_t)K_*C_*2;              // 0.79
  const size_t SZO = (size_t)NC_*HEADS_*K_*HD_*4;  // 12.58/batch
  const size_t SZH = (size_t)HID_*N_*2;            // 25.17/batch
  int nb = (ws_size >= (size_t)B_*SZH) ? B_ : 1;   // deterministic

  char* ws = (char*)d_ws;
  unsigned short* y16  = (unsigned short*)ws;
  unsigned short* qkvb = (unsigned short*)(ws + (size_t)nb*SZY);
  unsigned short* aob  = (unsigned short*)(ws + (size_t)nb*(SZY+SZQ));
  float*          po   = (float*)(ws + (size_t)nb*(SZY+SZQ+SZA));
  float*          pml  = (float*)(ws + (size_t)nb*(SZY+SZQ+SZA+SZO));
  unsigned short* h1s  = (unsigned short*)ws;      // MLP phase (front dead): nb slots

  for (int b0 = 0; b0 < B_; b0 += nb){
    k_ln1   <<<nb*256,             256, 0, stream>>>(x, ln1_w, ln1_b, y16, b0);
    k_qkv   <<<nb*16*9,            256, 0, stream>>>(y16, idx, qkv_w, qkvb, b0);
    k_attn  <<<nb*HEADS_*32*NC_,   256, 0, stream>>>(qkvb, po, pml, nb);
    k_amerge<<<nb*HEADS_*K_/4,     256, 0, stream>>>(po, pml, aob, nb);
    k_proj  <<<nb*16*3,            256, 0, stream>>>(aob, idx, proj_w, proj_b, y16, b0);
    k_ln2   <<<nb*256,             256, 0, stream>>>(x, y16, ln2_w, ln2_b, out, b0);
    k_fc1   <<<nb*256,             256, 0, stream>>>(out, fc1_w, fc1_b, h1s, b0);
    k_fc2f  <<<nb*256,             512, 0, stream>>>(h1s, dw_w, fc2_w, fc2_b, out, b0);
  }
}

// Round 18
// 258.926 us; speedup vs baseline: 1.0674x; 1.0674x over previous
//
#include <hip/hip_runtime.h>

#define B_ 4
#define C_ 192
#define H_ 128
#define W_ 128
#define N_ (H_*W_)      // 16384
#define K_ 2048
#define HEADS_ 3
#define HD_ 64
#define HID_ 768
#define NC_ 8           // attention split-K chunks
#define KC_ (K_/NC_)    // 256

typedef __attribute__((ext_vector_type(4))) float f32x4;
typedef __attribute__((ext_vector_type(8))) short bf16x8;

__device__ __forceinline__ unsigned short f2bf(float f){
  unsigned int u = __float_as_uint(f);
  u += 0x7FFFu + ((u >> 16) & 1u);
  return (unsigned short)(u >> 16);
}
__device__ __forceinline__ float bf2f(unsigned short s){
  return __uint_as_float(((unsigned int)s) << 16);
}
__device__ __forceinline__ unsigned cvtpk(float lo, float hi){
  unsigned r;
  asm("v_cvt_pk_bf16_f32 %0, %1, %2" : "=v"(r) : "v"(lo), "v"(hi));
  return r;
}
// tanh-form GELU; t = 1 - 2/(1+e^{2y}) is overflow-safe for both signs
__device__ __forceinline__ float gelu_fast(float x){
  float y = 0.7978845608f*x*(1.f + 0.044715f*x*x);
  float e = __expf(2.f*y);
  float t = 1.f - 2.f/(1.f + e);
  return 0.5f*x*(1.f + t);
}

__device__ __forceinline__ int load_idx(const unsigned* __restrict__ ip, int pos){
  bool is64 = (ip[1]==0u) & (ip[3]==0u) & (ip[5]==0u) & (ip[7]==0u);
  int v = is64 ? (int)ip[2*pos] : (int)ip[pos];
  return min(max(v, 0), N_-1);
}

// ---------------- LN1: x (B,C,N) -> y bf16 (nb,N,C) ----------------
__global__ __launch_bounds__(256) void k_ln1(const float* __restrict__ x,
    const float* __restrict__ w, const float* __restrict__ bias,
    unsigned short* __restrict__ y, int b_off){
  int blk = blockIdx.x;
  int bl = blk >> 8;
  int b  = b_off + bl;
  int n0 = (blk & 255) * 64;
  int t  = threadIdx.x;
  int tok = t & 63, q = t >> 6;
  __shared__ float tile[64][C_+1];
  __shared__ float red[8][64];
  __shared__ float wls[C_], bls[C_];
  if (t < C_){ wls[t] = w[t]; bls[t] = bias[t]; }
  const float* xb = x + (size_t)b*C_*N_ + n0;
  float sum = 0.f, sq = 0.f;
#pragma unroll
  for (int i = 0; i < 48; ++i){
    int c = q + 4*i;
    float v = xb[(size_t)c*N_ + tok];
    tile[tok][c] = v;
    sum += v; sq += v*v;
  }
  red[q][tok] = sum; red[4+q][tok] = sq;
  __syncthreads();
  if (q == 0){
    float s  = red[0][tok]+red[1][tok]+red[2][tok]+red[3][tok];
    float s2 = red[4][tok]+red[5][tok]+red[6][tok]+red[7][tok];
    float mu = s*(1.f/C_);
    float rstd = rsqrtf(s2*(1.f/C_) - mu*mu + 1e-5f);
    red[0][tok] = mu; red[1][tok] = rstd;
  }
  __syncthreads();
  unsigned* yb = reinterpret_cast<unsigned*>(y + ((size_t)bl*N_ + n0)*C_);
#pragma unroll
  for (int i = 0; i < 24; ++i){
    int li = t + 256*i;                 // 6144 u32
    int tk = li / 96, c2 = li % 96;
    int c = 2*c2;
    float v0 = (tile[tk][c]  -red[0][tk])*red[1][tk]*wls[c]   + bls[c];
    float v1 = (tile[tk][c+1]-red[0][tk])*red[1][tk]*wls[c+1] + bls[c+1];
    yb[li] = cvtpk(v0, v1);
  }
}

// ---------------- QKV MFMA GEMM with gather: y bf16 -> qkv bf16 ----------------
__global__ __launch_bounds__(256) void k_qkv(const unsigned short* __restrict__ y,
    const unsigned* __restrict__ idx, const float* __restrict__ wq,
    unsigned short* __restrict__ qkv, int b_off){
  const int NT = (3*C_)/64;  // 9
  int bid = blockIdx.x;
  int bl  = bid / (16*NT);
  int rem = bid % (16*NT);
  int m0  = (rem / NT) * 128;
  int n0  = (rem % NT) * 64;
  int t = threadIdx.x, lane = t & 63;
  int wv = t >> 6, wm = wv & 1, wn = wv >> 1;
  __shared__ unsigned short Al[128][40];
  __shared__ unsigned short Bl[64][40];
  __shared__ int rows[128];
  if (t < 128) rows[t] = load_idx(idx, (b_off+bl)*K_ + m0 + t);
  __syncthreads();
  f32x4 acc[4][2] = {};
  int l15 = lane & 15, lhi = lane >> 4;
  for (int k0 = 0; k0 < C_; k0 += 32){
    {
      int m = t >> 1;
      const unsigned short* src = y + ((size_t)bl*N_ + rows[m])*C_ + k0;
#pragma unroll
      for (int i = 0; i < 4; ++i){
        int kq = (t & 1) + 2*i;
        *reinterpret_cast<ushort4*>(&Al[m][4*kq]) =
            *reinterpret_cast<const ushort4*>(src + 4*kq);
      }
      int n = t >> 2;
      const float* bsrc = wq + (size_t)(n0+n)*C_ + k0;
#pragma unroll
      for (int i = 0; i < 2; ++i){
        int q = (t & 3) + 4*i;
        float4 v = *reinterpret_cast<const float4*>(bsrc + 4*q);
        *reinterpret_cast<uint2*>(&Bl[n][4*q]) =
            make_uint2(cvtpk(v.x, v.y), cvtpk(v.z, v.w));
      }
    }
    __syncthreads();
    bf16x8 af[4], bfr[2];
#pragma unroll
    for (int mf = 0; mf < 4; ++mf)
      af[mf] = *reinterpret_cast<const bf16x8*>(&Al[wm*64 + mf*16 + l15][lhi*8]);
#pragma unroll
    for (int nf = 0; nf < 2; ++nf)
      bfr[nf] = *reinterpret_cast<const bf16x8*>(&Bl[wn*32 + nf*16 + l15][lhi*8]);
#pragma unroll
    for (int mf = 0; mf < 4; ++mf)
#pragma unroll
      for (int nf = 0; nf < 2; ++nf)
        acc[mf][nf] = __builtin_amdgcn_mfma_f32_16x16x32_bf16(af[mf], bfr[nf], acc[mf][nf], 0,0,0);
    __syncthreads();
  }
#pragma unroll
  for (int mf = 0; mf < 4; ++mf){
    int mb = m0 + wm*64 + mf*16 + lhi*4;
#pragma unroll
    for (int nf = 0; nf < 2; ++nf){
      int n = n0 + wn*32 + nf*16 + l15;
#pragma unroll
      for (int r = 0; r < 4; ++r)
        qkv[((size_t)bl*K_ + mb + r)*(3*C_) + n] = f2bf(acc[mf][nf][r]);
    }
  }
}

// ------- attention split-K (NC=8), swapped QK^T, defer-max, cvt_pk -------
__global__ __launch_bounds__(256) void k_attn(const unsigned short* __restrict__ qkv,
    float* __restrict__ po, float* __restrict__ pml, int nb){
  int bid = blockIdx.x;
  int c   = bid & (NC_-1);
  int qt  = (bid >> 3) & 31;
  int bh  = bid >> 8;
  int h = bh % HEADS_, bl = bh / HEADS_;
  int q0 = qt*64;
  int t = threadIdx.x, lane = t & 63, wv = t >> 6;
  int l15 = lane & 15, lhi = lane >> 4;
  const unsigned short* base = qkv + (size_t)bl*K_*(3*C_) + h*HD_;
  __shared__ unsigned short Ql[64][72];
  __shared__ unsigned short Kl[64][72];
  __shared__ unsigned short Vt[64][72];
  __shared__ unsigned short Pl[4][16][72];
  {
    int r = t >> 2, d0 = (t & 3) * 16;
    const uint4* src = reinterpret_cast<const uint4*>(base + (size_t)(q0+r)*(3*C_) + d0);
    *reinterpret_cast<uint4*>(&Ql[r][d0])   = src[0];
    *reinterpret_cast<uint4*>(&Ql[r][d0+8]) = src[1];
  }
  __syncthreads();
  float m_q = -1e30f, l_q = 0.f;
  f32x4 o[4] = {};
  for (int kt0 = c*KC_; kt0 < c*KC_ + KC_; kt0 += 64){
    {
      int r = t >> 2, d0 = (t & 3) * 16;
      const uint4* src = reinterpret_cast<const uint4*>(base + (size_t)(kt0+r)*(3*C_) + C_ + d0);
      *reinterpret_cast<uint4*>(&Kl[r][d0])   = src[0];
      *reinterpret_cast<uint4*>(&Kl[r][d0+8]) = src[1];
      int kp = t & 31, vd0 = (t >> 5) * 8, k = 2*kp;
      const ushort4* v0 = reinterpret_cast<const ushort4*>(base + (size_t)(kt0+k)*(3*C_)   + 2*C_ + vd0);
      const ushort4* v1 = reinterpret_cast<const ushort4*>(base + (size_t)(kt0+k+1)*(3*C_) + 2*C_ + vd0);
      ushort4 a0 = v0[0], a1 = v0[1], b0 = v1[0], b1 = v1[1];
      unsigned short va[8] = {a0.x,a0.y,a0.z,a0.w,a1.x,a1.y,a1.z,a1.w};
      unsigned short vb[8] = {b0.x,b0.y,b0.z,b0.w,b1.x,b1.y,b1.z,b1.w};
#pragma unroll
      for (int j = 0; j < 8; ++j){
        unsigned u = (unsigned)va[j] | ((unsigned)vb[j] << 16);
        *reinterpret_cast<unsigned*>(&Vt[vd0+j][k]) = u;
      }
    }
    __syncthreads();
    f32x4 s[4] = {};
    __builtin_amdgcn_s_setprio(1);
#pragma unroll
    for (int kt = 0; kt < 2; ++kt){
      bf16x8 qf = *reinterpret_cast<const bf16x8*>(&Ql[wv*16 + l15][kt*32 + lhi*8]);
#pragma unroll
      for (int nt = 0; nt < 4; ++nt){
        bf16x8 kf = *reinterpret_cast<const bf16x8*>(&Kl[nt*16 + l15][kt*32 + lhi*8]);
        s[nt] = __builtin_amdgcn_mfma_f32_16x16x32_bf16(kf, qf, s[nt], 0,0,0);
      }
    }
    __builtin_amdgcn_s_setprio(0);
    float mx = s[0][0];
#pragma unroll
    for (int nt = 0; nt < 4; ++nt)
#pragma unroll
      for (int reg = 0; reg < 4; ++reg) mx = fmaxf(mx, s[nt][reg]);
    mx = fmaxf(mx, __shfl_xor(mx, 16));
    mx = fmaxf(mx, __shfl_xor(mx, 32));
    mx *= 0.125f;
    bool skip = __all(mx <= m_q + 8.f);
    if (!skip){
      float mn = fmaxf(m_q, mx);
      float corr = __expf(m_q - mn);
      l_q *= corr;
      float cr[4];
#pragma unroll
      for (int reg = 0; reg < 4; ++reg) cr[reg] = __shfl(corr, lhi*4 + reg);
#pragma unroll
      for (int nt = 0; nt < 4; ++nt)
#pragma unroll
        for (int reg = 0; reg < 4; ++reg) o[nt][reg] *= cr[reg];
      m_q = mn;
    }
    float ls = 0.f;
#pragma unroll
    for (int nt = 0; nt < 4; ++nt){
      float p0 = __expf(fmaf(s[nt][0], 0.125f, -m_q));
      float p1 = __expf(fmaf(s[nt][1], 0.125f, -m_q));
      float p2 = __expf(fmaf(s[nt][2], 0.125f, -m_q));
      float p3 = __expf(fmaf(s[nt][3], 0.125f, -m_q));
      ls += (p0 + p1) + (p2 + p3);
      uint2 uu;
      uu.x = cvtpk(p0, p1);
      uu.y = cvtpk(p2, p3);
      *reinterpret_cast<uint2*>(&Pl[wv][l15][nt*16 + lhi*4]) = uu;
    }
    ls += __shfl_xor(ls, 16);
    ls += __shfl_xor(ls, 32);
    l_q += ls;
    __threadfence_block();
    __builtin_amdgcn_s_setprio(1);
#pragma unroll
    for (int kt = 0; kt < 2; ++kt){
      bf16x8 pa = *reinterpret_cast<const bf16x8*>(&Pl[wv][l15][kt*32 + lhi*8]);
#pragma unroll
      for (int nt = 0; nt < 4; ++nt){
        bf16x8 vb = *reinterpret_cast<const bf16x8*>(&Vt[nt*16 + l15][kt*32 + lhi*8]);
        o[nt] = __builtin_amdgcn_mfma_f32_16x16x32_bf16(pa, vb, o[nt], 0,0,0);
      }
    }
    __builtin_amdgcn_s_setprio(0);
    __syncthreads();
  }
  int R = nb*HEADS_*K_;
  int rowb = (bl*HEADS_ + h)*K_;
#pragma unroll
  for (int reg = 0; reg < 4; ++reg){
    int rq = rowb + q0 + wv*16 + lhi*4 + reg;
#pragma unroll
    for (int nt = 0; nt < 4; ++nt)
      po[((size_t)c*R + rq)*HD_ + nt*16 + l15] = o[nt][reg];
  }
  if (lhi == 0){
    int rq = rowb + q0 + wv*16 + l15;
    *reinterpret_cast<float2*>(pml + 2*((size_t)c*R + rq)) = make_float2(m_q, l_q);
  }
}

// ---------------- merge split-K partials -> ao bf16 (bl,K,C) ----------------
__global__ __launch_bounds__(256) void k_amerge(const float* __restrict__ po,
    const float* __restrict__ pml, unsigned short* __restrict__ ao, int nb){
  int R = nb*HEADS_*K_;
  int row = blockIdx.x*4 + (threadIdx.x >> 6);
  int lane = threadIdx.x & 63;
  float m[NC_], l[NC_];
#pragma unroll
  for (int cc = 0; cc < NC_; ++cc){
    float2 v = *reinterpret_cast<const float2*>(pml + 2*((size_t)cc*R + row));
    m[cc] = v.x; l[cc] = v.y;
  }
  float M = m[0];
#pragma unroll
  for (int cc = 1; cc < NC_; ++cc) M = fmaxf(M, m[cc]);
  float L = 0.f, o = 0.f;
#pragma unroll
  for (int cc = 0; cc < NC_; ++cc){
    float e = __expf(m[cc] - M);
    L += l[cc]*e;
    o += e * po[((size_t)cc*R + row)*HD_ + lane];
  }
  o /= L;
  int q = row & (K_-1);
  int bh = row >> 11;
  int h = bh % HEADS_, bl = bh / HEADS_;
  ao[((size_t)bl*K_ + q)*C_ + h*HD_ + lane] = f2bf(o);
}

// ---------------- proj MFMA GEMM + scatter into y (bf16) ----------------
__global__ __launch_bounds__(256) void k_proj(const unsigned short* __restrict__ ain,
    const unsigned* __restrict__ idx, const float* __restrict__ pw,
    const float* __restrict__ pb, unsigned short* __restrict__ y, int b_off){
  const int NT = C_/64;   // 3
  int bid = blockIdx.x;
  int bl  = bid / (16*NT);
  int rem = bid % (16*NT);
  int m0  = (rem / NT) * 128;
  int n0  = (rem % NT) * 64;
  int t = threadIdx.x, lane = t & 63;
  int wv = t >> 6, wm = wv & 1, wn = wv >> 1;
  __shared__ unsigned short Al[128][40];
  __shared__ unsigned short Bl[64][40];
  __shared__ int rows[128];
  if (t < 128) rows[t] = load_idx(idx, (b_off+bl)*K_ + m0 + t);
  __syncthreads();
  f32x4 acc[4][2] = {};
  int l15 = lane & 15, lhi = lane >> 4;
  for (int k0 = 0; k0 < C_; k0 += 32){
    {
      int m = t >> 1;
      const unsigned short* src = ain + ((size_t)bl*K_ + m0 + m)*C_ + k0;
#pragma unroll
      for (int i = 0; i < 4; ++i){
        int kq = (t & 1) + 2*i;
        *reinterpret_cast<ushort4*>(&Al[m][4*kq]) =
            *reinterpret_cast<const ushort4*>(src + 4*kq);
      }
      int n = t >> 2;
      const float* bsrc = pw + (size_t)(n0+n)*C_ + k0;
#pragma unroll
      for (int i = 0; i < 2; ++i){
        int q = (t & 3) + 4*i;
        float4 v = *reinterpret_cast<const float4*>(bsrc + 4*q);
        *reinterpret_cast<uint2*>(&Bl[n][4*q]) =
            make_uint2(cvtpk(v.x, v.y), cvtpk(v.z, v.w));
      }
    }
    __syncthreads();
    bf16x8 af[4], bfr[2];
#pragma unroll
    for (int mf = 0; mf < 4; ++mf)
      af[mf] = *reinterpret_cast<const bf16x8*>(&Al[wm*64 + mf*16 + l15][lhi*8]);
#pragma unroll
    for (int nf = 0; nf < 2; ++nf)
      bfr[nf] = *reinterpret_cast<const bf16x8*>(&Bl[wn*32 + nf*16 + l15][lhi*8]);
#pragma unroll
    for (int mf = 0; mf < 4; ++mf)
#pragma unroll
      for (int nf = 0; nf < 2; ++nf)
        acc[mf][nf] = __builtin_amdgcn_mfma_f32_16x16x32_bf16(af[mf], bfr[nf], acc[mf][nf], 0,0,0);
    __syncthreads();
  }
#pragma unroll
  for (int mf = 0; mf < 4; ++mf){
    int mb = wm*64 + mf*16 + lhi*4;
#pragma unroll
    for (int nf = 0; nf < 2; ++nf){
      int n = n0 + wn*32 + nf*16 + l15;
      float bv = pb[n];
#pragma unroll
      for (int r = 0; r < 4; ++r)
        y[((size_t)bl*N_ + rows[mb + r])*C_ + n] = f2bf(acc[mf][nf][r] + bv);
    }
  }
}

// ---------------- residual + LN2 -> ln2t (B,C,N) [== d_out] ----------------
__global__ __launch_bounds__(256) void k_ln2(const float* __restrict__ x,
    const unsigned short* __restrict__ y, const float* __restrict__ w,
    const float* __restrict__ bias, float* __restrict__ ln2t, int b_off){
  int blk = blockIdx.x;
  int bl = blk >> 8;
  int b  = b_off + bl;
  int n0 = (blk & 255) * 64;
  int t  = threadIdx.x;
  int tok = t & 63, q = t >> 6;
  __shared__ float tile[64][C_+1];
  __shared__ float red[8][64];
  __shared__ float wls[C_], bls[C_];
  if (t < C_){ wls[t] = w[t]; bls[t] = bias[t]; }
  const unsigned* yb = reinterpret_cast<const unsigned*>(y + ((size_t)bl*N_ + n0)*C_);
#pragma unroll
  for (int i = 0; i < 24; ++i){
    int li = t + 256*i;
    unsigned u = yb[li];
    int tk = li / 96, c2 = li % 96;
    tile[tk][2*c2]   = bf2f((unsigned short)(u & 0xffffu));
    tile[tk][2*c2+1] = bf2f((unsigned short)(u >> 16));
  }
  __syncthreads();
  const float* xb = x + (size_t)b*C_*N_ + n0;
  float sum = 0.f, sq = 0.f;
#pragma unroll
  for (int i = 0; i < 48; ++i){
    int c = q + 4*i;
    float v = xb[(size_t)c*N_ + tok] + tile[tok][c];
    tile[tok][c] = v;
    sum += v; sq += v*v;
  }
  red[q][tok] = sum; red[4+q][tok] = sq;
  __syncthreads();
  if (q == 0){
    float s  = red[0][tok]+red[1][tok]+red[2][tok]+red[3][tok];
    float s2 = red[4][tok]+red[5][tok]+red[6][tok]+red[7][tok];
    float mu = s*(1.f/C_);
    float rstd = rsqrtf(s2*(1.f/C_) - mu*mu + 1e-5f);
    red[0][tok] = mu; red[1][tok] = rstd;
  }
  __syncthreads();
  float* ob = ln2t + (size_t)b*C_*N_ + n0;
  float mu = red[0][tok], rstd = red[1][tok];
#pragma unroll
  for (int i = 0; i < 48; ++i){
    int c = q + 4*i;
    ob[(size_t)c*N_ + tok] = (tile[tok][c]-mu)*rstd*wls[c] + bls[c];
  }
}

// ------- fc1 MFMA: block = 128-token m-tile x 384-hid half, loop 6 n-tiles -------
__global__ __launch_bounds__(256) void k_fc1(const float* __restrict__ ln2t,
    const float* __restrict__ wgt, const float* __restrict__ bias,
    unsigned short* __restrict__ h1, int b_off){
  int bid = blockIdx.x;
  int bl  = bid >> 8;                  // slot-local batch
  int rem = bid & 255;
  int m0  = (rem >> 1) * 128;
  int nh  = (rem & 1) * 6;             // n-tile half
  int t = threadIdx.x, lane = t & 63;
  int wv = t >> 6, wm = wv & 1, wn = wv >> 1;
  int l15 = lane & 15, lhi = lane >> 4;
  __shared__ unsigned short Al[128][200];
  __shared__ unsigned short Bl[64][200];
  const float* a = ln2t + (size_t)(b_off+bl)*C_*N_ + m0;
  unsigned short* hb = h1 + (size_t)bl*HID_*N_;
  {
    int m = t & 127, half = t >> 7;
#pragma unroll
    for (int i = 0; i < 48; ++i){
      int p = half + 2*i;                    // 0..95
      float v0 = a[(size_t)(2*p)*N_ + m];
      float v1 = a[(size_t)(2*p+1)*N_ + m];
      *reinterpret_cast<unsigned*>(&Al[m][2*p]) = cvtpk(v0, v1);
    }
  }
  for (int nt = 0; nt < 6; ++nt){
    int n0 = (nh + nt)*64;
    __syncthreads();
    {
      int n = t >> 2;
      const float* bsrc = wgt + (size_t)(n0+n)*C_;
#pragma unroll
      for (int i = 0; i < 12; ++i){
        int q = (t & 3) + 4*i;               // 0..47 float4 segs
        float4 v = *reinterpret_cast<const float4*>(bsrc + 4*q);
        *reinterpret_cast<uint2*>(&Bl[n][4*q]) =
            make_uint2(cvtpk(v.x, v.y), cvtpk(v.z, v.w));
      }
    }
    __syncthreads();
    f32x4 acc[4][2] = {};
#pragma unroll
    for (int ks = 0; ks < 6; ++ks){
      bf16x8 af[4], bfr[2];
#pragma unroll
      for (int mf = 0; mf < 4; ++mf)
        af[mf] = *reinterpret_cast<const bf16x8*>(&Al[wm*64 + mf*16 + l15][ks*32 + lhi*8]);
#pragma unroll
      for (int nf = 0; nf < 2; ++nf)
        bfr[nf] = *reinterpret_cast<const bf16x8*>(&Bl[wn*32 + nf*16 + l15][ks*32 + lhi*8]);
#pragma unroll
      for (int mf = 0; mf < 4; ++mf)
#pragma unroll
        for (int nf = 0; nf < 2; ++nf)
          acc[mf][nf] = __builtin_amdgcn_mfma_f32_16x16x32_bf16(af[mf], bfr[nf], acc[mf][nf], 0,0,0);
    }
#pragma unroll
    for (int mf = 0; mf < 4; ++mf){
      int mb = m0 + wm*64 + mf*16 + lhi*4;
#pragma unroll
      for (int nf = 0; nf < 2; ++nf){
        int n = n0 + wn*32 + nf*16 + l15;
        float bv = bias[n];
        uint2 pk;
        pk.x = cvtpk(acc[mf][nf][0] + bv, acc[mf][nf][1] + bv);
        pk.y = cvtpk(acc[mf][nf][2] + bv, acc[mf][nf][3] + bv);
        *reinterpret_cast<uint2*>(&hb[(size_t)n*N_ + mb]) = pk;
      }
    }
  }
}

// ------- fused depthwise3x3+GELU+fc2+residual: block = 1 image row x 192 ch -------
// 512 thr, 51.7KB LDS; single Ht buffer, 2 barriers/chunk, reg-prefetched h1
__global__ __launch_bounds__(512) void k_fc2f(const unsigned short* __restrict__ h1,
    const float* __restrict__ dw, const float* __restrict__ wgt,
    const float* __restrict__ bias, float* __restrict__ out, int b_off){
  int nwg = gridDim.x;
  int cpx = nwg >> 3;
  int bid = (blockIdx.x & 7)*cpx + (blockIdx.x >> 3);  // contiguous rows per XCD
  int bl  = bid >> 7;            // slot-local batch
  int r   = bid & 127;           // image row
  int b   = b_off + bl;
  int t = threadIdx.x, lane = t & 63, wv = t >> 6;
  int wm = wv & 1, wn = wv >> 1;
  int l15 = lane & 15, lhi = lane >> 4;
  __shared__ unsigned short Ht[32][3][136];     // 26.1KB; ch-stride 816B (51x16B)
  __shared__ unsigned short Alc[128][40];       // 10.2KB
  __shared__ unsigned short Bl[192][40];        // 15.4KB
  const unsigned short* h1b = h1 + (size_t)bl*HID_*N_;
  f32x4 acc[4][3] = {};
  int cch = t & 31, j0 = (t >> 5) * 8;          // conv: channel, col base
  // ---- hoisted per-thread staging state ----
  const unsigned short* gp[3]; unsigned short* lp[3]; bool gok[3];
#pragma unroll
  for (int i = 0; i < 3; ++i){
    int li = t + 512*i;                         // 0..1535
    int ch = li / 48, rm = li % 48, dy = rm >> 4, seg = rm & 15;
    int rr = r - 1 + dy;
    gok[i] = (rr >= 0 && rr < H_);
    gp[i] = h1b + (size_t)ch*N_ + (gok[i] ? rr : 0)*W_ + seg*8;
    lp[i] = &Ht[ch][dy][seg*8];
  }
  const float* wgp[3]; unsigned short* blp[3];
#pragma unroll
  for (int i = 0; i < 3; ++i){
    int row = (t >> 3) + 64*i, seg = t & 7;
    wgp[i] = wgt + (size_t)row*HID_ + seg*4;
    blp[i] = &Bl[row][seg*4];
  }
  const float* dwp = dw + (size_t)cch*9;        // advance +288 per chunk
  uint4 hr[3];
  auto hload = [&](){
#pragma unroll
    for (int i = 0; i < 3; ++i)
      hr[i] = gok[i] ? *reinterpret_cast<const uint4*>(gp[i]) : make_uint4(0u,0u,0u,0u);
#pragma unroll
    for (int i = 0; i < 3; ++i) gp[i] += 32*N_;
  };
  // prologue: chunk 0 into Ht, prefetch chunk 1 into regs
  hload();
#pragma unroll
  for (int i = 0; i < 3; ++i) *reinterpret_cast<uint4*>(lp[i]) = hr[i];
  hload();
  for (int c24 = 0; c24 < 24; ++c24){
    __syncthreads();                  // A: Ht(c) visible; prev MFMA done
    // stage Bl direct from global (L2-hot weights)
#pragma unroll
    for (int i = 0; i < 3; ++i){
      float4 v = *reinterpret_cast<const float4*>(wgp[i]);
      wgp[i] += 32;
      *reinterpret_cast<uint2*>(blp[i]) =
          make_uint2(cvtpk(v.x, v.y), cvtpk(v.z, v.w));
    }
    // conv 3x3 + fast GELU from Ht -> Alc; dw direct (broadcast-hot)
    {
      float w9[9];
#pragma unroll
      for (int i = 0; i < 9; ++i) w9[i] = dwp[i];
      dwp += 288;
      const unsigned short* hp = &Ht[cch][0][j0];
      float s[8] = {0.f,0.f,0.f,0.f,0.f,0.f,0.f,0.f};
#pragma unroll
      for (int dy = 0; dy < 3; ++dy){
        const unsigned short* rp = hp + dy*136;
        bf16x8 mid = *reinterpret_cast<const bf16x8*>(rp);
        float v[10];
        v[0] = (j0 > 0)   ? bf2f(rp[-1]) : 0.f;
        v[9] = (j0 < 120) ? bf2f(rp[8])  : 0.f;
#pragma unroll
        for (int j = 0; j < 8; ++j) v[1+j] = bf2f((unsigned short)mid[j]);
        float wa = w9[3*dy], wb = w9[3*dy+1], wc = w9[3*dy+2];
#pragma unroll
        for (int j = 0; j < 8; ++j)
          s[j] += v[j]*wa + v[j+1]*wb + v[j+2]*wc;
      }
#pragma unroll
      for (int j = 0; j < 8; ++j)
        Alc[j0+j][cch] = f2bf(gelu_fast(s[j]));
    }
    __syncthreads();                  // B: Alc+Bl visible; Ht reads complete
    // write prefetched chunk c+1 into Ht (dead now); prefetch c+2
    if (c24 < 23){
#pragma unroll
      for (int i = 0; i < 3; ++i)
        *reinterpret_cast<uint4*>(lp[i]) = hr[i];
      if (c24 < 22) hload();
    }
    // MFMA: wave = 64-tok half (wm) x 48-ch quarter (wn)
    bf16x8 af[4], bfr[3];
#pragma unroll
    for (int mf = 0; mf < 4; ++mf)
      af[mf] = *reinterpret_cast<const bf16x8*>(&Alc[wm*64 + mf*16 + l15][lhi*8]);
#pragma unroll
    for (int nf = 0; nf < 3; ++nf)
      bfr[nf] = *reinterpret_cast<const bf16x8*>(&Bl[wn*48 + nf*16 + l15][lhi*8]);
    __builtin_amdgcn_s_setprio(1);
#pragma unroll
    for (int mf = 0; mf < 4; ++mf)
#pragma unroll
      for (int nf = 0; nf < 3; ++nf)
        acc[mf][nf] = __builtin_amdgcn_mfma_f32_16x16x32_bf16(af[mf], bfr[nf], acc[mf][nf], 0,0,0);
    __builtin_amdgcn_s_setprio(0);
  }
  // epilogue: += bias + residual (out holds ln2t)
#pragma unroll
  for (int mf = 0; mf < 4; ++mf){
    int tok = r*W_ + wm*64 + mf*16 + lhi*4;
#pragma unroll
    for (int nf = 0; nf < 3; ++nf){
      int oc = wn*48 + nf*16 + l15;
      float bv = bias[oc];
      size_t off = ((size_t)b*C_ + oc)*N_ + tok;
      float4 rr = *reinterpret_cast<const float4*>(out + off);
      float4 v = make_float4(rr.x + acc[mf][nf][0] + bv, rr.y + acc[mf][nf][1] + bv,
                             rr.z + acc[mf][nf][2] + bv, rr.w + acc[mf][nf][3] + bv);
      *reinterpret_cast<float4*>(out + off) = v;
    }
  }
}

extern "C" void kernel_launch(void* const* d_in, const int* in_sizes, int n_in,
                              void* d_out, int out_size, void* d_ws, size_t ws_size,
                              hipStream_t stream) {
  const float*    x      = (const float*)d_in[0];
  const unsigned* idx    = (const unsigned*)d_in[1];
  const float*    ln1_w  = (const float*)d_in[2];
  const float*    ln1_b  = (const float*)d_in[3];
  const float*    qkv_w  = (const float*)d_in[4];
  const float*    proj_w = (const float*)d_in[5];
  const float*    proj_b = (const float*)d_in[6];
  const float*    ln2_w  = (const float*)d_in[7];
  const float*    ln2_b  = (const float*)d_in[8];
  const float*    fc1_w  = (const float*)d_in[9];
  const float*    fc1_b  = (const float*)d_in[10];
  const float*    dw_w   = (const float*)d_in[11];
  const float*    fc2_w  = (const float*)d_in[12];
  const float*    fc2_b  = (const float*)d_in[13];
  float* out = (float*)d_out;          // doubles as ln2t (B,C,N) f32

  const size_t SZY = (size_t)N_*C_*2;              // y bf16: 6.29 MB/batch
  const size_t SZQ = (size_t)K_*3*C_*2;            // 2.36
  const size_t SZA = (size_t)K_*C_*2;              // 0.79
  const size_t SZO = (size_t)NC_*HEADS_*K_*HD_*4;  // 12.58/batch
  const size_t SZH = (size_t)HID_*N_*2;            // 25.17/batch
  int nb = (ws_size >= (size_t)B_*SZH) ? B_ : 1;   // deterministic

  char* ws = (char*)d_ws;
  unsigned short* y16  = (unsigned short*)ws;
  unsigned short* qkvb = (unsigned short*)(ws + (size_t)nb*SZY);
  unsigned short* aob  = (unsigned short*)(ws + (size_t)nb*(SZY+SZQ));
  float*          po   = (float*)(ws + (size_t)nb*(SZY+SZQ+SZA));
  float*          pml  = (float*)(ws + (size_t)nb*(SZY+SZQ+SZA+SZO));
  unsigned short* h1s  = (unsigned short*)ws;      // MLP phase (front dead): nb slots

  for (int b0 = 0; b0 < B_; b0 += nb){
    k_ln1   <<<nb*256,             256, 0, stream>>>(x, ln1_w, ln1_b, y16, b0);
    k_qkv   <<<nb*16*9,            256, 0, stream>>>(y16, idx, qkv_w, qkvb, b0);
    k_attn  <<<nb*HEADS_*32*NC_,   256, 0, stream>>>(qkvb, po, pml, nb);
    k_amerge<<<nb*HEADS_*K_/4,     256, 0, stream>>>(po, pml, aob, nb);
    k_proj  <<<nb*16*3,            256, 0, stream>>>(aob, idx, proj_w, proj_b, y16, b0);
    k_ln2   <<<nb*256,             256, 0, stream>>>(x, y16, ln2_w, ln2_b, out, b0);
    k_fc1   <<<nb*256,             256, 0, stream>>>(out, fc1_w, fc1_b, h1s, b0);
    k_fc2f  <<<nb*128,             512, 0, stream>>>(h1s, dw_w, fc2_w, fc2_b, out, b0);
  }
}

// Round 19
// 243.819 us; speedup vs baseline: 1.1335x; 1.0620x over previous
//
#include <hip/hip_runtime.h>

#define B_ 4
#define C_ 192
#define H_ 128
#define W_ 128
#define N_ (H_*W_)      // 16384
#define K_ 2048
#define HEADS_ 3
#define HD_ 64
#define HID_ 768
#define NC_ 8           // attention split-K chunks
#define KC_ (K_/NC_)    // 256

typedef __attribute__((ext_vector_type(4))) float f32x4;
typedef __attribute__((ext_vector_type(8))) short bf16x8;

__device__ __forceinline__ unsigned short f2bf(float f){
  unsigned int u = __float_as_uint(f);
  u += 0x7FFFu + ((u >> 16) & 1u);
  return (unsigned short)(u >> 16);
}
__device__ __forceinline__ float bf2f(unsigned short s){
  return __uint_as_float(((unsigned int)s) << 16);
}
__device__ __forceinline__ unsigned cvtpk(float lo, float hi){
  unsigned r;
  asm("v_cvt_pk_bf16_f32 %0, %1, %2" : "=v"(r) : "v"(lo), "v"(hi));
  return r;
}
// sigmoid-form GELU: x * sigma(1.702x); ~5 VALU via HW rcp. |err| <= ~0.02
__device__ __forceinline__ float gelu_fast(float x){
  float e = __expf(-1.702f*x);
  return x * __builtin_amdgcn_rcpf(1.f + e);
}

__device__ __forceinline__ int load_idx(const unsigned* __restrict__ ip, int pos){
  bool is64 = (ip[1]==0u) & (ip[3]==0u) & (ip[5]==0u) & (ip[7]==0u);
  int v = is64 ? (int)ip[2*pos] : (int)ip[pos];
  return min(max(v, 0), N_-1);
}

// ---------------- LN1: x (B,C,N) -> y bf16 (nb,N,C) ----------------
__global__ __launch_bounds__(256) void k_ln1(const float* __restrict__ x,
    const float* __restrict__ w, const float* __restrict__ bias,
    unsigned short* __restrict__ y, int b_off){
  int blk = blockIdx.x;
  int bl = blk >> 8;
  int b  = b_off + bl;
  int n0 = (blk & 255) * 64;
  int t  = threadIdx.x;
  int tok = t & 63, q = t >> 6;
  __shared__ float tile[64][C_+1];
  __shared__ float red[8][64];
  __shared__ float wls[C_], bls[C_];
  if (t < C_){ wls[t] = w[t]; bls[t] = bias[t]; }
  const float* xb = x + (size_t)b*C_*N_ + n0;
  float sum = 0.f, sq = 0.f;
#pragma unroll
  for (int i = 0; i < 48; ++i){
    int c = q + 4*i;
    float v = xb[(size_t)c*N_ + tok];
    tile[tok][c] = v;
    sum += v; sq += v*v;
  }
  red[q][tok] = sum; red[4+q][tok] = sq;
  __syncthreads();
  if (q == 0){
    float s  = red[0][tok]+red[1][tok]+red[2][tok]+red[3][tok];
    float s2 = red[4][tok]+red[5][tok]+red[6][tok]+red[7][tok];
    float mu = s*(1.f/C_);
    float rstd = rsqrtf(s2*(1.f/C_) - mu*mu + 1e-5f);
    red[0][tok] = mu; red[1][tok] = rstd;
  }
  __syncthreads();
  unsigned* yb = reinterpret_cast<unsigned*>(y + ((size_t)bl*N_ + n0)*C_);
#pragma unroll
  for (int i = 0; i < 24; ++i){
    int li = t + 256*i;                 // 6144 u32
    int tk = li / 96, c2 = li % 96;
    int c = 2*c2;
    float v0 = (tile[tk][c]  -red[0][tk])*red[1][tk]*wls[c]   + bls[c];
    float v1 = (tile[tk][c+1]-red[0][tk])*red[1][tk]*wls[c+1] + bls[c+1];
    yb[li] = cvtpk(v0, v1);
  }
}

// ---------------- QKV MFMA GEMM with gather: y bf16 -> qkv bf16 ----------------
__global__ __launch_bounds__(256) void k_qkv(const unsigned short* __restrict__ y,
    const unsigned* __restrict__ idx, const float* __restrict__ wq,
    unsigned short* __restrict__ qkv, int b_off){
  const int NT = (3*C_)/64;  // 9
  int bid = blockIdx.x;
  int bl  = bid / (16*NT);
  int rem = bid % (16*NT);
  int m0  = (rem / NT) * 128;
  int n0  = (rem % NT) * 64;
  int t = threadIdx.x, lane = t & 63;
  int wv = t >> 6, wm = wv & 1, wn = wv >> 1;
  __shared__ unsigned short Al[128][40];
  __shared__ unsigned short Bl[64][40];
  __shared__ int rows[128];
  if (t < 128) rows[t] = load_idx(idx, (b_off+bl)*K_ + m0 + t);
  __syncthreads();
  f32x4 acc[4][2] = {};
  int l15 = lane & 15, lhi = lane >> 4;
  for (int k0 = 0; k0 < C_; k0 += 32){
    {
      int m = t >> 1;
      const unsigned short* src = y + ((size_t)bl*N_ + rows[m])*C_ + k0;
#pragma unroll
      for (int i = 0; i < 4; ++i){
        int kq = (t & 1) + 2*i;
        *reinterpret_cast<ushort4*>(&Al[m][4*kq]) =
            *reinterpret_cast<const ushort4*>(src + 4*kq);
      }
      int n = t >> 2;
      const float* bsrc = wq + (size_t)(n0+n)*C_ + k0;
#pragma unroll
      for (int i = 0; i < 2; ++i){
        int q = (t & 3) + 4*i;
        float4 v = *reinterpret_cast<const float4*>(bsrc + 4*q);
        *reinterpret_cast<uint2*>(&Bl[n][4*q]) =
            make_uint2(cvtpk(v.x, v.y), cvtpk(v.z, v.w));
      }
    }
    __syncthreads();
    bf16x8 af[4], bfr[2];
#pragma unroll
    for (int mf = 0; mf < 4; ++mf)
      af[mf] = *reinterpret_cast<const bf16x8*>(&Al[wm*64 + mf*16 + l15][lhi*8]);
#pragma unroll
    for (int nf = 0; nf < 2; ++nf)
      bfr[nf] = *reinterpret_cast<const bf16x8*>(&Bl[wn*32 + nf*16 + l15][lhi*8]);
#pragma unroll
    for (int mf = 0; mf < 4; ++mf)
#pragma unroll
      for (int nf = 0; nf < 2; ++nf)
        acc[mf][nf] = __builtin_amdgcn_mfma_f32_16x16x32_bf16(af[mf], bfr[nf], acc[mf][nf], 0,0,0);
    __syncthreads();
  }
#pragma unroll
  for (int mf = 0; mf < 4; ++mf){
    int mb = m0 + wm*64 + mf*16 + lhi*4;
#pragma unroll
    for (int nf = 0; nf < 2; ++nf){
      int n = n0 + wn*32 + nf*16 + l15;
#pragma unroll
      for (int r = 0; r < 4; ++r)
        qkv[((size_t)bl*K_ + mb + r)*(3*C_) + n] = f2bf(acc[mf][nf][r]);
    }
  }
}

// ------- attention split-K (NC=8), swapped QK^T, defer-max, cvt_pk -------
__global__ __launch_bounds__(256) void k_attn(const unsigned short* __restrict__ qkv,
    float* __restrict__ po, float* __restrict__ pml, int nb){
  int bid = blockIdx.x;
  int c   = bid & (NC_-1);
  int qt  = (bid >> 3) & 31;
  int bh  = bid >> 8;
  int h = bh % HEADS_, bl = bh / HEADS_;
  int q0 = qt*64;
  int t = threadIdx.x, lane = t & 63, wv = t >> 6;
  int l15 = lane & 15, lhi = lane >> 4;
  const unsigned short* base = qkv + (size_t)bl*K_*(3*C_) + h*HD_;
  __shared__ unsigned short Ql[64][72];
  __shared__ unsigned short Kl[64][72];
  __shared__ unsigned short Vt[64][72];
  __shared__ unsigned short Pl[4][16][72];
  {
    int r = t >> 2, d0 = (t & 3) * 16;
    const uint4* src = reinterpret_cast<const uint4*>(base + (size_t)(q0+r)*(3*C_) + d0);
    *reinterpret_cast<uint4*>(&Ql[r][d0])   = src[0];
    *reinterpret_cast<uint4*>(&Ql[r][d0+8]) = src[1];
  }
  __syncthreads();
  float m_q = -1e30f, l_q = 0.f;
  f32x4 o[4] = {};
  for (int kt0 = c*KC_; kt0 < c*KC_ + KC_; kt0 += 64){
    {
      int r = t >> 2, d0 = (t & 3) * 16;
      const uint4* src = reinterpret_cast<const uint4*>(base + (size_t)(kt0+r)*(3*C_) + C_ + d0);
      *reinterpret_cast<uint4*>(&Kl[r][d0])   = src[0];
      *reinterpret_cast<uint4*>(&Kl[r][d0+8]) = src[1];
      int kp = t & 31, vd0 = (t >> 5) * 8, k = 2*kp;
      const ushort4* v0 = reinterpret_cast<const ushort4*>(base + (size_t)(kt0+k)*(3*C_)   + 2*C_ + vd0);
      const ushort4* v1 = reinterpret_cast<const ushort4*>(base + (size_t)(kt0+k+1)*(3*C_) + 2*C_ + vd0);
      ushort4 a0 = v0[0], a1 = v0[1], b0 = v1[0], b1 = v1[1];
      unsigned short va[8] = {a0.x,a0.y,a0.z,a0.w,a1.x,a1.y,a1.z,a1.w};
      unsigned short vb[8] = {b0.x,b0.y,b0.z,b0.w,b1.x,b1.y,b1.z,b1.w};
#pragma unroll
      for (int j = 0; j < 8; ++j){
        unsigned u = (unsigned)va[j] | ((unsigned)vb[j] << 16);
        *reinterpret_cast<unsigned*>(&Vt[vd0+j][k]) = u;
      }
    }
    __syncthreads();
    f32x4 s[4] = {};
    __builtin_amdgcn_s_setprio(1);
#pragma unroll
    for (int kt = 0; kt < 2; ++kt){
      bf16x8 qf = *reinterpret_cast<const bf16x8*>(&Ql[wv*16 + l15][kt*32 + lhi*8]);
#pragma unroll
      for (int nt = 0; nt < 4; ++nt){
        bf16x8 kf = *reinterpret_cast<const bf16x8*>(&Kl[nt*16 + l15][kt*32 + lhi*8]);
        s[nt] = __builtin_amdgcn_mfma_f32_16x16x32_bf16(kf, qf, s[nt], 0,0,0);
      }
    }
    __builtin_amdgcn_s_setprio(0);
    float mx = s[0][0];
#pragma unroll
    for (int nt = 0; nt < 4; ++nt)
#pragma unroll
      for (int reg = 0; reg < 4; ++reg) mx = fmaxf(mx, s[nt][reg]);
    mx = fmaxf(mx, __shfl_xor(mx, 16));
    mx = fmaxf(mx, __shfl_xor(mx, 32));
    mx *= 0.125f;
    bool skip = __all(mx <= m_q + 8.f);
    if (!skip){
      float mn = fmaxf(m_q, mx);
      float corr = __expf(m_q - mn);
      l_q *= corr;
      float cr[4];
#pragma unroll
      for (int reg = 0; reg < 4; ++reg) cr[reg] = __shfl(corr, lhi*4 + reg);
#pragma unroll
      for (int nt = 0; nt < 4; ++nt)
#pragma unroll
        for (int reg = 0; reg < 4; ++reg) o[nt][reg] *= cr[reg];
      m_q = mn;
    }
    float ls = 0.f;
#pragma unroll
    for (int nt = 0; nt < 4; ++nt){
      float p0 = __expf(fmaf(s[nt][0], 0.125f, -m_q));
      float p1 = __expf(fmaf(s[nt][1], 0.125f, -m_q));
      float p2 = __expf(fmaf(s[nt][2], 0.125f, -m_q));
      float p3 = __expf(fmaf(s[nt][3], 0.125f, -m_q));
      ls += (p0 + p1) + (p2 + p3);
      uint2 uu;
      uu.x = cvtpk(p0, p1);
      uu.y = cvtpk(p2, p3);
      *reinterpret_cast<uint2*>(&Pl[wv][l15][nt*16 + lhi*4]) = uu;
    }
    ls += __shfl_xor(ls, 16);
    ls += __shfl_xor(ls, 32);
    l_q += ls;
    __threadfence_block();
    __builtin_amdgcn_s_setprio(1);
#pragma unroll
    for (int kt = 0; kt < 2; ++kt){
      bf16x8 pa = *reinterpret_cast<const bf16x8*>(&Pl[wv][l15][kt*32 + lhi*8]);
#pragma unroll
      for (int nt = 0; nt < 4; ++nt){
        bf16x8 vb = *reinterpret_cast<const bf16x8*>(&Vt[nt*16 + l15][kt*32 + lhi*8]);
        o[nt] = __builtin_amdgcn_mfma_f32_16x16x32_bf16(pa, vb, o[nt], 0,0,0);
      }
    }
    __builtin_amdgcn_s_setprio(0);
    __syncthreads();
  }
  int R = nb*HEADS_*K_;
  int rowb = (bl*HEADS_ + h)*K_;
#pragma unroll
  for (int reg = 0; reg < 4; ++reg){
    int rq = rowb + q0 + wv*16 + lhi*4 + reg;
#pragma unroll
    for (int nt = 0; nt < 4; ++nt)
      po[((size_t)c*R + rq)*HD_ + nt*16 + l15] = o[nt][reg];
  }
  if (lhi == 0){
    int rq = rowb + q0 + wv*16 + l15;
    *reinterpret_cast<float2*>(pml + 2*((size_t)c*R + rq)) = make_float2(m_q, l_q);
  }
}

// ---------------- merge split-K partials -> ao bf16 (bl,K,C) ----------------
__global__ __launch_bounds__(256) void k_amerge(const float* __restrict__ po,
    const float* __restrict__ pml, unsigned short* __restrict__ ao, int nb){
  int R = nb*HEADS_*K_;
  int row = blockIdx.x*4 + (threadIdx.x >> 6);
  int lane = threadIdx.x & 63;
  float m[NC_], l[NC_];
#pragma unroll
  for (int cc = 0; cc < NC_; ++cc){
    float2 v = *reinterpret_cast<const float2*>(pml + 2*((size_t)cc*R + row));
    m[cc] = v.x; l[cc] = v.y;
  }
  float M = m[0];
#pragma unroll
  for (int cc = 1; cc < NC_; ++cc) M = fmaxf(M, m[cc]);
  float L = 0.f, o = 0.f;
#pragma unroll
  for (int cc = 0; cc < NC_; ++cc){
    float e = __expf(m[cc] - M);
    L += l[cc]*e;
    o += e * po[((size_t)cc*R + row)*HD_ + lane];
  }
  o /= L;
  int q = row & (K_-1);
  int bh = row >> 11;
  int h = bh % HEADS_, bl = bh / HEADS_;
  ao[((size_t)bl*K_ + q)*C_ + h*HD_ + lane] = f2bf(o);
}

// ---------------- proj MFMA GEMM + scatter into y (bf16) ----------------
__global__ __launch_bounds__(256) void k_proj(const unsigned short* __restrict__ ain,
    const unsigned* __restrict__ idx, const float* __restrict__ pw,
    const float* __restrict__ pb, unsigned short* __restrict__ y, int b_off){
  const int NT = C_/64;   // 3
  int bid = blockIdx.x;
  int bl  = bid / (16*NT);
  int rem = bid % (16*NT);
  int m0  = (rem / NT) * 128;
  int n0  = (rem % NT) * 64;
  int t = threadIdx.x, lane = t & 63;
  int wv = t >> 6, wm = wv & 1, wn = wv >> 1;
  __shared__ unsigned short Al[128][40];
  __shared__ unsigned short Bl[64][40];
  __shared__ int rows[128];
  if (t < 128) rows[t] = load_idx(idx, (b_off+bl)*K_ + m0 + t);
  __syncthreads();
  f32x4 acc[4][2] = {};
  int l15 = lane & 15, lhi = lane >> 4;
  for (int k0 = 0; k0 < C_; k0 += 32){
    {
      int m = t >> 1;
      const unsigned short* src = ain + ((size_t)bl*K_ + m0 + m)*C_ + k0;
#pragma unroll
      for (int i = 0; i < 4; ++i){
        int kq = (t & 1) + 2*i;
        *reinterpret_cast<ushort4*>(&Al[m][4*kq]) =
            *reinterpret_cast<const ushort4*>(src + 4*kq);
      }
      int n = t >> 2;
      const float* bsrc = pw + (size_t)(n0+n)*C_ + k0;
#pragma unroll
      for (int i = 0; i < 2; ++i){
        int q = (t & 3) + 4*i;
        float4 v = *reinterpret_cast<const float4*>(bsrc + 4*q);
        *reinterpret_cast<uint2*>(&Bl[n][4*q]) =
            make_uint2(cvtpk(v.x, v.y), cvtpk(v.z, v.w));
      }
    }
    __syncthreads();
    bf16x8 af[4], bfr[2];
#pragma unroll
    for (int mf = 0; mf < 4; ++mf)
      af[mf] = *reinterpret_cast<const bf16x8*>(&Al[wm*64 + mf*16 + l15][lhi*8]);
#pragma unroll
    for (int nf = 0; nf < 2; ++nf)
      bfr[nf] = *reinterpret_cast<const bf16x8*>(&Bl[wn*32 + nf*16 + l15][lhi*8]);
#pragma unroll
    for (int mf = 0; mf < 4; ++mf)
#pragma unroll
      for (int nf = 0; nf < 2; ++nf)
        acc[mf][nf] = __builtin_amdgcn_mfma_f32_16x16x32_bf16(af[mf], bfr[nf], acc[mf][nf], 0,0,0);
    __syncthreads();
  }
#pragma unroll
  for (int mf = 0; mf < 4; ++mf){
    int mb = wm*64 + mf*16 + lhi*4;
#pragma unroll
    for (int nf = 0; nf < 2; ++nf){
      int n = n0 + wn*32 + nf*16 + l15;
      float bv = pb[n];
#pragma unroll
      for (int r = 0; r < 4; ++r)
        y[((size_t)bl*N_ + rows[mb + r])*C_ + n] = f2bf(acc[mf][nf][r] + bv);
    }
  }
}

// ---------------- residual + LN2 -> ln2t (B,C,N) [== d_out] ----------------
__global__ __launch_bounds__(256) void k_ln2(const float* __restrict__ x,
    const unsigned short* __restrict__ y, const float* __restrict__ w,
    const float* __restrict__ bias, float* __restrict__ ln2t, int b_off){
  int blk = blockIdx.x;
  int bl = blk >> 8;
  int b  = b_off + bl;
  int n0 = (blk & 255) * 64;
  int t  = threadIdx.x;
  int tok = t & 63, q = t >> 6;
  __shared__ float tile[64][C_+1];
  __shared__ float red[8][64];
  __shared__ float wls[C_], bls[C_];
  if (t < C_){ wls[t] = w[t]; bls[t] = bias[t]; }
  const unsigned* yb = reinterpret_cast<const unsigned*>(y + ((size_t)bl*N_ + n0)*C_);
#pragma unroll
  for (int i = 0; i < 24; ++i){
    int li = t + 256*i;
    unsigned u = yb[li];
    int tk = li / 96, c2 = li % 96;
    tile[tk][2*c2]   = bf2f((unsigned short)(u & 0xffffu));
    tile[tk][2*c2+1] = bf2f((unsigned short)(u >> 16));
  }
  __syncthreads();
  const float* xb = x + (size_t)b*C_*N_ + n0;
  float sum = 0.f, sq = 0.f;
#pragma unroll
  for (int i = 0; i < 48; ++i){
    int c = q + 4*i;
    float v = xb[(size_t)c*N_ + tok] + tile[tok][c];
    tile[tok][c] = v;
    sum += v; sq += v*v;
  }
  red[q][tok] = sum; red[4+q][tok] = sq;
  __syncthreads();
  if (q == 0){
    float s  = red[0][tok]+red[1][tok]+red[2][tok]+red[3][tok];
    float s2 = red[4][tok]+red[5][tok]+red[6][tok]+red[7][tok];
    float mu = s*(1.f/C_);
    float rstd = rsqrtf(s2*(1.f/C_) - mu*mu + 1e-5f);
    red[0][tok] = mu; red[1][tok] = rstd;
  }
  __syncthreads();
  float* ob = ln2t + (size_t)b*C_*N_ + n0;
  float mu = red[0][tok], rstd = red[1][tok];
#pragma unroll
  for (int i = 0; i < 48; ++i){
    int c = q + 4*i;
    ob[(size_t)c*N_ + tok] = (tile[tok][c]-mu)*rstd*wls[c] + bls[c];
  }
}

// ------- fc1 MFMA: block = 128-token m-tile x 384-hid half, loop 6 n-tiles -------
__global__ __launch_bounds__(256) void k_fc1(const float* __restrict__ ln2t,
    const float* __restrict__ wgt, const float* __restrict__ bias,
    unsigned short* __restrict__ h1, int b_off){
  int bid = blockIdx.x;
  int bl  = bid >> 8;                  // slot-local batch
  int rem = bid & 255;
  int m0  = (rem >> 1) * 128;
  int nh  = (rem & 1) * 6;             // n-tile half
  int t = threadIdx.x, lane = t & 63;
  int wv = t >> 6, wm = wv & 1, wn = wv >> 1;
  int l15 = lane & 15, lhi = lane >> 4;
  __shared__ unsigned short Al[128][200];
  __shared__ unsigned short Bl[64][200];
  const float* a = ln2t + (size_t)(b_off+bl)*C_*N_ + m0;
  unsigned short* hb = h1 + (size_t)bl*HID_*N_;
  {
    int m = t & 127, half = t >> 7;
#pragma unroll
    for (int i = 0; i < 48; ++i){
      int p = half + 2*i;                    // 0..95
      float v0 = a[(size_t)(2*p)*N_ + m];
      float v1 = a[(size_t)(2*p+1)*N_ + m];
      *reinterpret_cast<unsigned*>(&Al[m][2*p]) = cvtpk(v0, v1);
    }
  }
  for (int nt = 0; nt < 6; ++nt){
    int n0 = (nh + nt)*64;
    __syncthreads();
    {
      int n = t >> 2;
      const float* bsrc = wgt + (size_t)(n0+n)*C_;
#pragma unroll
      for (int i = 0; i < 12; ++i){
        int q = (t & 3) + 4*i;               // 0..47 float4 segs
        float4 v = *reinterpret_cast<const float4*>(bsrc + 4*q);
        *reinterpret_cast<uint2*>(&Bl[n][4*q]) =
            make_uint2(cvtpk(v.x, v.y), cvtpk(v.z, v.w));
      }
    }
    __syncthreads();
    f32x4 acc[4][2] = {};
#pragma unroll
    for (int ks = 0; ks < 6; ++ks){
      bf16x8 af[4], bfr[2];
#pragma unroll
      for (int mf = 0; mf < 4; ++mf)
        af[mf] = *reinterpret_cast<const bf16x8*>(&Al[wm*64 + mf*16 + l15][ks*32 + lhi*8]);
#pragma unroll
      for (int nf = 0; nf < 2; ++nf)
        bfr[nf] = *reinterpret_cast<const bf16x8*>(&Bl[wn*32 + nf*16 + l15][ks*32 + lhi*8]);
#pragma unroll
      for (int mf = 0; mf < 4; ++mf)
#pragma unroll
        for (int nf = 0; nf < 2; ++nf)
          acc[mf][nf] = __builtin_amdgcn_mfma_f32_16x16x32_bf16(af[mf], bfr[nf], acc[mf][nf], 0,0,0);
    }
#pragma unroll
    for (int mf = 0; mf < 4; ++mf){
      int mb = m0 + wm*64 + mf*16 + lhi*4;
#pragma unroll
      for (int nf = 0; nf < 2; ++nf){
        int n = n0 + wn*32 + nf*16 + l15;
        float bv = bias[n];
        uint2 pk;
        pk.x = cvtpk(acc[mf][nf][0] + bv, acc[mf][nf][1] + bv);
        pk.y = cvtpk(acc[mf][nf][2] + bv, acc[mf][nf][3] + bv);
        *reinterpret_cast<uint2*>(&hb[(size_t)n*N_ + mb]) = pk;
      }
    }
  }
}

// ------- fused depthwise3x3+GELU+fc2+residual: block = 1 image row x 192 ch -------
// 512 thr, 51.7KB LDS; single Ht buffer, 2 barriers/chunk, reg-prefetched h1
__global__ __launch_bounds__(512) void k_fc2f(const unsigned short* __restrict__ h1,
    const float* __restrict__ dw, const float* __restrict__ wgt,
    const float* __restrict__ bias, float* __restrict__ out, int b_off){
  int nwg = gridDim.x;
  int cpx = nwg >> 3;
  int bid = (blockIdx.x & 7)*cpx + (blockIdx.x >> 3);  // contiguous rows per XCD
  int bl  = bid >> 7;            // slot-local batch
  int r   = bid & 127;           // image row
  int b   = b_off + bl;
  int t = threadIdx.x, lane = t & 63, wv = t >> 6;
  int wm = wv & 1, wn = wv >> 1;
  int l15 = lane & 15, lhi = lane >> 4;
  __shared__ unsigned short Ht[32][3][136];     // 26.1KB; ch-stride 816B (51x16B)
  __shared__ unsigned short Alc[128][40];       // 10.2KB
  __shared__ unsigned short Bl[192][40];        // 15.4KB
  const unsigned short* h1b = h1 + (size_t)bl*HID_*N_;
  f32x4 acc[4][3] = {};
  int cch = t & 31, j0 = (t >> 5) * 8;          // conv: channel, col base
  // ---- hoisted per-thread staging state ----
  const unsigned short* gp[3]; unsigned short* lp[3]; bool gok[3];
#pragma unroll
  for (int i = 0; i < 3; ++i){
    int li = t + 512*i;                         // 0..1535
    int ch = li / 48, rm = li % 48, dy = rm >> 4, seg = rm & 15;
    int rr = r - 1 + dy;
    gok[i] = (rr >= 0 && rr < H_);
    gp[i] = h1b + (size_t)ch*N_ + (gok[i] ? rr : 0)*W_ + seg*8;
    lp[i] = &Ht[ch][dy][seg*8];
  }
  const float* wgp[3]; unsigned short* blp[3];
#pragma unroll
  for (int i = 0; i < 3; ++i){
    int row = (t >> 3) + 64*i, seg = t & 7;
    wgp[i] = wgt + (size_t)row*HID_ + seg*4;
    blp[i] = &Bl[row][seg*4];
  }
  const float* dwp = dw + (size_t)cch*9;        // advance +288 per chunk
  uint4 hr[3];
  auto hload = [&](){
#pragma unroll
    for (int i = 0; i < 3; ++i)
      hr[i] = gok[i] ? *reinterpret_cast<const uint4*>(gp[i]) : make_uint4(0u,0u,0u,0u);
#pragma unroll
    for (int i = 0; i < 3; ++i) gp[i] += 32*N_;
  };
  // prologue: chunk 0 into Ht, prefetch chunk 1 into regs
  hload();
#pragma unroll
  for (int i = 0; i < 3; ++i) *reinterpret_cast<uint4*>(lp[i]) = hr[i];
  hload();
  for (int c24 = 0; c24 < 24; ++c24){
    __syncthreads();                  // A: Ht(c) visible; prev MFMA done
    // stage Bl direct from global (L2-hot weights)
#pragma unroll
    for (int i = 0; i < 3; ++i){
      float4 v = *reinterpret_cast<const float4*>(wgp[i]);
      wgp[i] += 32;
      *reinterpret_cast<uint2*>(blp[i]) =
          make_uint2(cvtpk(v.x, v.y), cvtpk(v.z, v.w));
    }
    // conv 3x3 + fast GELU from Ht -> Alc; dw direct (broadcast-hot)
    {
      float w9[9];
#pragma unroll
      for (int i = 0; i < 9; ++i) w9[i] = dwp[i];
      dwp += 288;
      const unsigned short* hp = &Ht[cch][0][j0];
      float s[8] = {0.f,0.f,0.f,0.f,0.f,0.f,0.f,0.f};
#pragma unroll
      for (int dy = 0; dy < 3; ++dy){
        const unsigned short* rp = hp + dy*136;
        bf16x8 mid = *reinterpret_cast<const bf16x8*>(rp);
        float v[10];
        v[0] = (j0 > 0)   ? bf2f(rp[-1]) : 0.f;
        v[9] = (j0 < 120) ? bf2f(rp[8])  : 0.f;
#pragma unroll
        for (int j = 0; j < 8; ++j) v[1+j] = bf2f((unsigned short)mid[j]);
        float wa = w9[3*dy], wb = w9[3*dy+1], wc = w9[3*dy+2];
#pragma unroll
        for (int j = 0; j < 8; ++j)
          s[j] += v[j]*wa + v[j+1]*wb + v[j+2]*wc;
      }
#pragma unroll
      for (int j = 0; j < 8; ++j)
        Alc[j0+j][cch] = f2bf(gelu_fast(s[j]));
    }
    __syncthreads();                  // B: Alc+Bl visible; Ht reads complete
    // write prefetched chunk c+1 into Ht (dead now); prefetch c+2
    if (c24 < 23){
#pragma unroll
      for (int i = 0; i < 3; ++i)
        *reinterpret_cast<uint4*>(lp[i]) = hr[i];
      if (c24 < 22) hload();
    }
    // MFMA: wave = 64-tok half (wm) x 48-ch quarter (wn)
    bf16x8 af[4], bfr[3];
#pragma unroll
    for (int mf = 0; mf < 4; ++mf)
      af[mf] = *reinterpret_cast<const bf16x8*>(&Alc[wm*64 + mf*16 + l15][lhi*8]);
#pragma unroll
    for (int nf = 0; nf < 3; ++nf)
      bfr[nf] = *reinterpret_cast<const bf16x8*>(&Bl[wn*48 + nf*16 + l15][lhi*8]);
    __builtin_amdgcn_s_setprio(1);
#pragma unroll
    for (int mf = 0; mf < 4; ++mf)
#pragma unroll
      for (int nf = 0; nf < 3; ++nf)
        acc[mf][nf] = __builtin_amdgcn_mfma_f32_16x16x32_bf16(af[mf], bfr[nf], acc[mf][nf], 0,0,0);
    __builtin_amdgcn_s_setprio(0);
  }
  // epilogue: += bias + residual (out holds ln2t)
#pragma unroll
  for (int mf = 0; mf < 4; ++mf){
    int tok = r*W_ + wm*64 + mf*16 + lhi*4;
#pragma unroll
    for (int nf = 0; nf < 3; ++nf){
      int oc = wn*48 + nf*16 + l15;
      float bv = bias[oc];
      size_t off = ((size_t)b*C_ + oc)*N_ + tok;
      float4 rr = *reinterpret_cast<const float4*>(out + off);
      float4 v = make_float4(rr.x + acc[mf][nf][0] + bv, rr.y + acc[mf][nf][1] + bv,
                             rr.z + acc[mf][nf][2] + bv, rr.w + acc[mf][nf][3] + bv);
      *reinterpret_cast<float4*>(out + off) = v;
    }
  }
}

extern "C" void kernel_launch(void* const* d_in, const int* in_sizes, int n_in,
                              void* d_out, int out_size, void* d_ws, size_t ws_size,
                              hipStream_t stream) {
  const float*    x      = (const float*)d_in[0];
  const unsigned* idx    = (const unsigned*)d_in[1];
  const float*    ln1_w  = (const float*)d_in[2];
  const float*    ln1_b  = (const float*)d_in[3];
  const float*    qkv_w  = (const float*)d_in[4];
  const float*    proj_w = (const float*)d_in[5];
  const float*    proj_b = (const float*)d_in[6];
  const float*    ln2_w  = (const float*)d_in[7];
  const float*    ln2_b  = (const float*)d_in[8];
  const float*    fc1_w  = (const float*)d_in[9];
  const float*    fc1_b  = (const float*)d_in[10];
  const float*    dw_w   = (const float*)d_in[11];
  const float*    fc2_w  = (const float*)d_in[12];
  const float*    fc2_b  = (const float*)d_in[13];
  float* out = (float*)d_out;          // doubles as ln2t (B,C,N) f32

  const size_t SZY = (size_t)N_*C_*2;              // y bf16: 6.29 MB/batch
  const size_t SZQ = (size_t)K_*3*C_*2;            // 2.36
  const size_t SZA = (size_t)K_*C_*2;              // 0.79
  const size_t SZO = (size_t)NC_*HEADS_*K_*HD_*4;  // 12.58/batch
  const size_t SZH = (size_t)HID_*N_*2;            // 25.17/batch
  int nb = (ws_size >= (size_t)B_*SZH) ? B_ : 1;   // deterministic

  char* ws = (char*)d_ws;
  unsigned short* y16  = (unsigned short*)ws;
  unsigned short* qkvb = (unsigned short*)(ws + (size_t)nb*SZY);
  unsigned short* aob  = (unsigned short*)(ws + (size_t)nb*(SZY+SZQ));
  float*          po   = (float*)(ws + (size_t)nb*(SZY+SZQ+SZA));
  float*          pml  = (float*)(ws + (size_t)nb*(SZY+SZQ+SZA+SZO));
  unsigned short* h1s  = (unsigned short*)ws;      // MLP phase (front dead): nb slots

  for (int b0 = 0; b0 < B_; b0 += nb){
    k_ln1   <<<nb*256,             256, 0, stream>>>(x, ln1_w, ln1_b, y16, b0);
    k_qkv   <<<nb*16*9,            256, 0, stream>>>(y16, idx, qkv_w, qkvb, b0);
    k_attn  <<<nb*HEADS_*32*NC_,   256, 0, stream>>>(qkvb, po, pml, nb);
    k_amerge<<<nb*HEADS_*K_/4,     256, 0, stream>>>(po, pml, aob, nb);
    k_proj  <<<nb*16*3,            256, 0, stream>>>(aob, idx, proj_w, proj_b, y16, b0);
    k_ln2   <<<nb*256,             256, 0, stream>>>(x, y16, ln2_w, ln2_b, out, b0);
    k_fc1   <<<nb*256,             256, 0, stream>>>(out, fc1_w, fc1_b, h1s, b0);
    k_fc2f  <<<nb*128,             512, 0, stream>>>(h1s, dw_w, fc2_w, fc2_b, out, b0);
  }
}

// Round 20
// 238.299 us; speedup vs baseline: 1.1598x; 1.0232x over previous
//
#include <hip/hip_runtime.h>

#define B_ 4
#define C_ 192
#define H_ 128
#define W_ 128
#define N_ (H_*W_)      // 16384
#define K_ 2048
#define HEADS_ 3
#define HD_ 64
#define HID_ 768
#define NC_ 4           // attention split-K chunks
#define KC_ (K_/NC_)    // 512

typedef __attribute__((ext_vector_type(4))) float f32x4;
typedef __attribute__((ext_vector_type(8))) short bf16x8;

__device__ __forceinline__ unsigned short f2bf(float f){
  unsigned int u = __float_as_uint(f);
  u += 0x7FFFu + ((u >> 16) & 1u);
  return (unsigned short)(u >> 16);
}
__device__ __forceinline__ float bf2f(unsigned short s){
  return __uint_as_float(((unsigned int)s) << 16);
}
__device__ __forceinline__ unsigned cvtpk(float lo, float hi){
  unsigned r;
  asm("v_cvt_pk_bf16_f32 %0, %1, %2" : "=v"(r) : "v"(lo), "v"(hi));
  return r;
}
// sigmoid-form GELU: x * sigma(1.702x); ~5 VALU via HW rcp. |err| <= ~0.02
__device__ __forceinline__ float gelu_fast(float x){
  float e = __expf(-1.702f*x);
  return x * __builtin_amdgcn_rcpf(1.f + e);
}

__device__ __forceinline__ int load_idx(const unsigned* __restrict__ ip, int pos){
  bool is64 = (ip[1]==0u) & (ip[3]==0u) & (ip[5]==0u) & (ip[7]==0u);
  int v = is64 ? (int)ip[2*pos] : (int)ip[pos];
  return min(max(v, 0), N_-1);
}

// ---------------- LN1: x (B,C,N) -> y bf16 (nb,N,C) ----------------
__global__ __launch_bounds__(256) void k_ln1(const float* __restrict__ x,
    const float* __restrict__ w, const float* __restrict__ bias,
    unsigned short* __restrict__ y, int b_off){
  int blk = blockIdx.x;
  int bl = blk >> 8;
  int b  = b_off + bl;
  int n0 = (blk & 255) * 64;
  int t  = threadIdx.x;
  int tok = t & 63, q = t >> 6;
  __shared__ float tile[64][C_+1];
  __shared__ float red[8][64];
  __shared__ float wls[C_], bls[C_];
  if (t < C_){ wls[t] = w[t]; bls[t] = bias[t]; }
  const float* xb = x + (size_t)b*C_*N_ + n0;
  float sum = 0.f, sq = 0.f;
#pragma unroll
  for (int i = 0; i < 48; ++i){
    int c = q + 4*i;
    float v = xb[(size_t)c*N_ + tok];
    tile[tok][c] = v;
    sum += v; sq += v*v;
  }
  red[q][tok] = sum; red[4+q][tok] = sq;
  __syncthreads();
  if (q == 0){
    float s  = red[0][tok]+red[1][tok]+red[2][tok]+red[3][tok];
    float s2 = red[4][tok]+red[5][tok]+red[6][tok]+red[7][tok];
    float mu = s*(1.f/C_);
    float rstd = rsqrtf(s2*(1.f/C_) - mu*mu + 1e-5f);
    red[0][tok] = mu; red[1][tok] = rstd;
  }
  __syncthreads();
  unsigned* yb = reinterpret_cast<unsigned*>(y + ((size_t)bl*N_ + n0)*C_);
#pragma unroll
  for (int i = 0; i < 24; ++i){
    int li = t + 256*i;                 // 6144 u32
    int tk = li / 96, c2 = li % 96;
    int c = 2*c2;
    float v0 = (tile[tk][c]  -red[0][tk])*red[1][tk]*wls[c]   + bls[c];
    float v1 = (tile[tk][c+1]-red[0][tk])*red[1][tk]*wls[c+1] + bls[c+1];
    yb[li] = cvtpk(v0, v1);
  }
}

// ---------------- QKV MFMA GEMM with gather: y bf16 -> qkv bf16 ----------------
__global__ __launch_bounds__(256) void k_qkv(const unsigned short* __restrict__ y,
    const unsigned* __restrict__ idx, const float* __restrict__ wq,
    unsigned short* __restrict__ qkv, int b_off){
  const int NT = (3*C_)/64;  // 9
  int bid = blockIdx.x;
  int bl  = bid / (16*NT);
  int rem = bid % (16*NT);
  int m0  = (rem / NT) * 128;
  int n0  = (rem % NT) * 64;
  int t = threadIdx.x, lane = t & 63;
  int wv = t >> 6, wm = wv & 1, wn = wv >> 1;
  __shared__ unsigned short Al[128][40];
  __shared__ unsigned short Bl[64][40];
  __shared__ int rows[128];
  if (t < 128) rows[t] = load_idx(idx, (b_off+bl)*K_ + m0 + t);
  __syncthreads();
  f32x4 acc[4][2] = {};
  int l15 = lane & 15, lhi = lane >> 4;
  for (int k0 = 0; k0 < C_; k0 += 32){
    {
      int m = t >> 1;
      const unsigned short* src = y + ((size_t)bl*N_ + rows[m])*C_ + k0;
#pragma unroll
      for (int i = 0; i < 4; ++i){
        int kq = (t & 1) + 2*i;
        *reinterpret_cast<ushort4*>(&Al[m][4*kq]) =
            *reinterpret_cast<const ushort4*>(src + 4*kq);
      }
      int n = t >> 2;
      const float* bsrc = wq + (size_t)(n0+n)*C_ + k0;
#pragma unroll
      for (int i = 0; i < 2; ++i){
        int q = (t & 3) + 4*i;
        float4 v = *reinterpret_cast<const float4*>(bsrc + 4*q);
        *reinterpret_cast<uint2*>(&Bl[n][4*q]) =
            make_uint2(cvtpk(v.x, v.y), cvtpk(v.z, v.w));
      }
    }
    __syncthreads();
    bf16x8 af[4], bfr[2];
#pragma unroll
    for (int mf = 0; mf < 4; ++mf)
      af[mf] = *reinterpret_cast<const bf16x8*>(&Al[wm*64 + mf*16 + l15][lhi*8]);
#pragma unroll
    for (int nf = 0; nf < 2; ++nf)
      bfr[nf] = *reinterpret_cast<const bf16x8*>(&Bl[wn*32 + nf*16 + l15][lhi*8]);
#pragma unroll
    for (int mf = 0; mf < 4; ++mf)
#pragma unroll
      for (int nf = 0; nf < 2; ++nf)
        acc[mf][nf] = __builtin_amdgcn_mfma_f32_16x16x32_bf16(af[mf], bfr[nf], acc[mf][nf], 0,0,0);
    __syncthreads();
  }
#pragma unroll
  for (int mf = 0; mf < 4; ++mf){
    int mb = m0 + wm*64 + mf*16 + lhi*4;
#pragma unroll
    for (int nf = 0; nf < 2; ++nf){
      int n = n0 + wn*32 + nf*16 + l15;
#pragma unroll
      for (int r = 0; r < 4; ++r)
        qkv[((size_t)bl*K_ + mb + r)*(3*C_) + n] = f2bf(acc[mf][nf][r]);
    }
  }
}

// ------- attention split-K (NC=4), swapped QK^T, defer-max, cvt_pk -------
__global__ __launch_bounds__(256) void k_attn(const unsigned short* __restrict__ qkv,
    float* __restrict__ po, float* __restrict__ pml, int nb){
  int bid = blockIdx.x;
  int c   = bid & (NC_-1);
  int qt  = (bid >> 2) & 31;
  int bh  = bid >> 7;
  int h = bh % HEADS_, bl = bh / HEADS_;
  int q0 = qt*64;
  int t = threadIdx.x, lane = t & 63, wv = t >> 6;
  int l15 = lane & 15, lhi = lane >> 4;
  const unsigned short* base = qkv + (size_t)bl*K_*(3*C_) + h*HD_;
  __shared__ unsigned short Ql[64][72];
  __shared__ unsigned short Kl[64][72];
  __shared__ unsigned short Vt[64][72];
  __shared__ unsigned short Pl[4][16][72];
  {
    int r = t >> 2, d0 = (t & 3) * 16;
    const uint4* src = reinterpret_cast<const uint4*>(base + (size_t)(q0+r)*(3*C_) + d0);
    *reinterpret_cast<uint4*>(&Ql[r][d0])   = src[0];
    *reinterpret_cast<uint4*>(&Ql[r][d0+8]) = src[1];
  }
  __syncthreads();
  float m_q = -1e30f, l_q = 0.f;
  f32x4 o[4] = {};
  for (int kt0 = c*KC_; kt0 < c*KC_ + KC_; kt0 += 64){
    {
      int r = t >> 2, d0 = (t & 3) * 16;
      const uint4* src = reinterpret_cast<const uint4*>(base + (size_t)(kt0+r)*(3*C_) + C_ + d0);
      *reinterpret_cast<uint4*>(&Kl[r][d0])   = src[0];
      *reinterpret_cast<uint4*>(&Kl[r][d0+8]) = src[1];
      int kp = t & 31, vd0 = (t >> 5) * 8, k = 2*kp;
      const ushort4* v0 = reinterpret_cast<const ushort4*>(base + (size_t)(kt0+k)*(3*C_)   + 2*C_ + vd0);
      const ushort4* v1 = reinterpret_cast<const ushort4*>(base + (size_t)(kt0+k+1)*(3*C_) + 2*C_ + vd0);
      ushort4 a0 = v0[0], a1 = v0[1], b0 = v1[0], b1 = v1[1];
      unsigned short va[8] = {a0.x,a0.y,a0.z,a0.w,a1.x,a1.y,a1.z,a1.w};
      unsigned short vb[8] = {b0.x,b0.y,b0.z,b0.w,b1.x,b1.y,b1.z,b1.w};
#pragma unroll
      for (int j = 0; j < 8; ++j){
        unsigned u = (unsigned)va[j] | ((unsigned)vb[j] << 16);
        *reinterpret_cast<unsigned*>(&Vt[vd0+j][k]) = u;
      }
    }
    __syncthreads();
    f32x4 s[4] = {};
    __builtin_amdgcn_s_setprio(1);
#pragma unroll
    for (int kt = 0; kt < 2; ++kt){
      bf16x8 qf = *reinterpret_cast<const bf16x8*>(&Ql[wv*16 + l15][kt*32 + lhi*8]);
#pragma unroll
      for (int nt = 0; nt < 4; ++nt){
        bf16x8 kf = *reinterpret_cast<const bf16x8*>(&Kl[nt*16 + l15][kt*32 + lhi*8]);
        s[nt] = __builtin_amdgcn_mfma_f32_16x16x32_bf16(kf, qf, s[nt], 0,0,0);
      }
    }
    __builtin_amdgcn_s_setprio(0);
    float mx = s[0][0];
#pragma unroll
    for (int nt = 0; nt < 4; ++nt)
#pragma unroll
      for (int reg = 0; reg < 4; ++reg) mx = fmaxf(mx, s[nt][reg]);
    mx = fmaxf(mx, __shfl_xor(mx, 16));
    mx = fmaxf(mx, __shfl_xor(mx, 32));
    mx *= 0.125f;
    bool skip = __all(mx <= m_q + 8.f);
    if (!skip){
      float mn = fmaxf(m_q, mx);
      float corr = __expf(m_q - mn);
      l_q *= corr;
      float cr[4];
#pragma unroll
      for (int reg = 0; reg < 4; ++reg) cr[reg] = __shfl(corr, lhi*4 + reg);
#pragma unroll
      for (int nt = 0; nt < 4; ++nt)
#pragma unroll
        for (int reg = 0; reg < 4; ++reg) o[nt][reg] *= cr[reg];
      m_q = mn;
    }
    float ls = 0.f;
#pragma unroll
    for (int nt = 0; nt < 4; ++nt){
      float p0 = __expf(fmaf(s[nt][0], 0.125f, -m_q));
      float p1 = __expf(fmaf(s[nt][1], 0.125f, -m_q));
      float p2 = __expf(fmaf(s[nt][2], 0.125f, -m_q));
      float p3 = __expf(fmaf(s[nt][3], 0.125f, -m_q));
      ls += (p0 + p1) + (p2 + p3);
      uint2 uu;
      uu.x = cvtpk(p0, p1);
      uu.y = cvtpk(p2, p3);
      *reinterpret_cast<uint2*>(&Pl[wv][l15][nt*16 + lhi*4]) = uu;
    }
    ls += __shfl_xor(ls, 16);
    ls += __shfl_xor(ls, 32);
    l_q += ls;
    __threadfence_block();
    __builtin_amdgcn_s_setprio(1);
#pragma unroll
    for (int kt = 0; kt < 2; ++kt){
      bf16x8 pa = *reinterpret_cast<const bf16x8*>(&Pl[wv][l15][kt*32 + lhi*8]);
#pragma unroll
      for (int nt = 0; nt < 4; ++nt){
        bf16x8 vb = *reinterpret_cast<const bf16x8*>(&Vt[nt*16 + l15][kt*32 + lhi*8]);
        o[nt] = __builtin_amdgcn_mfma_f32_16x16x32_bf16(pa, vb, o[nt], 0,0,0);
      }
    }
    __builtin_amdgcn_s_setprio(0);
    __syncthreads();
  }
  int R = nb*HEADS_*K_;
  int rowb = (bl*HEADS_ + h)*K_;
#pragma unroll
  for (int reg = 0; reg < 4; ++reg){
    int rq = rowb + q0 + wv*16 + lhi*4 + reg;
#pragma unroll
    for (int nt = 0; nt < 4; ++nt)
      po[((size_t)c*R + rq)*HD_ + nt*16 + l15] = o[nt][reg];
  }
  if (lhi == 0){
    int rq = rowb + q0 + wv*16 + l15;
    *reinterpret_cast<float2*>(pml + 2*((size_t)c*R + rq)) = make_float2(m_q, l_q);
  }
}

// ---------------- merge split-K partials -> ao bf16 (bl,K,C) ----------------
__global__ __launch_bounds__(256) void k_amerge(const float* __restrict__ po,
    const float* __restrict__ pml, unsigned short* __restrict__ ao, int nb){
  int R = nb*HEADS_*K_;
  int row = blockIdx.x*4 + (threadIdx.x >> 6);
  int lane = threadIdx.x & 63;
  float m[NC_], l[NC_];
#pragma unroll
  for (int cc = 0; cc < NC_; ++cc){
    float2 v = *reinterpret_cast<const float2*>(pml + 2*((size_t)cc*R + row));
    m[cc] = v.x; l[cc] = v.y;
  }
  float M = m[0];
#pragma unroll
  for (int cc = 1; cc < NC_; ++cc) M = fmaxf(M, m[cc]);
  float L = 0.f, o = 0.f;
#pragma unroll
  for (int cc = 0; cc < NC_; ++cc){
    float e = __expf(m[cc] - M);
    L += l[cc]*e;
    o += e * po[((size_t)cc*R + row)*HD_ + lane];
  }
  o /= L;
  int q = row & (K_-1);
  int bh = row >> 11;
  int h = bh % HEADS_, bl = bh / HEADS_;
  ao[((size_t)bl*K_ + q)*C_ + h*HD_ + lane] = f2bf(o);
}

// ---------------- proj MFMA GEMM + scatter into y (bf16) ----------------
__global__ __launch_bounds__(256) void k_proj(const unsigned short* __restrict__ ain,
    const unsigned* __restrict__ idx, const float* __restrict__ pw,
    const float* __restrict__ pb, unsigned short* __restrict__ y, int b_off){
  const int NT = C_/64;   // 3
  int bid = blockIdx.x;
  int bl  = bid / (16*NT);
  int rem = bid % (16*NT);
  int m0  = (rem / NT) * 128;
  int n0  = (rem % NT) * 64;
  int t = threadIdx.x, lane = t & 63;
  int wv = t >> 6, wm = wv & 1, wn = wv >> 1;
  __shared__ unsigned short Al[128][40];
  __shared__ unsigned short Bl[64][40];
  __shared__ int rows[128];
  if (t < 128) rows[t] = load_idx(idx, (b_off+bl)*K_ + m0 + t);
  __syncthreads();
  f32x4 acc[4][2] = {};
  int l15 = lane & 15, lhi = lane >> 4;
  for (int k0 = 0; k0 < C_; k0 += 32){
    {
      int m = t >> 1;
      const unsigned short* src = ain + ((size_t)bl*K_ + m0 + m)*C_ + k0;
#pragma unroll
      for (int i = 0; i < 4; ++i){
        int kq = (t & 1) + 2*i;
        *reinterpret_cast<ushort4*>(&Al[m][4*kq]) =
            *reinterpret_cast<const ushort4*>(src + 4*kq);
      }
      int n = t >> 2;
      const float* bsrc = pw + (size_t)(n0+n)*C_ + k0;
#pragma unroll
      for (int i = 0; i < 2; ++i){
        int q = (t & 3) + 4*i;
        float4 v = *reinterpret_cast<const float4*>(bsrc + 4*q);
        *reinterpret_cast<uint2*>(&Bl[n][4*q]) =
            make_uint2(cvtpk(v.x, v.y), cvtpk(v.z, v.w));
      }
    }
    __syncthreads();
    bf16x8 af[4], bfr[2];
#pragma unroll
    for (int mf = 0; mf < 4; ++mf)
      af[mf] = *reinterpret_cast<const bf16x8*>(&Al[wm*64 + mf*16 + l15][lhi*8]);
#pragma unroll
    for (int nf = 0; nf < 2; ++nf)
      bfr[nf] = *reinterpret_cast<const bf16x8*>(&Bl[wn*32 + nf*16 + l15][lhi*8]);
#pragma unroll
    for (int mf = 0; mf < 4; ++mf)
#pragma unroll
      for (int nf = 0; nf < 2; ++nf)
        acc[mf][nf] = __builtin_amdgcn_mfma_f32_16x16x32_bf16(af[mf], bfr[nf], acc[mf][nf], 0,0,0);
    __syncthreads();
  }
#pragma unroll
  for (int mf = 0; mf < 4; ++mf){
    int mb = wm*64 + mf*16 + lhi*4;
#pragma unroll
    for (int nf = 0; nf < 2; ++nf){
      int n = n0 + wn*32 + nf*16 + l15;
      float bv = pb[n];
#pragma unroll
      for (int r = 0; r < 4; ++r)
        y[((size_t)bl*N_ + rows[mb + r])*C_ + n] = f2bf(acc[mf][nf][r] + bv);
    }
  }
}

// ---------------- residual + LN2 -> ln2t (B,C,N) [== d_out] ----------------
__global__ __launch_bounds__(256) void k_ln2(const float* __restrict__ x,
    const unsigned short* __restrict__ y, const float* __restrict__ w,
    const float* __restrict__ bias, float* __restrict__ ln2t, int b_off){
  int blk = blockIdx.x;
  int bl = blk >> 8;
  int b  = b_off + bl;
  int n0 = (blk & 255) * 64;
  int t  = threadIdx.x;
  int tok = t & 63, q = t >> 6;
  __shared__ float tile[64][C_+1];
  __shared__ float red[8][64];
  __shared__ float wls[C_], bls[C_];
  if (t < C_){ wls[t] = w[t]; bls[t] = bias[t]; }
  const unsigned* yb = reinterpret_cast<const unsigned*>(y + ((size_t)bl*N_ + n0)*C_);
#pragma unroll
  for (int i = 0; i < 24; ++i){
    int li = t + 256*i;
    unsigned u = yb[li];
    int tk = li / 96, c2 = li % 96;
    tile[tk][2*c2]   = bf2f((unsigned short)(u & 0xffffu));
    tile[tk][2*c2+1] = bf2f((unsigned short)(u >> 16));
  }
  __syncthreads();
  const float* xb = x + (size_t)b*C_*N_ + n0;
  float sum = 0.f, sq = 0.f;
#pragma unroll
  for (int i = 0; i < 48; ++i){
    int c = q + 4*i;
    float v = xb[(size_t)c*N_ + tok] + tile[tok][c];
    tile[tok][c] = v;
    sum += v; sq += v*v;
  }
  red[q][tok] = sum; red[4+q][tok] = sq;
  __syncthreads();
  if (q == 0){
    float s  = red[0][tok]+red[1][tok]+red[2][tok]+red[3][tok];
    float s2 = red[4][tok]+red[5][tok]+red[6][tok]+red[7][tok];
    float mu = s*(1.f/C_);
    float rstd = rsqrtf(s2*(1.f/C_) - mu*mu + 1e-5f);
    red[0][tok] = mu; red[1][tok] = rstd;
  }
  __syncthreads();
  float* ob = ln2t + (size_t)b*C_*N_ + n0;
  float mu = red[0][tok], rstd = red[1][tok];
#pragma unroll
  for (int i = 0; i < 48; ++i){
    int c = q + 4*i;
    ob[(size_t)c*N_ + tok] = (tile[tok][c]-mu)*rstd*wls[c] + bls[c];
  }
}

// ------- fc1 MFMA: block = 128-token m-tile x 384-hid half, loop 6 n-tiles -------
__global__ __launch_bounds__(256) void k_fc1(const float* __restrict__ ln2t,
    const float* __restrict__ wgt, const float* __restrict__ bias,
    unsigned short* __restrict__ h1, int b_off){
  int bid = blockIdx.x;
  int bl  = bid >> 8;                  // slot-local batch
  int rem = bid & 255;
  int m0  = (rem >> 1) * 128;
  int nh  = (rem & 1) * 6;             // n-tile half
  int t = threadIdx.x, lane = t & 63;
  int wv = t >> 6, wm = wv & 1, wn = wv >> 1;
  int l15 = lane & 15, lhi = lane >> 4;
  __shared__ unsigned short Al[128][200];
  __shared__ unsigned short Bl[64][200];
  const float* a = ln2t + (size_t)(b_off+bl)*C_*N_ + m0;
  unsigned short* hb = h1 + (size_t)bl*HID_*N_;
  {
    int m = t & 127, half = t >> 7;
#pragma unroll
    for (int i = 0; i < 48; ++i){
      int p = half + 2*i;                    // 0..95
      float v0 = a[(size_t)(2*p)*N_ + m];
      float v1 = a[(size_t)(2*p+1)*N_ + m];
      *reinterpret_cast<unsigned*>(&Al[m][2*p]) = cvtpk(v0, v1);
    }
  }
  for (int nt = 0; nt < 6; ++nt){
    int n0 = (nh + nt)*64;
    __syncthreads();
    {
      int n = t >> 2;
      const float* bsrc = wgt + (size_t)(n0+n)*C_;
#pragma unroll
      for (int i = 0; i < 12; ++i){
        int q = (t & 3) + 4*i;               // 0..47 float4 segs
        float4 v = *reinterpret_cast<const float4*>(bsrc + 4*q);
        *reinterpret_cast<uint2*>(&Bl[n][4*q]) =
            make_uint2(cvtpk(v.x, v.y), cvtpk(v.z, v.w));
      }
    }
    __syncthreads();
    f32x4 acc[4][2] = {};
#pragma unroll
    for (int ks = 0; ks < 6; ++ks){
      bf16x8 af[4], bfr[2];
#pragma unroll
      for (int mf = 0; mf < 4; ++mf)
        af[mf] = *reinterpret_cast<const bf16x8*>(&Al[wm*64 + mf*16 + l15][ks*32 + lhi*8]);
#pragma unroll
      for (int nf = 0; nf < 2; ++nf)
        bfr[nf] = *reinterpret_cast<const bf16x8*>(&Bl[wn*32 + nf*16 + l15][ks*32 + lhi*8]);
#pragma unroll
      for (int mf = 0; mf < 4; ++mf)
#pragma unroll
        for (int nf = 0; nf < 2; ++nf)
          acc[mf][nf] = __builtin_amdgcn_mfma_f32_16x16x32_bf16(af[mf], bfr[nf], acc[mf][nf], 0,0,0);
    }
#pragma unroll
    for (int mf = 0; mf < 4; ++mf){
      int mb = m0 + wm*64 + mf*16 + lhi*4;
#pragma unroll
      for (int nf = 0; nf < 2; ++nf){
        int n = n0 + wn*32 + nf*16 + l15;
        float bv = bias[n];
        uint2 pk;
        pk.x = cvtpk(acc[mf][nf][0] + bv, acc[mf][nf][1] + bv);
        pk.y = cvtpk(acc[mf][nf][2] + bv, acc[mf][nf][3] + bv);
        *reinterpret_cast<uint2*>(&hb[(size_t)n*N_ + mb]) = pk;
      }
    }
  }
}

// ------- fused depthwise3x3+GELU+fc2+residual: block = 1 image row x 192 ch -------
// 512 thr, 51.7KB LDS; single Ht buffer, 2 barriers/chunk, reg-prefetched h1
__global__ __launch_bounds__(512) void k_fc2f(const unsigned short* __restrict__ h1,
    const float* __restrict__ dw, const float* __restrict__ wgt,
    const float* __restrict__ bias, float* __restrict__ out, int b_off){
  int nwg = gridDim.x;
  int cpx = nwg >> 3;
  int bid = (blockIdx.x & 7)*cpx + (blockIdx.x >> 3);  // contiguous rows per XCD
  int bl  = bid >> 7;            // slot-local batch
  int r   = bid & 127;           // image row
  int b   = b_off + bl;
  int t = threadIdx.x, lane = t & 63, wv = t >> 6;
  int wm = wv & 1, wn = wv >> 1;
  int l15 = lane & 15, lhi = lane >> 4;
  __shared__ unsigned short Ht[32][3][136];     // 26.1KB; ch-stride 816B (51x16B)
  __shared__ unsigned short Alc[128][40];       // 10.2KB
  __shared__ unsigned short Bl[192][40];        // 15.4KB
  const unsigned short* h1b = h1 + (size_t)bl*HID_*N_;
  f32x4 acc[4][3] = {};
  int cch = t & 31, j0 = (t >> 5) * 8;          // conv: channel, col base
  // ---- hoisted per-thread staging state ----
  const unsigned short* gp[3]; unsigned short* lp[3]; bool gok[3];
#pragma unroll
  for (int i = 0; i < 3; ++i){
    int li = t + 512*i;                         // 0..1535
    int ch = li / 48, rm = li % 48, dy = rm >> 4, seg = rm & 15;
    int rr = r - 1 + dy;
    gok[i] = (rr >= 0 && rr < H_);
    gp[i] = h1b + (size_t)ch*N_ + (gok[i] ? rr : 0)*W_ + seg*8;
    lp[i] = &Ht[ch][dy][seg*8];
  }
  const float* wgp[3]; unsigned short* blp[3];
#pragma unroll
  for (int i = 0; i < 3; ++i){
    int row = (t >> 3) + 64*i, seg = t & 7;
    wgp[i] = wgt + (size_t)row*HID_ + seg*4;
    blp[i] = &Bl[row][seg*4];
  }
  const float* dwp = dw + (size_t)cch*9;        // advance +288 per chunk
  uint4 hr[3];
  auto hload = [&](){
#pragma unroll
    for (int i = 0; i < 3; ++i)
      hr[i] = gok[i] ? *reinterpret_cast<const uint4*>(gp[i]) : make_uint4(0u,0u,0u,0u);
#pragma unroll
    for (int i = 0; i < 3; ++i) gp[i] += 32*N_;
  };
  // prologue: chunk 0 into Ht, prefetch chunk 1 into regs
  hload();
#pragma unroll
  for (int i = 0; i < 3; ++i) *reinterpret_cast<uint4*>(lp[i]) = hr[i];
  hload();
  for (int c24 = 0; c24 < 24; ++c24){
    __syncthreads();                  // A: Ht(c) visible; prev MFMA done
    // stage Bl direct from global (L2-hot weights)
#pragma unroll
    for (int i = 0; i < 3; ++i){
      float4 v = *reinterpret_cast<const float4*>(wgp[i]);
      wgp[i] += 32;
      *reinterpret_cast<uint2*>(blp[i]) =
          make_uint2(cvtpk(v.x, v.y), cvtpk(v.z, v.w));
    }
    // conv 3x3 + fast GELU from Ht -> Alc; dw direct (broadcast-hot)
    {
      float w9[9];
#pragma unroll
      for (int i = 0; i < 9; ++i) w9[i] = dwp[i];
      dwp += 288;
      const unsigned short* hp = &Ht[cch][0][j0];
      float s[8] = {0.f,0.f,0.f,0.f,0.f,0.f,0.f,0.f};
#pragma unroll
      for (int dy = 0; dy < 3; ++dy){
        const unsigned short* rp = hp + dy*136;
        bf16x8 mid = *reinterpret_cast<const bf16x8*>(rp);
        float v[10];
        v[0] = (j0 > 0)   ? bf2f(rp[-1]) : 0.f;
        v[9] = (j0 < 120) ? bf2f(rp[8])  : 0.f;
#pragma unroll
        for (int j = 0; j < 8; ++j) v[1+j] = bf2f((unsigned short)mid[j]);
        float wa = w9[3*dy], wb = w9[3*dy+1], wc = w9[3*dy+2];
#pragma unroll
        for (int j = 0; j < 8; ++j)
          s[j] += v[j]*wa + v[j+1]*wb + v[j+2]*wc;
      }
#pragma unroll
      for (int j = 0; j < 8; ++j)
        Alc[j0+j][cch] = f2bf(gelu_fast(s[j]));
    }
    __syncthreads();                  // B: Alc+Bl visible; Ht reads complete
    // write prefetched chunk c+1 into Ht (dead now); prefetch c+2
    if (c24 < 23){
#pragma unroll
      for (int i = 0; i < 3; ++i)
        *reinterpret_cast<uint4*>(lp[i]) = hr[i];
      if (c24 < 22) hload();
    }
    // MFMA: wave = 64-tok half (wm) x 48-ch quarter (wn)
    bf16x8 af[4], bfr[3];
#pragma unroll
    for (int mf = 0; mf < 4; ++mf)
      af[mf] = *reinterpret_cast<const bf16x8*>(&Alc[wm*64 + mf*16 + l15][lhi*8]);
#pragma unroll
    for (int nf = 0; nf < 3; ++nf)
      bfr[nf] = *reinterpret_cast<const bf16x8*>(&Bl[wn*48 + nf*16 + l15][lhi*8]);
    __builtin_amdgcn_s_setprio(1);
#pragma unroll
    for (int mf = 0; mf < 4; ++mf)
#pragma unroll
      for (int nf = 0; nf < 3; ++nf)
        acc[mf][nf] = __builtin_amdgcn_mfma_f32_16x16x32_bf16(af[mf], bfr[nf], acc[mf][nf], 0,0,0);
    __builtin_amdgcn_s_setprio(0);
  }
  // epilogue: += bias + residual (out holds ln2t)
#pragma unroll
  for (int mf = 0; mf < 4; ++mf){
    int tok = r*W_ + wm*64 + mf*16 + lhi*4;
#pragma unroll
    for (int nf = 0; nf < 3; ++nf){
      int oc = wn*48 + nf*16 + l15;
      float bv = bias[oc];
      size_t off = ((size_t)b*C_ + oc)*N_ + tok;
      float4 rr = *reinterpret_cast<const float4*>(out + off);
      float4 v = make_float4(rr.x + acc[mf][nf][0] + bv, rr.y + acc[mf][nf][1] + bv,
                             rr.z + acc[mf][nf][2] + bv, rr.w + acc[mf][nf][3] + bv);
      *reinterpret_cast<float4*>(out + off) = v;
    }
  }
}

extern "C" void kernel_launch(void* const* d_in, const int* in_sizes, int n_in,
                              void* d_out, int out_size, void* d_ws, size_t ws_size,
                              hipStream_t stream) {
  const float*    x      = (const float*)d_in[0];
  const unsigned* idx    = (const unsigned*)d_in[1];
  const float*    ln1_w  = (const float*)d_in[2];
  const float*    ln1_b  = (const float*)d_in[3];
  const float*    qkv_w  = (const float*)d_in[4];
  const float*    proj_w = (const float*)d_in[5];
  const float*    proj_b = (const float*)d_in[6];
  const float*    ln2_w  = (const float*)d_in[7];
  const float*    ln2_b  = (const float*)d_in[8];
  const float*    fc1_w  = (const float*)d_in[9];
  const float*    fc1_b  = (const float*)d_in[10];
  const float*    dw_w   = (const float*)d_in[11];
  const float*    fc2_w  = (const float*)d_in[12];
  const float*    fc2_b  = (const float*)d_in[13];
  float* out = (float*)d_out;          // doubles as ln2t (B,C,N) f32

  const size_t SZY = (size_t)N_*C_*2;              // y bf16: 6.29 MB/batch
  const size_t SZQ = (size_t)K_*3*C_*2;            // 2.36
  const size_t SZA = (size_t)K_*C_*2;              // 0.79
  const size_t SZO = (size_t)NC_*HEADS_*K_*HD_*4;  // 6.29/batch
  const size_t SZH = (size_t)HID_*N_*2;            // 25.17/batch
  int nb = (ws_size >= (size_t)B_*SZH) ? B_ : 1;   // deterministic

  char* ws = (char*)d_ws;
  unsigned short* y16  = (unsigned short*)ws;
  unsigned short* qkvb = (unsigned short*)(ws + (size_t)nb*SZY);
  unsigned short* aob  = (unsigned short*)(ws + (size_t)nb*(SZY+SZQ));
  float*          po   = (float*)(ws + (size_t)nb*(SZY+SZQ+SZA));
  float*          pml  = (float*)(ws + (size_t)nb*(SZY+SZQ+SZA+SZO));
  unsigned short* h1s  = (unsigned short*)ws;      // MLP phase (front dead): nb slots

  for (int b0 = 0; b0 < B_; b0 += nb){
    k_ln1   <<<nb*256,             256, 0, stream>>>(x, ln1_w, ln1_b, y16, b0);
    k_qkv   <<<nb*16*9,            256, 0, stream>>>(y16, idx, qkv_w, qkvb, b0);
    k_attn  <<<nb*HEADS_*32*NC_,   256, 0, stream>>>(qkvb, po, pml, nb);
    k_amerge<<<nb*HEADS_*K_/4,     256, 0, stream>>>(po, pml, aob, nb);
    k_proj  <<<nb*16*3,            256, 0, stream>>>(aob, idx, proj_w, proj_b, y16, b0);
    k_ln2   <<<nb*256,             256, 0, stream>>>(x, y16, ln2_w, ln2_b, out, b0);
    k_fc1   <<<nb*256,             256, 0, stream>>>(out, fc1_w, fc1_b, h1s, b0);
    k_fc2f  <<<nb*128,             512, 0, stream>>>(h1s, dw_w, fc2_w, fc2_b, out, b0);
  }
}

// Round 21
// 235.005 us; speedup vs baseline: 1.1761x; 1.0140x over previous
//
#include <hip/hip_runtime.h>

#define B_ 4
#define C_ 192
#define H_ 128
#define W_ 128
#define N_ (H_*W_)      // 16384
#define K_ 2048
#define HEADS_ 3
#define HD_ 64
#define HID_ 768
#define NC_ 2           // attention split-K chunks
#define KC_ (K_/NC_)    // 1024

typedef __attribute__((ext_vector_type(4))) float f32x4;
typedef __attribute__((ext_vector_type(8))) short bf16x8;

__device__ __forceinline__ unsigned short f2bf(float f){
  unsigned int u = __float_as_uint(f);
  u += 0x7FFFu + ((u >> 16) & 1u);
  return (unsigned short)(u >> 16);
}
__device__ __forceinline__ float bf2f(unsigned short s){
  return __uint_as_float(((unsigned int)s) << 16);
}
__device__ __forceinline__ unsigned cvtpk(float lo, float hi){
  unsigned r;
  asm("v_cvt_pk_bf16_f32 %0, %1, %2" : "=v"(r) : "v"(lo), "v"(hi));
  return r;
}
// sigmoid-form GELU: x * sigma(1.702x); ~5 VALU via HW rcp. |err| <= ~0.02
__device__ __forceinline__ float gelu_fast(float x){
  float e = __expf(-1.702f*x);
  return x * __builtin_amdgcn_rcpf(1.f + e);
}

__device__ __forceinline__ int load_idx(const unsigned* __restrict__ ip, int pos){
  bool is64 = (ip[1]==0u) & (ip[3]==0u) & (ip[5]==0u) & (ip[7]==0u);
  int v = is64 ? (int)ip[2*pos] : (int)ip[pos];
  return min(max(v, 0), N_-1);
}

// ---------------- LN1: x (B,C,N) -> y bf16 (nb,N,C) ----------------
__global__ __launch_bounds__(256) void k_ln1(const float* __restrict__ x,
    const float* __restrict__ w, const float* __restrict__ bias,
    unsigned short* __restrict__ y, int b_off){
  int blk = blockIdx.x;
  int bl = blk >> 8;
  int b  = b_off + bl;
  int n0 = (blk & 255) * 64;
  int t  = threadIdx.x;
  int tok = t & 63, q = t >> 6;
  __shared__ float tile[64][C_+1];
  __shared__ float red[8][64];
  __shared__ float wls[C_], bls[C_];
  if (t < C_){ wls[t] = w[t]; bls[t] = bias[t]; }
  const float* xb = x + (size_t)b*C_*N_ + n0;
  float sum = 0.f, sq = 0.f;
#pragma unroll
  for (int i = 0; i < 48; ++i){
    int c = q + 4*i;
    float v = xb[(size_t)c*N_ + tok];
    tile[tok][c] = v;
    sum += v; sq += v*v;
  }
  red[q][tok] = sum; red[4+q][tok] = sq;
  __syncthreads();
  if (q == 0){
    float s  = red[0][tok]+red[1][tok]+red[2][tok]+red[3][tok];
    float s2 = red[4][tok]+red[5][tok]+red[6][tok]+red[7][tok];
    float mu = s*(1.f/C_);
    float rstd = rsqrtf(s2*(1.f/C_) - mu*mu + 1e-5f);
    red[0][tok] = mu; red[1][tok] = rstd;
  }
  __syncthreads();
  unsigned* yb = reinterpret_cast<unsigned*>(y + ((size_t)bl*N_ + n0)*C_);
#pragma unroll
  for (int i = 0; i < 24; ++i){
    int li = t + 256*i;                 // 6144 u32
    int tk = li / 96, c2 = li % 96;
    int c = 2*c2;
    float v0 = (tile[tk][c]  -red[0][tk])*red[1][tk]*wls[c]   + bls[c];
    float v1 = (tile[tk][c+1]-red[0][tk])*red[1][tk]*wls[c+1] + bls[c+1];
    yb[li] = cvtpk(v0, v1);
  }
}

// ---------------- QKV MFMA GEMM with gather: y bf16 -> qkv bf16 ----------------
__global__ __launch_bounds__(256) void k_qkv(const unsigned short* __restrict__ y,
    const unsigned* __restrict__ idx, const float* __restrict__ wq,
    unsigned short* __restrict__ qkv, int b_off){
  const int NT = (3*C_)/64;  // 9
  int bid = blockIdx.x;
  int bl  = bid / (16*NT);
  int rem = bid % (16*NT);
  int m0  = (rem / NT) * 128;
  int n0  = (rem % NT) * 64;
  int t = threadIdx.x, lane = t & 63;
  int wv = t >> 6, wm = wv & 1, wn = wv >> 1;
  __shared__ unsigned short Al[128][40];
  __shared__ unsigned short Bl[64][40];
  __shared__ int rows[128];
  if (t < 128) rows[t] = load_idx(idx, (b_off+bl)*K_ + m0 + t);
  __syncthreads();
  f32x4 acc[4][2] = {};
  int l15 = lane & 15, lhi = lane >> 4;
  for (int k0 = 0; k0 < C_; k0 += 32){
    {
      int m = t >> 1;
      const unsigned short* src = y + ((size_t)bl*N_ + rows[m])*C_ + k0;
#pragma unroll
      for (int i = 0; i < 4; ++i){
        int kq = (t & 1) + 2*i;
        *reinterpret_cast<ushort4*>(&Al[m][4*kq]) =
            *reinterpret_cast<const ushort4*>(src + 4*kq);
      }
      int n = t >> 2;
      const float* bsrc = wq + (size_t)(n0+n)*C_ + k0;
#pragma unroll
      for (int i = 0; i < 2; ++i){
        int q = (t & 3) + 4*i;
        float4 v = *reinterpret_cast<const float4*>(bsrc + 4*q);
        *reinterpret_cast<uint2*>(&Bl[n][4*q]) =
            make_uint2(cvtpk(v.x, v.y), cvtpk(v.z, v.w));
      }
    }
    __syncthreads();
    bf16x8 af[4], bfr[2];
#pragma unroll
    for (int mf = 0; mf < 4; ++mf)
      af[mf] = *reinterpret_cast<const bf16x8*>(&Al[wm*64 + mf*16 + l15][lhi*8]);
#pragma unroll
    for (int nf = 0; nf < 2; ++nf)
      bfr[nf] = *reinterpret_cast<const bf16x8*>(&Bl[wn*32 + nf*16 + l15][lhi*8]);
#pragma unroll
    for (int mf = 0; mf < 4; ++mf)
#pragma unroll
      for (int nf = 0; nf < 2; ++nf)
        acc[mf][nf] = __builtin_amdgcn_mfma_f32_16x16x32_bf16(af[mf], bfr[nf], acc[mf][nf], 0,0,0);
    __syncthreads();
  }
#pragma unroll
  for (int mf = 0; mf < 4; ++mf){
    int mb = m0 + wm*64 + mf*16 + lhi*4;
#pragma unroll
    for (int nf = 0; nf < 2; ++nf){
      int n = n0 + wn*32 + nf*16 + l15;
#pragma unroll
      for (int r = 0; r < 4; ++r)
        qkv[((size_t)bl*K_ + mb + r)*(3*C_) + n] = f2bf(acc[mf][nf][r]);
    }
  }
}

// ------- attention split-K (NC=2), swapped QK^T, defer-max, cvt_pk -------
__global__ __launch_bounds__(256) void k_attn(const unsigned short* __restrict__ qkv,
    float* __restrict__ po, float* __restrict__ pml, int nb){
  int bid = blockIdx.x;
  int c   = bid & (NC_-1);
  int qt  = (bid >> 1) & 31;
  int bh  = bid >> 6;
  int h = bh % HEADS_, bl = bh / HEADS_;
  int q0 = qt*64;
  int t = threadIdx.x, lane = t & 63, wv = t >> 6;
  int l15 = lane & 15, lhi = lane >> 4;
  const unsigned short* base = qkv + (size_t)bl*K_*(3*C_) + h*HD_;
  __shared__ unsigned short Ql[64][72];
  __shared__ unsigned short Kl[64][72];
  __shared__ unsigned short Vt[64][72];
  __shared__ unsigned short Pl[4][16][72];
  {
    int r = t >> 2, d0 = (t & 3) * 16;
    const uint4* src = reinterpret_cast<const uint4*>(base + (size_t)(q0+r)*(3*C_) + d0);
    *reinterpret_cast<uint4*>(&Ql[r][d0])   = src[0];
    *reinterpret_cast<uint4*>(&Ql[r][d0+8]) = src[1];
  }
  __syncthreads();
  float m_q = -1e30f, l_q = 0.f;
  f32x4 o[4] = {};
  for (int kt0 = c*KC_; kt0 < c*KC_ + KC_; kt0 += 64){
    {
      int r = t >> 2, d0 = (t & 3) * 16;
      const uint4* src = reinterpret_cast<const uint4*>(base + (size_t)(kt0+r)*(3*C_) + C_ + d0);
      *reinterpret_cast<uint4*>(&Kl[r][d0])   = src[0];
      *reinterpret_cast<uint4*>(&Kl[r][d0+8]) = src[1];
      int kp = t & 31, vd0 = (t >> 5) * 8, k = 2*kp;
      const ushort4* v0 = reinterpret_cast<const ushort4*>(base + (size_t)(kt0+k)*(3*C_)   + 2*C_ + vd0);
      const ushort4* v1 = reinterpret_cast<const ushort4*>(base + (size_t)(kt0+k+1)*(3*C_) + 2*C_ + vd0);
      ushort4 a0 = v0[0], a1 = v0[1], b0 = v1[0], b1 = v1[1];
      unsigned short va[8] = {a0.x,a0.y,a0.z,a0.w,a1.x,a1.y,a1.z,a1.w};
      unsigned short vb[8] = {b0.x,b0.y,b0.z,b0.w,b1.x,b1.y,b1.z,b1.w};
#pragma unroll
      for (int j = 0; j < 8; ++j){
        unsigned u = (unsigned)va[j] | ((unsigned)vb[j] << 16);
        *reinterpret_cast<unsigned*>(&Vt[vd0+j][k]) = u;
      }
    }
    __syncthreads();
    f32x4 s[4] = {};
    __builtin_amdgcn_s_setprio(1);
#pragma unroll
    for (int kt = 0; kt < 2; ++kt){
      bf16x8 qf = *reinterpret_cast<const bf16x8*>(&Ql[wv*16 + l15][kt*32 + lhi*8]);
#pragma unroll
      for (int nt = 0; nt < 4; ++nt){
        bf16x8 kf = *reinterpret_cast<const bf16x8*>(&Kl[nt*16 + l15][kt*32 + lhi*8]);
        s[nt] = __builtin_amdgcn_mfma_f32_16x16x32_bf16(kf, qf, s[nt], 0,0,0);
      }
    }
    __builtin_amdgcn_s_setprio(0);
    float mx = s[0][0];
#pragma unroll
    for (int nt = 0; nt < 4; ++nt)
#pragma unroll
      for (int reg = 0; reg < 4; ++reg) mx = fmaxf(mx, s[nt][reg]);
    mx = fmaxf(mx, __shfl_xor(mx, 16));
    mx = fmaxf(mx, __shfl_xor(mx, 32));
    mx *= 0.125f;
    bool skip = __all(mx <= m_q + 8.f);
    if (!skip){
      float mn = fmaxf(m_q, mx);
      float corr = __expf(m_q - mn);
      l_q *= corr;
      float cr[4];
#pragma unroll
      for (int reg = 0; reg < 4; ++reg) cr[reg] = __shfl(corr, lhi*4 + reg);
#pragma unroll
      for (int nt = 0; nt < 4; ++nt)
#pragma unroll
        for (int reg = 0; reg < 4; ++reg) o[nt][reg] *= cr[reg];
      m_q = mn;
    }
    float ls = 0.f;
#pragma unroll
    for (int nt = 0; nt < 4; ++nt){
      float p0 = __expf(fmaf(s[nt][0], 0.125f, -m_q));
      float p1 = __expf(fmaf(s[nt][1], 0.125f, -m_q));
      float p2 = __expf(fmaf(s[nt][2], 0.125f, -m_q));
      float p3 = __expf(fmaf(s[nt][3], 0.125f, -m_q));
      ls += (p0 + p1) + (p2 + p3);
      uint2 uu;
      uu.x = cvtpk(p0, p1);
      uu.y = cvtpk(p2, p3);
      *reinterpret_cast<uint2*>(&Pl[wv][l15][nt*16 + lhi*4]) = uu;
    }
    ls += __shfl_xor(ls, 16);
    ls += __shfl_xor(ls, 32);
    l_q += ls;
    __threadfence_block();
    __builtin_amdgcn_s_setprio(1);
#pragma unroll
    for (int kt = 0; kt < 2; ++kt){
      bf16x8 pa = *reinterpret_cast<const bf16x8*>(&Pl[wv][l15][kt*32 + lhi*8]);
#pragma unroll
      for (int nt = 0; nt < 4; ++nt){
        bf16x8 vb = *reinterpret_cast<const bf16x8*>(&Vt[nt*16 + l15][kt*32 + lhi*8]);
        o[nt] = __builtin_amdgcn_mfma_f32_16x16x32_bf16(pa, vb, o[nt], 0,0,0);
      }
    }
    __builtin_amdgcn_s_setprio(0);
    __syncthreads();
  }
  int R = nb*HEADS_*K_;
  int rowb = (bl*HEADS_ + h)*K_;
#pragma unroll
  for (int reg = 0; reg < 4; ++reg){
    int rq = rowb + q0 + wv*16 + lhi*4 + reg;
#pragma unroll
    for (int nt = 0; nt < 4; ++nt)
      po[((size_t)c*R + rq)*HD_ + nt*16 + l15] = o[nt][reg];
  }
  if (lhi == 0){
    int rq = rowb + q0 + wv*16 + l15;
    *reinterpret_cast<float2*>(pml + 2*((size_t)c*R + rq)) = make_float2(m_q, l_q);
  }
}

// ---------------- merge split-K partials -> ao bf16 (bl,K,C) ----------------
__global__ __launch_bounds__(256) void k_amerge(const float* __restrict__ po,
    const float* __restrict__ pml, unsigned short* __restrict__ ao, int nb){
  int R = nb*HEADS_*K_;
  int row = blockIdx.x*4 + (threadIdx.x >> 6);
  int lane = threadIdx.x & 63;
  float m[NC_], l[NC_];
#pragma unroll
  for (int cc = 0; cc < NC_; ++cc){
    float2 v = *reinterpret_cast<const float2*>(pml + 2*((size_t)cc*R + row));
    m[cc] = v.x; l[cc] = v.y;
  }
  float M = m[0];
#pragma unroll
  for (int cc = 1; cc < NC_; ++cc) M = fmaxf(M, m[cc]);
  float L = 0.f, o = 0.f;
#pragma unroll
  for (int cc = 0; cc < NC_; ++cc){
    float e = __expf(m[cc] - M);
    L += l[cc]*e;
    o += e * po[((size_t)cc*R + row)*HD_ + lane];
  }
  o /= L;
  int q = row & (K_-1);
  int bh = row >> 11;
  int h = bh % HEADS_, bl = bh / HEADS_;
  ao[((size_t)bl*K_ + q)*C_ + h*HD_ + lane] = f2bf(o);
}

// ---------------- proj MFMA GEMM + scatter into y (bf16) ----------------
__global__ __launch_bounds__(256) void k_proj(const unsigned short* __restrict__ ain,
    const unsigned* __restrict__ idx, const float* __restrict__ pw,
    const float* __restrict__ pb, unsigned short* __restrict__ y, int b_off){
  const int NT = C_/64;   // 3
  int bid = blockIdx.x;
  int bl  = bid / (16*NT);
  int rem = bid % (16*NT);
  int m0  = (rem / NT) * 128;
  int n0  = (rem % NT) * 64;
  int t = threadIdx.x, lane = t & 63;
  int wv = t >> 6, wm = wv & 1, wn = wv >> 1;
  __shared__ unsigned short Al[128][40];
  __shared__ unsigned short Bl[64][40];
  __shared__ int rows[128];
  if (t < 128) rows[t] = load_idx(idx, (b_off+bl)*K_ + m0 + t);
  __syncthreads();
  f32x4 acc[4][2] = {};
  int l15 = lane & 15, lhi = lane >> 4;
  for (int k0 = 0; k0 < C_; k0 += 32){
    {
      int m = t >> 1;
      const unsigned short* src = ain + ((size_t)bl*K_ + m0 + m)*C_ + k0;
#pragma unroll
      for (int i = 0; i < 4; ++i){
        int kq = (t & 1) + 2*i;
        *reinterpret_cast<ushort4*>(&Al[m][4*kq]) =
            *reinterpret_cast<const ushort4*>(src + 4*kq);
      }
      int n = t >> 2;
      const float* bsrc = pw + (size_t)(n0+n)*C_ + k0;
#pragma unroll
      for (int i = 0; i < 2; ++i){
        int q = (t & 3) + 4*i;
        float4 v = *reinterpret_cast<const float4*>(bsrc + 4*q);
        *reinterpret_cast<uint2*>(&Bl[n][4*q]) =
            make_uint2(cvtpk(v.x, v.y), cvtpk(v.z, v.w));
      }
    }
    __syncthreads();
    bf16x8 af[4], bfr[2];
#pragma unroll
    for (int mf = 0; mf < 4; ++mf)
      af[mf] = *reinterpret_cast<const bf16x8*>(&Al[wm*64 + mf*16 + l15][lhi*8]);
#pragma unroll
    for (int nf = 0; nf < 2; ++nf)
      bfr[nf] = *reinterpret_cast<const bf16x8*>(&Bl[wn*32 + nf*16 + l15][lhi*8]);
#pragma unroll
    for (int mf = 0; mf < 4; ++mf)
#pragma unroll
      for (int nf = 0; nf < 2; ++nf)
        acc[mf][nf] = __builtin_amdgcn_mfma_f32_16x16x32_bf16(af[mf], bfr[nf], acc[mf][nf], 0,0,0);
    __syncthreads();
  }
#pragma unroll
  for (int mf = 0; mf < 4; ++mf){
    int mb = wm*64 + mf*16 + lhi*4;
#pragma unroll
    for (int nf = 0; nf < 2; ++nf){
      int n = n0 + wn*32 + nf*16 + l15;
      float bv = pb[n];
#pragma unroll
      for (int r = 0; r < 4; ++r)
        y[((size_t)bl*N_ + rows[mb + r])*C_ + n] = f2bf(acc[mf][nf][r] + bv);
    }
  }
}

// ---------------- residual + LN2 -> ln2t (B,C,N) [== d_out] ----------------
__global__ __launch_bounds__(256) void k_ln2(const float* __restrict__ x,
    const unsigned short* __restrict__ y, const float* __restrict__ w,
    const float* __restrict__ bias, float* __restrict__ ln2t, int b_off){
  int blk = blockIdx.x;
  int bl = blk >> 8;
  int b  = b_off + bl;
  int n0 = (blk & 255) * 64;
  int t  = threadIdx.x;
  int tok = t & 63, q = t >> 6;
  __shared__ float tile[64][C_+1];
  __shared__ float red[8][64];
  __shared__ float wls[C_], bls[C_];
  if (t < C_){ wls[t] = w[t]; bls[t] = bias[t]; }
  const unsigned* yb = reinterpret_cast<const unsigned*>(y + ((size_t)bl*N_ + n0)*C_);
#pragma unroll
  for (int i = 0; i < 24; ++i){
    int li = t + 256*i;
    unsigned u = yb[li];
    int tk = li / 96, c2 = li % 96;
    tile[tk][2*c2]   = bf2f((unsigned short)(u & 0xffffu));
    tile[tk][2*c2+1] = bf2f((unsigned short)(u >> 16));
  }
  __syncthreads();
  const float* xb = x + (size_t)b*C_*N_ + n0;
  float sum = 0.f, sq = 0.f;
#pragma unroll
  for (int i = 0; i < 48; ++i){
    int c = q + 4*i;
    float v = xb[(size_t)c*N_ + tok] + tile[tok][c];
    tile[tok][c] = v;
    sum += v; sq += v*v;
  }
  red[q][tok] = sum; red[4+q][tok] = sq;
  __syncthreads();
  if (q == 0){
    float s  = red[0][tok]+red[1][tok]+red[2][tok]+red[3][tok];
    float s2 = red[4][tok]+red[5][tok]+red[6][tok]+red[7][tok];
    float mu = s*(1.f/C_);
    float rstd = rsqrtf(s2*(1.f/C_) - mu*mu + 1e-5f);
    red[0][tok] = mu; red[1][tok] = rstd;
  }
  __syncthreads();
  float* ob = ln2t + (size_t)b*C_*N_ + n0;
  float mu = red[0][tok], rstd = red[1][tok];
#pragma unroll
  for (int i = 0; i < 48; ++i){
    int c = q + 4*i;
    ob[(size_t)c*N_ + tok] = (tile[tok][c]-mu)*rstd*wls[c] + bls[c];
  }
}

// ------- fc1 MFMA: block = 128-token m-tile x 384-hid half, loop 6 n-tiles -------
__global__ __launch_bounds__(256) void k_fc1(const float* __restrict__ ln2t,
    const float* __restrict__ wgt, const float* __restrict__ bias,
    unsigned short* __restrict__ h1, int b_off){
  int bid = blockIdx.x;
  int bl  = bid >> 8;                  // slot-local batch
  int rem = bid & 255;
  int m0  = (rem >> 1) * 128;
  int nh  = (rem & 1) * 6;             // n-tile half
  int t = threadIdx.x, lane = t & 63;
  int wv = t >> 6, wm = wv & 1, wn = wv >> 1;
  int l15 = lane & 15, lhi = lane >> 4;
  __shared__ unsigned short Al[128][200];
  __shared__ unsigned short Bl[64][200];
  const float* a = ln2t + (size_t)(b_off+bl)*C_*N_ + m0;
  unsigned short* hb = h1 + (size_t)bl*HID_*N_;
  {
    int m = t & 127, half = t >> 7;
#pragma unroll
    for (int i = 0; i < 48; ++i){
      int p = half + 2*i;                    // 0..95
      float v0 = a[(size_t)(2*p)*N_ + m];
      float v1 = a[(size_t)(2*p+1)*N_ + m];
      *reinterpret_cast<unsigned*>(&Al[m][2*p]) = cvtpk(v0, v1);
    }
  }
  for (int nt = 0; nt < 6; ++nt){
    int n0 = (nh + nt)*64;
    __syncthreads();
    {
      int n = t >> 2;
      const float* bsrc = wgt + (size_t)(n0+n)*C_;
#pragma unroll
      for (int i = 0; i < 12; ++i){
        int q = (t & 3) + 4*i;               // 0..47 float4 segs
        float4 v = *reinterpret_cast<const float4*>(bsrc + 4*q);
        *reinterpret_cast<uint2*>(&Bl[n][4*q]) =
            make_uint2(cvtpk(v.x, v.y), cvtpk(v.z, v.w));
      }
    }
    __syncthreads();
    f32x4 acc[4][2] = {};
#pragma unroll
    for (int ks = 0; ks < 6; ++ks){
      bf16x8 af[4], bfr[2];
#pragma unroll
      for (int mf = 0; mf < 4; ++mf)
        af[mf] = *reinterpret_cast<const bf16x8*>(&Al[wm*64 + mf*16 + l15][ks*32 + lhi*8]);
#pragma unroll
      for (int nf = 0; nf < 2; ++nf)
        bfr[nf] = *reinterpret_cast<const bf16x8*>(&Bl[wn*32 + nf*16 + l15][ks*32 + lhi*8]);
#pragma unroll
      for (int mf = 0; mf < 4; ++mf)
#pragma unroll
        for (int nf = 0; nf < 2; ++nf)
          acc[mf][nf] = __builtin_amdgcn_mfma_f32_16x16x32_bf16(af[mf], bfr[nf], acc[mf][nf], 0,0,0);
    }
#pragma unroll
    for (int mf = 0; mf < 4; ++mf){
      int mb = m0 + wm*64 + mf*16 + lhi*4;
#pragma unroll
      for (int nf = 0; nf < 2; ++nf){
        int n = n0 + wn*32 + nf*16 + l15;
        float bv = bias[n];
        uint2 pk;
        pk.x = cvtpk(acc[mf][nf][0] + bv, acc[mf][nf][1] + bv);
        pk.y = cvtpk(acc[mf][nf][2] + bv, acc[mf][nf][3] + bv);
        *reinterpret_cast<uint2*>(&hb[(size_t)n*N_ + mb]) = pk;
      }
    }
  }
}

// ------- fused depthwise3x3+GELU+fc2+residual: block = 1 image row x 192 ch -------
// 512 thr, 51.7KB LDS; single Ht buffer, 2 barriers/chunk, reg-prefetched h1
__global__ __launch_bounds__(512) void k_fc2f(const unsigned short* __restrict__ h1,
    const float* __restrict__ dw, const float* __restrict__ wgt,
    const float* __restrict__ bias, float* __restrict__ out, int b_off){
  int nwg = gridDim.x;
  int cpx = nwg >> 3;
  int bid = (blockIdx.x & 7)*cpx + (blockIdx.x >> 3);  // contiguous rows per XCD
  int bl  = bid >> 7;            // slot-local batch
  int r   = bid & 127;           // image row
  int b   = b_off + bl;
  int t = threadIdx.x, lane = t & 63, wv = t >> 6;
  int wm = wv & 1, wn = wv >> 1;
  int l15 = lane & 15, lhi = lane >> 4;
  __shared__ unsigned short Ht[32][3][136];     // 26.1KB; ch-stride 816B (51x16B)
  __shared__ unsigned short Alc[128][40];       // 10.2KB
  __shared__ unsigned short Bl[192][40];        // 15.4KB
  const unsigned short* h1b = h1 + (size_t)bl*HID_*N_;
  f32x4 acc[4][3] = {};
  int cch = t & 31, j0 = (t >> 5) * 8;          // conv: channel, col base
  // ---- hoisted per-thread staging state ----
  const unsigned short* gp[3]; unsigned short* lp[3]; bool gok[3];
#pragma unroll
  for (int i = 0; i < 3; ++i){
    int li = t + 512*i;                         // 0..1535
    int ch = li / 48, rm = li % 48, dy = rm >> 4, seg = rm & 15;
    int rr = r - 1 + dy;
    gok[i] = (rr >= 0 && rr < H_);
    gp[i] = h1b + (size_t)ch*N_ + (gok[i] ? rr : 0)*W_ + seg*8;
    lp[i] = &Ht[ch][dy][seg*8];
  }
  const float* wgp[3]; unsigned short* blp[3];
#pragma unroll
  for (int i = 0; i < 3; ++i){
    int row = (t >> 3) + 64*i, seg = t & 7;
    wgp[i] = wgt + (size_t)row*HID_ + seg*4;
    blp[i] = &Bl[row][seg*4];
  }
  const float* dwp = dw + (size_t)cch*9;        // advance +288 per chunk
  uint4 hr[3];
  auto hload = [&](){
#pragma unroll
    for (int i = 0; i < 3; ++i)
      hr[i] = gok[i] ? *reinterpret_cast<const uint4*>(gp[i]) : make_uint4(0u,0u,0u,0u);
#pragma unroll
    for (int i = 0; i < 3; ++i) gp[i] += 32*N_;
  };
  // prologue: chunk 0 into Ht, prefetch chunk 1 into regs
  hload();
#pragma unroll
  for (int i = 0; i < 3; ++i) *reinterpret_cast<uint4*>(lp[i]) = hr[i];
  hload();
  for (int c24 = 0; c24 < 24; ++c24){
    __syncthreads();                  // A: Ht(c) visible; prev MFMA done
    // stage Bl direct from global (L2-hot weights)
#pragma unroll
    for (int i = 0; i < 3; ++i){
      float4 v = *reinterpret_cast<const float4*>(wgp[i]);
      wgp[i] += 32;
      *reinterpret_cast<uint2*>(blp[i]) =
          make_uint2(cvtpk(v.x, v.y), cvtpk(v.z, v.w));
    }
    // conv 3x3 + fast GELU from Ht -> Alc; dw direct (broadcast-hot)
    {
      float w9[9];
#pragma unroll
      for (int i = 0; i < 9; ++i) w9[i] = dwp[i];
      dwp += 288;
      const unsigned short* hp = &Ht[cch][0][j0];
      float s[8] = {0.f,0.f,0.f,0.f,0.f,0.f,0.f,0.f};
#pragma unroll
      for (int dy = 0; dy < 3; ++dy){
        const unsigned short* rp = hp + dy*136;
        bf16x8 mid = *reinterpret_cast<const bf16x8*>(rp);
        float v[10];
        v[0] = (j0 > 0)   ? bf2f(rp[-1]) : 0.f;
        v[9] = (j0 < 120) ? bf2f(rp[8])  : 0.f;
#pragma unroll
        for (int j = 0; j < 8; ++j) v[1+j] = bf2f((unsigned short)mid[j]);
        float wa = w9[3*dy], wb = w9[3*dy+1], wc = w9[3*dy+2];
#pragma unroll
        for (int j = 0; j < 8; ++j)
          s[j] += v[j]*wa + v[j+1]*wb + v[j+2]*wc;
      }
#pragma unroll
      for (int j = 0; j < 8; ++j)
        Alc[j0+j][cch] = f2bf(gelu_fast(s[j]));
    }
    __syncthreads();                  // B: Alc+Bl visible; Ht reads complete
    // write prefetched chunk c+1 into Ht (dead now); prefetch c+2
    if (c24 < 23){
#pragma unroll
      for (int i = 0; i < 3; ++i)
        *reinterpret_cast<uint4*>(lp[i]) = hr[i];
      if (c24 < 22) hload();
    }
    // MFMA: wave = 64-tok half (wm) x 48-ch quarter (wn)
    bf16x8 af[4], bfr[3];
#pragma unroll
    for (int mf = 0; mf < 4; ++mf)
      af[mf] = *reinterpret_cast<const bf16x8*>(&Alc[wm*64 + mf*16 + l15][lhi*8]);
#pragma unroll
    for (int nf = 0; nf < 3; ++nf)
      bfr[nf] = *reinterpret_cast<const bf16x8*>(&Bl[wn*48 + nf*16 + l15][lhi*8]);
    __builtin_amdgcn_s_setprio(1);
#pragma unroll
    for (int mf = 0; mf < 4; ++mf)
#pragma unroll
      for (int nf = 0; nf < 3; ++nf)
        acc[mf][nf] = __builtin_amdgcn_mfma_f32_16x16x32_bf16(af[mf], bfr[nf], acc[mf][nf], 0,0,0);
    __builtin_amdgcn_s_setprio(0);
  }
  // epilogue: += bias + residual (out holds ln2t)
#pragma unroll
  for (int mf = 0; mf < 4; ++mf){
    int tok = r*W_ + wm*64 + mf*16 + lhi*4;
#pragma unroll
    for (int nf = 0; nf < 3; ++nf){
      int oc = wn*48 + nf*16 + l15;
      float bv = bias[oc];
      size_t off = ((size_t)b*C_ + oc)*N_ + tok;
      float4 rr = *reinterpret_cast<const float4*>(out + off);
      float4 v = make_float4(rr.x + acc[mf][nf][0] + bv, rr.y + acc[mf][nf][1] + bv,
                             rr.z + acc[mf][nf][2] + bv, rr.w + acc[mf][nf][3] + bv);
      *reinterpret_cast<float4*>(out + off) = v;
    }
  }
}

extern "C" void kernel_launch(void* const* d_in, const int* in_sizes, int n_in,
                              void* d_out, int out_size, void* d_ws, size_t ws_size,
                              hipStream_t stream) {
  const float*    x      = (const float*)d_in[0];
  const unsigned* idx    = (const unsigned*)d_in[1];
  const float*    ln1_w  = (const float*)d_in[2];
  const float*    ln1_b  = (const float*)d_in[3];
  const float*    qkv_w  = (const float*)d_in[4];
  const float*    proj_w = (const float*)d_in[5];
  const float*    proj_b = (const float*)d_in[6];
  const float*    ln2_w  = (const float*)d_in[7];
  const float*    ln2_b  = (const float*)d_in[8];
  const float*    fc1_w  = (const float*)d_in[9];
  const float*    fc1_b  = (const float*)d_in[10];
  const float*    dw_w   = (const float*)d_in[11];
  const float*    fc2_w  = (const float*)d_in[12];
  const float*    fc2_b  = (const float*)d_in[13];
  float* out = (float*)d_out;          // doubles as ln2t (B,C,N) f32

  const size_t SZY = (size_t)N_*C_*2;              // y bf16: 6.29 MB/batch
  const size_t SZQ = (size_t)K_*3*C_*2;            // 2.36
  const size_t SZA = (size_t)K_*C_*2;              // 0.79
  const size_t SZO = (size_t)NC_*HEADS_*K_*HD_*4;  // 3.15/batch
  const size_t SZH = (size_t)HID_*N_*2;            // 25.17/batch
  int nb = (ws_size >= (size_t)B_*SZH) ? B_ : 1;   // deterministic

  char* ws = (char*)d_ws;
  unsigned short* y16  = (unsigned short*)ws;
  unsigned short* qkvb = (unsigned short*)(ws + (size_t)nb*SZY);
  unsigned short* aob  = (unsigned short*)(ws + (size_t)nb*(SZY+SZQ));
  float*          po   = (float*)(ws + (size_t)nb*(SZY+SZQ+SZA));
  float*          pml  = (float*)(ws + (size_t)nb*(SZY+SZQ+SZA+SZO));
  unsigned short* h1s  = (unsigned short*)ws;      // MLP phase (front dead): nb slots

  for (int b0 = 0; b0 < B_; b0 += nb){
    k_ln1   <<<nb*256,             256, 0, stream>>>(x, ln1_w, ln1_b, y16, b0);
    k_qkv   <<<nb*16*9,            256, 0, stream>>>(y16, idx, qkv_w, qkvb, b0);
    k_attn  <<<nb*HEADS_*32*NC_,   256, 0, stream>>>(qkvb, po, pml, nb);
    k_amerge<<<nb*HEADS_*K_/4,     256, 0, stream>>>(po, pml, aob, nb);
    k_proj  <<<nb*16*3,            256, 0, stream>>>(aob, idx, proj_w, proj_b, y16, b0);
    k_ln2   <<<nb*256,             256, 0, stream>>>(x, y16, ln2_w, ln2_b, out, b0);
    k_fc1   <<<nb*256,             256, 0, stream>>>(out, fc1_w, fc1_b, h1s, b0);
    k_fc2f  <<<nb*128,             512, 0, stream>>>(h1s, dw_w, fc2_w, fc2_b, out, b0);
  }
}

// Round 22
// 234.403 us; speedup vs baseline: 1.1791x; 1.0026x over previous
//
#include <hip/hip_runtime.h>

#define B_ 4
#define C_ 192
#define H_ 128
#define W_ 128
#define N_ (H_*W_)      // 16384
#define K_ 2048
#define HEADS_ 3
#define HD_ 64
#define HID_ 768
#define NC_ 2           // attention split-K chunks
#define KC_ (K_/NC_)    // 1024

typedef __attribute__((ext_vector_type(4))) float f32x4;
typedef __attribute__((ext_vector_type(8))) short bf16x8;

__device__ __forceinline__ unsigned short f2bf(float f){
  unsigned int u = __float_as_uint(f);
  u += 0x7FFFu + ((u >> 16) & 1u);
  return (unsigned short)(u >> 16);
}
__device__ __forceinline__ float bf2f(unsigned short s){
  return __uint_as_float(((unsigned int)s) << 16);
}
__device__ __forceinline__ unsigned cvtpk(float lo, float hi){
  unsigned r;
  asm("v_cvt_pk_bf16_f32 %0, %1, %2" : "=v"(r) : "v"(lo), "v"(hi));
  return r;
}
// sigmoid-form GELU: x * sigma(1.702x); ~5 VALU via HW rcp. |err| <= ~0.02
__device__ __forceinline__ float gelu_fast(float x){
  float e = __expf(-1.702f*x);
  return x * __builtin_amdgcn_rcpf(1.f + e);
}

__device__ __forceinline__ int load_idx(const unsigned* __restrict__ ip, int pos){
  bool is64 = (ip[1]==0u) & (ip[3]==0u) & (ip[5]==0u) & (ip[7]==0u);
  int v = is64 ? (int)ip[2*pos] : (int)ip[pos];
  return min(max(v, 0), N_-1);
}

// ---------------- LN1: x (B,C,N) -> y bf16 (nb,N,C) ----------------
__global__ __launch_bounds__(256) void k_ln1(const float* __restrict__ x,
    const float* __restrict__ w, const float* __restrict__ bias,
    unsigned short* __restrict__ y, int b_off){
  int blk = blockIdx.x;
  int bl = blk >> 8;
  int b  = b_off + bl;
  int n0 = (blk & 255) * 64;
  int t  = threadIdx.x;
  int tok = t & 63, q = t >> 6;
  __shared__ float tile[64][C_+1];
  __shared__ float red[8][64];
  __shared__ float wls[C_], bls[C_];
  if (t < C_){ wls[t] = w[t]; bls[t] = bias[t]; }
  const float* xb = x + (size_t)b*C_*N_ + n0;
  float sum = 0.f, sq = 0.f;
#pragma unroll
  for (int i = 0; i < 48; ++i){
    int c = q + 4*i;
    float v = xb[(size_t)c*N_ + tok];
    tile[tok][c] = v;
    sum += v; sq += v*v;
  }
  red[q][tok] = sum; red[4+q][tok] = sq;
  __syncthreads();
  if (q == 0){
    float s  = red[0][tok]+red[1][tok]+red[2][tok]+red[3][tok];
    float s2 = red[4][tok]+red[5][tok]+red[6][tok]+red[7][tok];
    float mu = s*(1.f/C_);
    float rstd = rsqrtf(s2*(1.f/C_) - mu*mu + 1e-5f);
    red[0][tok] = mu; red[1][tok] = rstd;
  }
  __syncthreads();
  unsigned* yb = reinterpret_cast<unsigned*>(y + ((size_t)bl*N_ + n0)*C_);
#pragma unroll
  for (int i = 0; i < 24; ++i){
    int li = t + 256*i;                 // 6144 u32
    int tk = li / 96, c2 = li % 96;
    int c = 2*c2;
    float v0 = (tile[tk][c]  -red[0][tk])*red[1][tk]*wls[c]   + bls[c];
    float v1 = (tile[tk][c+1]-red[0][tk])*red[1][tk]*wls[c+1] + bls[c+1];
    yb[li] = cvtpk(v0, v1);
  }
}

// ---------------- QKV MFMA GEMM with gather: y bf16 -> qkv bf16 ----------------
__global__ __launch_bounds__(256) void k_qkv(const unsigned short* __restrict__ y,
    const unsigned* __restrict__ idx, const float* __restrict__ wq,
    unsigned short* __restrict__ qkv, int b_off){
  const int NT = (3*C_)/64;  // 9
  int bid = blockIdx.x;
  int bl  = bid / (16*NT);
  int rem = bid % (16*NT);
  int m0  = (rem / NT) * 128;
  int n0  = (rem % NT) * 64;
  int t = threadIdx.x, lane = t & 63;
  int wv = t >> 6, wm = wv & 1, wn = wv >> 1;
  __shared__ unsigned short Al[128][40];
  __shared__ unsigned short Bl[64][40];
  __shared__ int rows[128];
  if (t < 128) rows[t] = load_idx(idx, (b_off+bl)*K_ + m0 + t);
  __syncthreads();
  f32x4 acc[4][2] = {};
  int l15 = lane & 15, lhi = lane >> 4;
  for (int k0 = 0; k0 < C_; k0 += 32){
    {
      int m = t >> 1;
      const unsigned short* src = y + ((size_t)bl*N_ + rows[m])*C_ + k0;
#pragma unroll
      for (int i = 0; i < 4; ++i){
        int kq = (t & 1) + 2*i;
        *reinterpret_cast<ushort4*>(&Al[m][4*kq]) =
            *reinterpret_cast<const ushort4*>(src + 4*kq);
      }
      int n = t >> 2;
      const float* bsrc = wq + (size_t)(n0+n)*C_ + k0;
#pragma unroll
      for (int i = 0; i < 2; ++i){
        int q = (t & 3) + 4*i;
        float4 v = *reinterpret_cast<const float4*>(bsrc + 4*q);
        *reinterpret_cast<uint2*>(&Bl[n][4*q]) =
            make_uint2(cvtpk(v.x, v.y), cvtpk(v.z, v.w));
      }
    }
    __syncthreads();
    bf16x8 af[4], bfr[2];
#pragma unroll
    for (int mf = 0; mf < 4; ++mf)
      af[mf] = *reinterpret_cast<const bf16x8*>(&Al[wm*64 + mf*16 + l15][lhi*8]);
#pragma unroll
    for (int nf = 0; nf < 2; ++nf)
      bfr[nf] = *reinterpret_cast<const bf16x8*>(&Bl[wn*32 + nf*16 + l15][lhi*8]);
#pragma unroll
    for (int mf = 0; mf < 4; ++mf)
#pragma unroll
      for (int nf = 0; nf < 2; ++nf)
        acc[mf][nf] = __builtin_amdgcn_mfma_f32_16x16x32_bf16(af[mf], bfr[nf], acc[mf][nf], 0,0,0);
    __syncthreads();
  }
#pragma unroll
  for (int mf = 0; mf < 4; ++mf){
    int mb = m0 + wm*64 + mf*16 + lhi*4;
#pragma unroll
    for (int nf = 0; nf < 2; ++nf){
      int n = n0 + wn*32 + nf*16 + l15;
#pragma unroll
      for (int r = 0; r < 4; ++r)
        qkv[((size_t)bl*K_ + mb + r)*(3*C_) + n] = f2bf(acc[mf][nf][r]);
    }
  }
}

// ------- attention split-K (NC=2), swapped QK^T, defer-max, cvt_pk -------
__global__ __launch_bounds__(256) void k_attn(const unsigned short* __restrict__ qkv,
    float* __restrict__ po, float* __restrict__ pml, int nb){
  int bid = blockIdx.x;
  int c   = bid & (NC_-1);
  int qt  = (bid >> 1) & 31;
  int bh  = bid >> 6;
  int h = bh % HEADS_, bl = bh / HEADS_;
  int q0 = qt*64;
  int t = threadIdx.x, lane = t & 63, wv = t >> 6;
  int l15 = lane & 15, lhi = lane >> 4;
  const unsigned short* base = qkv + (size_t)bl*K_*(3*C_) + h*HD_;
  __shared__ unsigned short Ql[64][72];
  __shared__ unsigned short Kl[64][72];
  __shared__ unsigned short Vt[64][72];
  __shared__ unsigned short Pl[4][16][72];
  {
    int r = t >> 2, d0 = (t & 3) * 16;
    const uint4* src = reinterpret_cast<const uint4*>(base + (size_t)(q0+r)*(3*C_) + d0);
    *reinterpret_cast<uint4*>(&Ql[r][d0])   = src[0];
    *reinterpret_cast<uint4*>(&Ql[r][d0+8]) = src[1];
  }
  __syncthreads();
  float m_q = -1e30f, l_q = 0.f;
  f32x4 o[4] = {};
  for (int kt0 = c*KC_; kt0 < c*KC_ + KC_; kt0 += 64){
    {
      int r = t >> 2, d0 = (t & 3) * 16;
      const uint4* src = reinterpret_cast<const uint4*>(base + (size_t)(kt0+r)*(3*C_) + C_ + d0);
      *reinterpret_cast<uint4*>(&Kl[r][d0])   = src[0];
      *reinterpret_cast<uint4*>(&Kl[r][d0+8]) = src[1];
      int kp = t & 31, vd0 = (t >> 5) * 8, k = 2*kp;
      const ushort4* v0 = reinterpret_cast<const ushort4*>(base + (size_t)(kt0+k)*(3*C_)   + 2*C_ + vd0);
      const ushort4* v1 = reinterpret_cast<const ushort4*>(base + (size_t)(kt0+k+1)*(3*C_) + 2*C_ + vd0);
      ushort4 a0 = v0[0], a1 = v0[1], b0 = v1[0], b1 = v1[1];
      unsigned short va[8] = {a0.x,a0.y,a0.z,a0.w,a1.x,a1.y,a1.z,a1.w};
      unsigned short vb[8] = {b0.x,b0.y,b0.z,b0.w,b1.x,b1.y,b1.z,b1.w};
#pragma unroll
      for (int j = 0; j < 8; ++j){
        unsigned u = (unsigned)va[j] | ((unsigned)vb[j] << 16);
        *reinterpret_cast<unsigned*>(&Vt[vd0+j][k]) = u;
      }
    }
    __syncthreads();
    f32x4 s[4] = {};
    __builtin_amdgcn_s_setprio(1);
#pragma unroll
    for (int kt = 0; kt < 2; ++kt){
      bf16x8 qf = *reinterpret_cast<const bf16x8*>(&Ql[wv*16 + l15][kt*32 + lhi*8]);
#pragma unroll
      for (int nt = 0; nt < 4; ++nt){
        bf16x8 kf = *reinterpret_cast<const bf16x8*>(&Kl[nt*16 + l15][kt*32 + lhi*8]);
        s[nt] = __builtin_amdgcn_mfma_f32_16x16x32_bf16(kf, qf, s[nt], 0,0,0);
      }
    }
    __builtin_amdgcn_s_setprio(0);
    float mx = s[0][0];
#pragma unroll
    for (int nt = 0; nt < 4; ++nt)
#pragma unroll
      for (int reg = 0; reg < 4; ++reg) mx = fmaxf(mx, s[nt][reg]);
    mx = fmaxf(mx, __shfl_xor(mx, 16));
    mx = fmaxf(mx, __shfl_xor(mx, 32));
    mx *= 0.125f;
    bool skip = __all(mx <= m_q + 8.f);
    if (!skip){
      float mn = fmaxf(m_q, mx);
      float corr = __expf(m_q - mn);
      l_q *= corr;
      float cr[4];
#pragma unroll
      for (int reg = 0; reg < 4; ++reg) cr[reg] = __shfl(corr, lhi*4 + reg);
#pragma unroll
      for (int nt = 0; nt < 4; ++nt)
#pragma unroll
        for (int reg = 0; reg < 4; ++reg) o[nt][reg] *= cr[reg];
      m_q = mn;
    }
    float ls = 0.f;
#pragma unroll
    for (int nt = 0; nt < 4; ++nt){
      float p0 = __expf(fmaf(s[nt][0], 0.125f, -m_q));
      float p1 = __expf(fmaf(s[nt][1], 0.125f, -m_q));
      float p2 = __expf(fmaf(s[nt][2], 0.125f, -m_q));
      float p3 = __expf(fmaf(s[nt][3], 0.125f, -m_q));
      ls += (p0 + p1) + (p2 + p3);
      uint2 uu;
      uu.x = cvtpk(p0, p1);
      uu.y = cvtpk(p2, p3);
      *reinterpret_cast<uint2*>(&Pl[wv][l15][nt*16 + lhi*4]) = uu;
    }
    ls += __shfl_xor(ls, 16);
    ls += __shfl_xor(ls, 32);
    l_q += ls;
    __threadfence_block();
    __builtin_amdgcn_s_setprio(1);
#pragma unroll
    for (int kt = 0; kt < 2; ++kt){
      bf16x8 pa = *reinterpret_cast<const bf16x8*>(&Pl[wv][l15][kt*32 + lhi*8]);
#pragma unroll
      for (int nt = 0; nt < 4; ++nt){
        bf16x8 vb = *reinterpret_cast<const bf16x8*>(&Vt[nt*16 + l15][kt*32 + lhi*8]);
        o[nt] = __builtin_amdgcn_mfma_f32_16x16x32_bf16(pa, vb, o[nt], 0,0,0);
      }
    }
    __builtin_amdgcn_s_setprio(0);
    __syncthreads();
  }
  int R = nb*HEADS_*K_;
  int rowb = (bl*HEADS_ + h)*K_;
#pragma unroll
  for (int reg = 0; reg < 4; ++reg){
    int rq = rowb + q0 + wv*16 + lhi*4 + reg;
#pragma unroll
    for (int nt = 0; nt < 4; ++nt)
      po[((size_t)c*R + rq)*HD_ + nt*16 + l15] = o[nt][reg];
  }
  if (lhi == 0){
    int rq = rowb + q0 + wv*16 + l15;
    *reinterpret_cast<float2*>(pml + 2*((size_t)c*R + rq)) = make_float2(m_q, l_q);
  }
}

// ------- proj MFMA GEMM with fused split-K merge + scatter into y (bf16) -------
// A-tile staged directly from po/pml: head h = k0>>6 is uniform per k0 chunk.
__global__ __launch_bounds__(256) void k_proj(const float* __restrict__ po,
    const float* __restrict__ pml, const unsigned* __restrict__ idx,
    const float* __restrict__ pw, const float* __restrict__ pb,
    unsigned short* __restrict__ y, int b_off, int nb){
  const int NT = C_/64;   // 3
  int bid = blockIdx.x;
  int bl  = bid / (16*NT);
  int rem = bid % (16*NT);
  int m0  = (rem / NT) * 128;
  int n0  = (rem % NT) * 64;
  int t = threadIdx.x, lane = t & 63;
  int wv = t >> 6, wm = wv & 1, wn = wv >> 1;
  __shared__ unsigned short Al[128][40];
  __shared__ unsigned short Bl[64][40];
  __shared__ int rows[128];
  if (t < 128) rows[t] = load_idx(idx, (b_off+bl)*K_ + m0 + t);
  __syncthreads();
  int R = nb*HEADS_*K_;
  f32x4 acc[4][2] = {};
  int l15 = lane & 15, lhi = lane >> 4;
  for (int k0 = 0; k0 < C_; k0 += 32){
    {
      int hh = k0 >> 6, d0 = k0 & 63;
      int m = t >> 1;
      int rq = (bl*HEADS_ + hh)*K_ + m0 + m;
      float2 s0 = *reinterpret_cast<const float2*>(pml + 2*(size_t)rq);
      float2 s1 = *reinterpret_cast<const float2*>(pml + 2*((size_t)R + rq));
      float M  = fmaxf(s0.x, s1.x);
      float e0 = __expf(s0.x - M), e1 = __expf(s1.x - M);
      float Li = __builtin_amdgcn_rcpf(fmaf(s0.y, e0, s1.y*e1));
      float w0 = e0*Li, w1 = e1*Li;
      const float* p0 = po + (size_t)rq*HD_ + d0;
      const float* p1 = po + ((size_t)R + rq)*HD_ + d0;
#pragma unroll
      for (int i = 0; i < 4; ++i){
        int kq = (t & 1) + 2*i;
        float4 a = *reinterpret_cast<const float4*>(p0 + 4*kq);
        float4 b = *reinterpret_cast<const float4*>(p1 + 4*kq);
        *reinterpret_cast<uint2*>(&Al[m][4*kq]) = make_uint2(
            cvtpk(fmaf(w0, a.x, w1*b.x), fmaf(w0, a.y, w1*b.y)),
            cvtpk(fmaf(w0, a.z, w1*b.z), fmaf(w0, a.w, w1*b.w)));
      }
      int n = t >> 2;
      const float* bsrc = pw + (size_t)(n0+n)*C_ + k0;
#pragma unroll
      for (int i = 0; i < 2; ++i){
        int q = (t & 3) + 4*i;
        float4 v = *reinterpret_cast<const float4*>(bsrc + 4*q);
        *reinterpret_cast<uint2*>(&Bl[n][4*q]) =
            make_uint2(cvtpk(v.x, v.y), cvtpk(v.z, v.w));
      }
    }
    __syncthreads();
    bf16x8 af[4], bfr[2];
#pragma unroll
    for (int mf = 0; mf < 4; ++mf)
      af[mf] = *reinterpret_cast<const bf16x8*>(&Al[wm*64 + mf*16 + l15][lhi*8]);
#pragma unroll
    for (int nf = 0; nf < 2; ++nf)
      bfr[nf] = *reinterpret_cast<const bf16x8*>(&Bl[wn*32 + nf*16 + l15][lhi*8]);
#pragma unroll
    for (int mf = 0; mf < 4; ++mf)
#pragma unroll
      for (int nf = 0; nf < 2; ++nf)
        acc[mf][nf] = __builtin_amdgcn_mfma_f32_16x16x32_bf16(af[mf], bfr[nf], acc[mf][nf], 0,0,0);
    __syncthreads();
  }
#pragma unroll
  for (int mf = 0; mf < 4; ++mf){
    int mb = wm*64 + mf*16 + lhi*4;
#pragma unroll
    for (int nf = 0; nf < 2; ++nf){
      int n = n0 + wn*32 + nf*16 + l15;
      float bv = pb[n];
#pragma unroll
      for (int r = 0; r < 4; ++r)
        y[((size_t)bl*N_ + rows[mb + r])*C_ + n] = f2bf(acc[mf][nf][r] + bv);
    }
  }
}

// ---------------- residual + LN2 -> ln2t (B,C,N) [== d_out] ----------------
__global__ __launch_bounds__(256) void k_ln2(const float* __restrict__ x,
    const unsigned short* __restrict__ y, const float* __restrict__ w,
    const float* __restrict__ bias, float* __restrict__ ln2t, int b_off){
  int blk = blockIdx.x;
  int bl = blk >> 8;
  int b  = b_off + bl;
  int n0 = (blk & 255) * 64;
  int t  = threadIdx.x;
  int tok = t & 63, q = t >> 6;
  __shared__ float tile[64][C_+1];
  __shared__ float red[8][64];
  __shared__ float wls[C_], bls[C_];
  if (t < C_){ wls[t] = w[t]; bls[t] = bias[t]; }
  const unsigned* yb = reinterpret_cast<const unsigned*>(y + ((size_t)bl*N_ + n0)*C_);
#pragma unroll
  for (int i = 0; i < 24; ++i){
    int li = t + 256*i;
    unsigned u = yb[li];
    int tk = li / 96, c2 = li % 96;
    tile[tk][2*c2]   = bf2f((unsigned short)(u & 0xffffu));
    tile[tk][2*c2+1] = bf2f((unsigned short)(u >> 16));
  }
  __syncthreads();
  const float* xb = x + (size_t)b*C_*N_ + n0;
  float sum = 0.f, sq = 0.f;
#pragma unroll
  for (int i = 0; i < 48; ++i){
    int c = q + 4*i;
    float v = xb[(size_t)c*N_ + tok] + tile[tok][c];
    tile[tok][c] = v;
    sum += v; sq += v*v;
  }
  red[q][tok] = sum; red[4+q][tok] = sq;
  __syncthreads();
  if (q == 0){
    float s  = red[0][tok]+red[1][tok]+red[2][tok]+red[3][tok];
    float s2 = red[4][tok]+red[5][tok]+red[6][tok]+red[7][tok];
    float mu = s*(1.f/C_);
    float rstd = rsqrtf(s2*(1.f/C_) - mu*mu + 1e-5f);
    red[0][tok] = mu; red[1][tok] = rstd;
  }
  __syncthreads();
  float* ob = ln2t + (size_t)b*C_*N_ + n0;
  float mu = red[0][tok], rstd = red[1][tok];
#pragma unroll
  for (int i = 0; i < 48; ++i){
    int c = q + 4*i;
    ob[(size_t)c*N_ + tok] = (tile[tok][c]-mu)*rstd*wls[c] + bls[c];
  }
}

// ------- fc1 MFMA: block = 128-token m-tile x 384-hid half, loop 6 n-tiles -------
__global__ __launch_bounds__(256) void k_fc1(const float* __restrict__ ln2t,
    const float* __restrict__ wgt, const float* __restrict__ bias,
    unsigned short* __restrict__ h1, int b_off){
  int bid = blockIdx.x;
  int bl  = bid >> 8;                  // slot-local batch
  int rem = bid & 255;
  int m0  = (rem >> 1) * 128;
  int nh  = (rem & 1) * 6;             // n-tile half
  int t = threadIdx.x, lane = t & 63;
  int wv = t >> 6, wm = wv & 1, wn = wv >> 1;
  int l15 = lane & 15, lhi = lane >> 4;
  __shared__ unsigned short Al[128][200];
  __shared__ unsigned short Bl[64][200];
  const float* a = ln2t + (size_t)(b_off+bl)*C_*N_ + m0;
  unsigned short* hb = h1 + (size_t)bl*HID_*N_;
  {
    int m = t & 127, half = t >> 7;
#pragma unroll
    for (int i = 0; i < 48; ++i){
      int p = half + 2*i;                    // 0..95
      float v0 = a[(size_t)(2*p)*N_ + m];
      float v1 = a[(size_t)(2*p+1)*N_ + m];
      *reinterpret_cast<unsigned*>(&Al[m][2*p]) = cvtpk(v0, v1);
    }
  }
  for (int nt = 0; nt < 6; ++nt){
    int n0 = (nh + nt)*64;
    __syncthreads();
    {
      int n = t >> 2;
      const float* bsrc = wgt + (size_t)(n0+n)*C_;
#pragma unroll
      for (int i = 0; i < 12; ++i){
        int q = (t & 3) + 4*i;               // 0..47 float4 segs
        float4 v = *reinterpret_cast<const float4*>(bsrc + 4*q);
        *reinterpret_cast<uint2*>(&Bl[n][4*q]) =
            make_uint2(cvtpk(v.x, v.y), cvtpk(v.z, v.w));
      }
    }
    __syncthreads();
    f32x4 acc[4][2] = {};
#pragma unroll
    for (int ks = 0; ks < 6; ++ks){
      bf16x8 af[4], bfr[2];
#pragma unroll
      for (int mf = 0; mf < 4; ++mf)
        af[mf] = *reinterpret_cast<const bf16x8*>(&Al[wm*64 + mf*16 + l15][ks*32 + lhi*8]);
#pragma unroll
      for (int nf = 0; nf < 2; ++nf)
        bfr[nf] = *reinterpret_cast<const bf16x8*>(&Bl[wn*32 + nf*16 + l15][ks*32 + lhi*8]);
#pragma unroll
      for (int mf = 0; mf < 4; ++mf)
#pragma unroll
        for (int nf = 0; nf < 2; ++nf)
          acc[mf][nf] = __builtin_amdgcn_mfma_f32_16x16x32_bf16(af[mf], bfr[nf], acc[mf][nf], 0,0,0);
    }
#pragma unroll
    for (int mf = 0; mf < 4; ++mf){
      int mb = m0 + wm*64 + mf*16 + lhi*4;
#pragma unroll
      for (int nf = 0; nf < 2; ++nf){
        int n = n0 + wn*32 + nf*16 + l15;
        float bv = bias[n];
        uint2 pk;
        pk.x = cvtpk(acc[mf][nf][0] + bv, acc[mf][nf][1] + bv);
        pk.y = cvtpk(acc[mf][nf][2] + bv, acc[mf][nf][3] + bv);
        *reinterpret_cast<uint2*>(&hb[(size_t)n*N_ + mb]) = pk;
      }
    }
  }
}

// ------- fused depthwise3x3+GELU+fc2+residual: block = 1 image row x 192 ch -------
// 512 thr, 51.7KB LDS; single Ht buffer, 2 barriers/chunk, reg-prefetched h1
__global__ __launch_bounds__(512) void k_fc2f(const unsigned short* __restrict__ h1,
    const float* __restrict__ dw, const float* __restrict__ wgt,
    const float* __restrict__ bias, float* __restrict__ out, int b_off){
  int nwg = gridDim.x;
  int cpx = nwg >> 3;
  int bid = (blockIdx.x & 7)*cpx + (blockIdx.x >> 3);  // contiguous rows per XCD
  int bl  = bid >> 7;            // slot-local batch
  int r   = bid & 127;           // image row
  int b   = b_off + bl;
  int t = threadIdx.x, lane = t & 63, wv = t >> 6;
  int wm = wv & 1, wn = wv >> 1;
  int l15 = lane & 15, lhi = lane >> 4;
  __shared__ unsigned short Ht[32][3][136];     // 26.1KB; ch-stride 816B (51x16B)
  __shared__ unsigned short Alc[128][40];       // 10.2KB
  __shared__ unsigned short Bl[192][40];        // 15.4KB
  const unsigned short* h1b = h1 + (size_t)bl*HID_*N_;
  f32x4 acc[4][3] = {};
  int cch = t & 31, j0 = (t >> 5) * 8;          // conv: channel, col base
  // ---- hoisted per-thread staging state ----
  const unsigned short* gp[3]; unsigned short* lp[3]; bool gok[3];
#pragma unroll
  for (int i = 0; i < 3; ++i){
    int li = t + 512*i;                         // 0..1535
    int ch = li / 48, rm = li % 48, dy = rm >> 4, seg = rm & 15;
    int rr = r - 1 + dy;
    gok[i] = (rr >= 0 && rr < H_);
    gp[i] = h1b + (size_t)ch*N_ + (gok[i] ? rr : 0)*W_ + seg*8;
    lp[i] = &Ht[ch][dy][seg*8];
  }
  const float* wgp[3]; unsigned short* blp[3];
#pragma unroll
  for (int i = 0; i < 3; ++i){
    int row = (t >> 3) + 64*i, seg = t & 7;
    wgp[i] = wgt + (size_t)row*HID_ + seg*4;
    blp[i] = &Bl[row][seg*4];
  }
  const float* dwp = dw + (size_t)cch*9;        // advance +288 per chunk
  uint4 hr[3];
  auto hload = [&](){
#pragma unroll
    for (int i = 0; i < 3; ++i)
      hr[i] = gok[i] ? *reinterpret_cast<const uint4*>(gp[i]) : make_uint4(0u,0u,0u,0u);
#pragma unroll
    for (int i = 0; i < 3; ++i) gp[i] += 32*N_;
  };
  // prologue: chunk 0 into Ht, prefetch chunk 1 into regs
  hload();
#pragma unroll
  for (int i = 0; i < 3; ++i) *reinterpret_cast<uint4*>(lp[i]) = hr[i];
  hload();
  for (int c24 = 0; c24 < 24; ++c24){
    __syncthreads();                  // A: Ht(c) visible; prev MFMA done
    // stage Bl direct from global (L2-hot weights)
#pragma unroll
    for (int i = 0; i < 3; ++i){
      float4 v = *reinterpret_cast<const float4*>(wgp[i]);
      wgp[i] += 32;
      *reinterpret_cast<uint2*>(blp[i]) =
          make_uint2(cvtpk(v.x, v.y), cvtpk(v.z, v.w));
    }
    // conv 3x3 + fast GELU from Ht -> Alc; dw direct (broadcast-hot)
    {
      float w9[9];
#pragma unroll
      for (int i = 0; i < 9; ++i) w9[i] = dwp[i];
      dwp += 288;
      const unsigned short* hp = &Ht[cch][0][j0];
      float s[8] = {0.f,0.f,0.f,0.f,0.f,0.f,0.f,0.f};
#pragma unroll
      for (int dy = 0; dy < 3; ++dy){
        const unsigned short* rp = hp + dy*136;
        bf16x8 mid = *reinterpret_cast<const bf16x8*>(rp);
        float v[10];
        v[0] = (j0 > 0)   ? bf2f(rp[-1]) : 0.f;
        v[9] = (j0 < 120) ? bf2f(rp[8])  : 0.f;
#pragma unroll
        for (int j = 0; j < 8; ++j) v[1+j] = bf2f((unsigned short)mid[j]);
        float wa = w9[3*dy], wb = w9[3*dy+1], wc = w9[3*dy+2];
#pragma unroll
        for (int j = 0; j < 8; ++j)
          s[j] += v[j]*wa + v[j+1]*wb + v[j+2]*wc;
      }
#pragma unroll
      for (int j = 0; j < 8; ++j)
        Alc[j0+j][cch] = f2bf(gelu_fast(s[j]));
    }
    __syncthreads();                  // B: Alc+Bl visible; Ht reads complete
    // write prefetched chunk c+1 into Ht (dead now); prefetch c+2
    if (c24 < 23){
#pragma unroll
      for (int i = 0; i < 3; ++i)
        *reinterpret_cast<uint4*>(lp[i]) = hr[i];
      if (c24 < 22) hload();
    }
    // MFMA: wave = 64-tok half (wm) x 48-ch quarter (wn)
    bf16x8 af[4], bfr[3];
#pragma unroll
    for (int mf = 0; mf < 4; ++mf)
      af[mf] = *reinterpret_cast<const bf16x8*>(&Alc[wm*64 + mf*16 + l15][lhi*8]);
#pragma unroll
    for (int nf = 0; nf < 3; ++nf)
      bfr[nf] = *reinterpret_cast<const bf16x8*>(&Bl[wn*48 + nf*16 + l15][lhi*8]);
    __builtin_amdgcn_s_setprio(1);
#pragma unroll
    for (int mf = 0; mf < 4; ++mf)
#pragma unroll
      for (int nf = 0; nf < 3; ++nf)
        acc[mf][nf] = __builtin_amdgcn_mfma_f32_16x16x32_bf16(af[mf], bfr[nf], acc[mf][nf], 0,0,0);
    __builtin_amdgcn_s_setprio(0);
  }
  // epilogue: += bias + residual (out holds ln2t)
#pragma unroll
  for (int mf = 0; mf < 4; ++mf){
    int tok = r*W_ + wm*64 + mf*16 + lhi*4;
#pragma unroll
    for (int nf = 0; nf < 3; ++nf){
      int oc = wn*48 + nf*16 + l15;
      float bv = bias[oc];
      size_t off = ((size_t)b*C_ + oc)*N_ + tok;
      float4 rr = *reinterpret_cast<const float4*>(out + off);
      float4 v = make_float4(rr.x + acc[mf][nf][0] + bv, rr.y + acc[mf][nf][1] + bv,
                             rr.z + acc[mf][nf][2] + bv, rr.w + acc[mf][nf][3] + bv);
      *reinterpret_cast<float4*>(out + off) = v;
    }
  }
}

extern "C" void kernel_launch(void* const* d_in, const int* in_sizes, int n_in,
                              void* d_out, int out_size, void* d_ws, size_t ws_size,
                              hipStream_t stream) {
  const float*    x      = (const float*)d_in[0];
  const unsigned* idx    = (const unsigned*)d_in[1];
  const float*    ln1_w  = (const float*)d_in[2];
  const float*    ln1_b  = (const float*)d_in[3];
  const float*    qkv_w  = (const float*)d_in[4];
  const float*    proj_w = (const float*)d_in[5];
  const float*    proj_b = (const float*)d_in[6];
  const float*    ln2_w  = (const float*)d_in[7];
  const float*    ln2_b  = (const float*)d_in[8];
  const float*    fc1_w  = (const float*)d_in[9];
  const float*    fc1_b  = (const float*)d_in[10];
  const float*    dw_w   = (const float*)d_in[11];
  const float*    fc2_w  = (const float*)d_in[12];
  const float*    fc2_b  = (const float*)d_in[13];
  float* out = (float*)d_out;          // doubles as ln2t (B,C,N) f32

  const size_t SZY = (size_t)N_*C_*2;              // y bf16: 6.29 MB/batch
  const size_t SZQ = (size_t)K_*3*C_*2;            // 2.36
  const size_t SZA = (size_t)K_*C_*2;              // 0.79 (unused slot, layout kept)
  const size_t SZO = (size_t)NC_*HEADS_*K_*HD_*4;  // 3.15/batch
  const size_t SZH = (size_t)HID_*N_*2;            // 25.17/batch
  int nb = (ws_size >= (size_t)B_*SZH) ? B_ : 1;   // deterministic

  char* ws = (char*)d_ws;
  unsigned short* y16  = (unsigned short*)ws;
  unsigned short* qkvb = (unsigned short*)(ws + (size_t)nb*SZY);
  float*          po   = (float*)(ws + (size_t)nb*(SZY+SZQ+SZA));
  float*          pml  = (float*)(ws + (size_t)nb*(SZY+SZQ+SZA+SZO));
  unsigned short* h1s  = (unsigned short*)ws;      // MLP phase (front dead): nb slots

  for (int b0 = 0; b0 < B_; b0 += nb){
    k_ln1   <<<nb*256,             256, 0, stream>>>(x, ln1_w, ln1_b, y16, b0);
    k_qkv   <<<nb*16*9,            256, 0, stream>>>(y16, idx, qkv_w, qkvb, b0);
    k_attn  <<<nb*HEADS_*32*NC_,   256, 0, stream>>>(qkvb, po, pml, nb);
    k_proj  <<<nb*16*3,            256, 0, stream>>>(po, pml, idx, proj_w, proj_b, y16, b0, nb);
    k_ln2   <<<nb*256,             256, 0, stream>>>(x, y16, ln2_w, ln2_b, out, b0);
    k_fc1   <<<nb*256,             256, 0, stream>>>(out, fc1_w, fc1_b, h1s, b0);
    k_fc2f  <<<nb*128,             512, 0, stream>>>(h1s, dw_w, fc2_w, fc2_b, out, b0);
  }
}

// Round 23
// 234.298 us; speedup vs baseline: 1.1796x; 1.0004x over previous
//
#include <hip/hip_runtime.h>

#define B_ 4
#define C_ 192
#define H_ 128
#define W_ 128
#define N_ (H_*W_)      // 16384
#define K_ 2048
#define HEADS_ 3
#define HD_ 64
#define HID_ 768
#define NC_ 2           // attention split-K chunks
#define KC_ (K_/NC_)    // 1024

typedef __attribute__((ext_vector_type(4))) float f32x4;
typedef __attribute__((ext_vector_type(8))) short bf16x8;

__device__ __forceinline__ unsigned short f2bf(float f){
  unsigned int u = __float_as_uint(f);
  u += 0x7FFFu + ((u >> 16) & 1u);
  return (unsigned short)(u >> 16);
}
__device__ __forceinline__ float bf2f(unsigned short s){
  return __uint_as_float(((unsigned int)s) << 16);
}
__device__ __forceinline__ unsigned cvtpk(float lo, float hi){
  unsigned r;
  asm("v_cvt_pk_bf16_f32 %0, %1, %2" : "=v"(r) : "v"(lo), "v"(hi));
  return r;
}
// sigmoid-form GELU: x * sigma(1.702x); ~5 VALU via HW rcp. |err| <= ~0.02
__device__ __forceinline__ float gelu_fast(float x){
  float e = __expf(-1.702f*x);
  return x * __builtin_amdgcn_rcpf(1.f + e);
}

__device__ __forceinline__ int load_idx(const unsigned* __restrict__ ip, int pos){
  bool is64 = (ip[1]==0u) & (ip[3]==0u) & (ip[5]==0u) & (ip[7]==0u);
  int v = is64 ? (int)ip[2*pos] : (int)ip[pos];
  return min(max(v, 0), N_-1);
}

// ---------------- LN1: x (B,C,N) -> y bf16 (nb,N,C) ----------------
__global__ __launch_bounds__(256) void k_ln1(const float* __restrict__ x,
    const float* __restrict__ w, const float* __restrict__ bias,
    unsigned short* __restrict__ y, int b_off){
  int blk = blockIdx.x;
  int bl = blk >> 8;
  int b  = b_off + bl;
  int n0 = (blk & 255) * 64;
  int t  = threadIdx.x;
  int tok = t & 63, q = t >> 6;
  __shared__ float tile[64][C_+1];
  __shared__ float red[8][64];
  __shared__ float wls[C_], bls[C_];
  if (t < C_){ wls[t] = w[t]; bls[t] = bias[t]; }
  const float* xb = x + (size_t)b*C_*N_ + n0;
  float sum = 0.f, sq = 0.f;
#pragma unroll
  for (int i = 0; i < 48; ++i){
    int c = q + 4*i;
    float v = xb[(size_t)c*N_ + tok];
    tile[tok][c] = v;
    sum += v; sq += v*v;
  }
  red[q][tok] = sum; red[4+q][tok] = sq;
  __syncthreads();
  if (q == 0){
    float s  = red[0][tok]+red[1][tok]+red[2][tok]+red[3][tok];
    float s2 = red[4][tok]+red[5][tok]+red[6][tok]+red[7][tok];
    float mu = s*(1.f/C_);
    float rstd = rsqrtf(s2*(1.f/C_) - mu*mu + 1e-5f);
    red[0][tok] = mu; red[1][tok] = rstd;
  }
  __syncthreads();
  unsigned* yb = reinterpret_cast<unsigned*>(y + ((size_t)bl*N_ + n0)*C_);
#pragma unroll
  for (int i = 0; i < 24; ++i){
    int li = t + 256*i;                 // 6144 u32
    int tk = li / 96, c2 = li % 96;
    int c = 2*c2;
    float v0 = (tile[tk][c]  -red[0][tk])*red[1][tk]*wls[c]   + bls[c];
    float v1 = (tile[tk][c+1]-red[0][tk])*red[1][tk]*wls[c+1] + bls[c+1];
    yb[li] = cvtpk(v0, v1);
  }
}

// ---------------- QKV MFMA GEMM with gather: y bf16 -> qkv bf16 ----------------
__global__ __launch_bounds__(256) void k_qkv(const unsigned short* __restrict__ y,
    const unsigned* __restrict__ idx, const float* __restrict__ wq,
    unsigned short* __restrict__ qkv, int b_off){
  const int NT = (3*C_)/64;  // 9
  int bid = blockIdx.x;
  int bl  = bid / (16*NT);
  int rem = bid % (16*NT);
  int m0  = (rem / NT) * 128;
  int n0  = (rem % NT) * 64;
  int t = threadIdx.x, lane = t & 63;
  int wv = t >> 6, wm = wv & 1, wn = wv >> 1;
  __shared__ unsigned short Al[128][40];
  __shared__ unsigned short Bl[64][40];
  __shared__ int rows[128];
  if (t < 128) rows[t] = load_idx(idx, (b_off+bl)*K_ + m0 + t);
  __syncthreads();
  f32x4 acc[4][2] = {};
  int l15 = lane & 15, lhi = lane >> 4;
  for (int k0 = 0; k0 < C_; k0 += 32){
    {
      int m = t >> 1;
      const unsigned short* src = y + ((size_t)bl*N_ + rows[m])*C_ + k0;
#pragma unroll
      for (int i = 0; i < 4; ++i){
        int kq = (t & 1) + 2*i;
        *reinterpret_cast<ushort4*>(&Al[m][4*kq]) =
            *reinterpret_cast<const ushort4*>(src + 4*kq);
      }
      int n = t >> 2;
      const float* bsrc = wq + (size_t)(n0+n)*C_ + k0;
#pragma unroll
      for (int i = 0; i < 2; ++i){
        int q = (t & 3) + 4*i;
        float4 v = *reinterpret_cast<const float4*>(bsrc + 4*q);
        *reinterpret_cast<uint2*>(&Bl[n][4*q]) =
            make_uint2(cvtpk(v.x, v.y), cvtpk(v.z, v.w));
      }
    }
    __syncthreads();
    bf16x8 af[4], bfr[2];
#pragma unroll
    for (int mf = 0; mf < 4; ++mf)
      af[mf] = *reinterpret_cast<const bf16x8*>(&Al[wm*64 + mf*16 + l15][lhi*8]);
#pragma unroll
    for (int nf = 0; nf < 2; ++nf)
      bfr[nf] = *reinterpret_cast<const bf16x8*>(&Bl[wn*32 + nf*16 + l15][lhi*8]);
#pragma unroll
    for (int mf = 0; mf < 4; ++mf)
#pragma unroll
      for (int nf = 0; nf < 2; ++nf)
        acc[mf][nf] = __builtin_amdgcn_mfma_f32_16x16x32_bf16(af[mf], bfr[nf], acc[mf][nf], 0,0,0);
    __syncthreads();
  }
#pragma unroll
  for (int mf = 0; mf < 4; ++mf){
    int mb = m0 + wm*64 + mf*16 + lhi*4;
#pragma unroll
    for (int nf = 0; nf < 2; ++nf){
      int n = n0 + wn*32 + nf*16 + l15;
#pragma unroll
      for (int r = 0; r < 4; ++r)
        qkv[((size_t)bl*K_ + mb + r)*(3*C_) + n] = f2bf(acc[mf][nf][r]);
    }
  }
}

// ------- attention split-K (NC=2), swapped QK^T, defer-max, cvt_pk -------
__global__ __launch_bounds__(256) void k_attn(const unsigned short* __restrict__ qkv,
    float* __restrict__ po, float* __restrict__ pml, int nb){
  int bid = blockIdx.x;
  int c   = bid & (NC_-1);
  int qt  = (bid >> 1) & 31;
  int bh  = bid >> 6;
  int h = bh % HEADS_, bl = bh / HEADS_;
  int q0 = qt*64;
  int t = threadIdx.x, lane = t & 63, wv = t >> 6;
  int l15 = lane & 15, lhi = lane >> 4;
  const unsigned short* base = qkv + (size_t)bl*K_*(3*C_) + h*HD_;
  __shared__ unsigned short Ql[64][72];
  __shared__ unsigned short Kl[64][72];
  __shared__ unsigned short Vt[64][72];
  __shared__ unsigned short Pl[4][16][72];
  {
    int r = t >> 2, d0 = (t & 3) * 16;
    const uint4* src = reinterpret_cast<const uint4*>(base + (size_t)(q0+r)*(3*C_) + d0);
    *reinterpret_cast<uint4*>(&Ql[r][d0])   = src[0];
    *reinterpret_cast<uint4*>(&Ql[r][d0+8]) = src[1];
  }
  __syncthreads();
  float m_q = -1e30f, l_q = 0.f;
  f32x4 o[4] = {};
  for (int kt0 = c*KC_; kt0 < c*KC_ + KC_; kt0 += 64){
    {
      int r = t >> 2, d0 = (t & 3) * 16;
      const uint4* src = reinterpret_cast<const uint4*>(base + (size_t)(kt0+r)*(3*C_) + C_ + d0);
      *reinterpret_cast<uint4*>(&Kl[r][d0])   = src[0];
      *reinterpret_cast<uint4*>(&Kl[r][d0+8]) = src[1];
      int kp = t & 31, vd0 = (t >> 5) * 8, k = 2*kp;
      const ushort4* v0 = reinterpret_cast<const ushort4*>(base + (size_t)(kt0+k)*(3*C_)   + 2*C_ + vd0);
      const ushort4* v1 = reinterpret_cast<const ushort4*>(base + (size_t)(kt0+k+1)*(3*C_) + 2*C_ + vd0);
      ushort4 a0 = v0[0], a1 = v0[1], b0 = v1[0], b1 = v1[1];
      unsigned short va[8] = {a0.x,a0.y,a0.z,a0.w,a1.x,a1.y,a1.z,a1.w};
      unsigned short vb[8] = {b0.x,b0.y,b0.z,b0.w,b1.x,b1.y,b1.z,b1.w};
#pragma unroll
      for (int j = 0; j < 8; ++j){
        unsigned u = (unsigned)va[j] | ((unsigned)vb[j] << 16);
        *reinterpret_cast<unsigned*>(&Vt[vd0+j][k]) = u;
      }
    }
    __syncthreads();
    f32x4 s[4] = {};
    __builtin_amdgcn_s_setprio(1);
#pragma unroll
    for (int kt = 0; kt < 2; ++kt){
      bf16x8 qf = *reinterpret_cast<const bf16x8*>(&Ql[wv*16 + l15][kt*32 + lhi*8]);
#pragma unroll
      for (int nt = 0; nt < 4; ++nt){
        bf16x8 kf = *reinterpret_cast<const bf16x8*>(&Kl[nt*16 + l15][kt*32 + lhi*8]);
        s[nt] = __builtin_amdgcn_mfma_f32_16x16x32_bf16(kf, qf, s[nt], 0,0,0);
      }
    }
    __builtin_amdgcn_s_setprio(0);
    float mx = s[0][0];
#pragma unroll
    for (int nt = 0; nt < 4; ++nt)
#pragma unroll
      for (int reg = 0; reg < 4; ++reg) mx = fmaxf(mx, s[nt][reg]);
    mx = fmaxf(mx, __shfl_xor(mx, 16));
    mx = fmaxf(mx, __shfl_xor(mx, 32));
    mx *= 0.125f;
    bool skip = __all(mx <= m_q + 8.f);
    if (!skip){
      float mn = fmaxf(m_q, mx);
      float corr = __expf(m_q - mn);
      l_q *= corr;
      float cr[4];
#pragma unroll
      for (int reg = 0; reg < 4; ++reg) cr[reg] = __shfl(corr, lhi*4 + reg);
#pragma unroll
      for (int nt = 0; nt < 4; ++nt)
#pragma unroll
        for (int reg = 0; reg < 4; ++reg) o[nt][reg] *= cr[reg];
      m_q = mn;
    }
    float ls = 0.f;
#pragma unroll
    for (int nt = 0; nt < 4; ++nt){
      float p0 = __expf(fmaf(s[nt][0], 0.125f, -m_q));
      float p1 = __expf(fmaf(s[nt][1], 0.125f, -m_q));
      float p2 = __expf(fmaf(s[nt][2], 0.125f, -m_q));
      float p3 = __expf(fmaf(s[nt][3], 0.125f, -m_q));
      ls += (p0 + p1) + (p2 + p3);
      uint2 uu;
      uu.x = cvtpk(p0, p1);
      uu.y = cvtpk(p2, p3);
      *reinterpret_cast<uint2*>(&Pl[wv][l15][nt*16 + lhi*4]) = uu;
    }
    ls += __shfl_xor(ls, 16);
    ls += __shfl_xor(ls, 32);
    l_q += ls;
    __threadfence_block();
    __builtin_amdgcn_s_setprio(1);
#pragma unroll
    for (int kt = 0; kt < 2; ++kt){
      bf16x8 pa = *reinterpret_cast<const bf16x8*>(&Pl[wv][l15][kt*32 + lhi*8]);
#pragma unroll
      for (int nt = 0; nt < 4; ++nt){
        bf16x8 vb = *reinterpret_cast<const bf16x8*>(&Vt[nt*16 + l15][kt*32 + lhi*8]);
        o[nt] = __builtin_amdgcn_mfma_f32_16x16x32_bf16(pa, vb, o[nt], 0,0,0);
      }
    }
    __builtin_amdgcn_s_setprio(0);
    __syncthreads();
  }
  int R = nb*HEADS_*K_;
  int rowb = (bl*HEADS_ + h)*K_;
#pragma unroll
  for (int reg = 0; reg < 4; ++reg){
    int rq = rowb + q0 + wv*16 + lhi*4 + reg;
#pragma unroll
    for (int nt = 0; nt < 4; ++nt)
      po[((size_t)c*R + rq)*HD_ + nt*16 + l15] = o[nt][reg];
  }
  if (lhi == 0){
    int rq = rowb + q0 + wv*16 + l15;
    *reinterpret_cast<float2*>(pml + 2*((size_t)c*R + rq)) = make_float2(m_q, l_q);
  }
}

// ------- proj MFMA GEMM with fused split-K merge + scatter into y (bf16) -------
// A-tile staged directly from po/pml: head h = k0>>6 is uniform per k0 chunk.
__global__ __launch_bounds__(256) void k_proj(const float* __restrict__ po,
    const float* __restrict__ pml, const unsigned* __restrict__ idx,
    const float* __restrict__ pw, const float* __restrict__ pb,
    unsigned short* __restrict__ y, int b_off, int nb){
  const int NT = C_/64;   // 3
  int bid = blockIdx.x;
  int bl  = bid / (16*NT);
  int rem = bid % (16*NT);
  int m0  = (rem / NT) * 128;
  int n0  = (rem % NT) * 64;
  int t = threadIdx.x, lane = t & 63;
  int wv = t >> 6, wm = wv & 1, wn = wv >> 1;
  __shared__ unsigned short Al[128][40];
  __shared__ unsigned short Bl[64][40];
  __shared__ int rows[128];
  if (t < 128) rows[t] = load_idx(idx, (b_off+bl)*K_ + m0 + t);
  __syncthreads();
  int R = nb*HEADS_*K_;
  f32x4 acc[4][2] = {};
  int l15 = lane & 15, lhi = lane >> 4;
  for (int k0 = 0; k0 < C_; k0 += 32){
    {
      int hh = k0 >> 6, d0 = k0 & 63;
      int m = t >> 1;
      int rq = (bl*HEADS_ + hh)*K_ + m0 + m;
      float2 s0 = *reinterpret_cast<const float2*>(pml + 2*(size_t)rq);
      float2 s1 = *reinterpret_cast<const float2*>(pml + 2*((size_t)R + rq));
      float M  = fmaxf(s0.x, s1.x);
      float e0 = __expf(s0.x - M), e1 = __expf(s1.x - M);
      float Li = __builtin_amdgcn_rcpf(fmaf(s0.y, e0, s1.y*e1));
      float w0 = e0*Li, w1 = e1*Li;
      const float* p0 = po + (size_t)rq*HD_ + d0;
      const float* p1 = po + ((size_t)R + rq)*HD_ + d0;
#pragma unroll
      for (int i = 0; i < 4; ++i){
        int kq = (t & 1) + 2*i;
        float4 a = *reinterpret_cast<const float4*>(p0 + 4*kq);
        float4 b = *reinterpret_cast<const float4*>(p1 + 4*kq);
        *reinterpret_cast<uint2*>(&Al[m][4*kq]) = make_uint2(
            cvtpk(fmaf(w0, a.x, w1*b.x), fmaf(w0, a.y, w1*b.y)),
            cvtpk(fmaf(w0, a.z, w1*b.z), fmaf(w0, a.w, w1*b.w)));
      }
      int n = t >> 2;
      const float* bsrc = pw + (size_t)(n0+n)*C_ + k0;
#pragma unroll
      for (int i = 0; i < 2; ++i){
        int q = (t & 3) + 4*i;
        float4 v = *reinterpret_cast<const float4*>(bsrc + 4*q);
        *reinterpret_cast<uint2*>(&Bl[n][4*q]) =
            make_uint2(cvtpk(v.x, v.y), cvtpk(v.z, v.w));
      }
    }
    __syncthreads();
    bf16x8 af[4], bfr[2];
#pragma unroll
    for (int mf = 0; mf < 4; ++mf)
      af[mf] = *reinterpret_cast<const bf16x8*>(&Al[wm*64 + mf*16 + l15][lhi*8]);
#pragma unroll
    for (int nf = 0; nf < 2; ++nf)
      bfr[nf] = *reinterpret_cast<const bf16x8*>(&Bl[wn*32 + nf*16 + l15][lhi*8]);
#pragma unroll
    for (int mf = 0; mf < 4; ++mf)
#pragma unroll
      for (int nf = 0; nf < 2; ++nf)
        acc[mf][nf] = __builtin_amdgcn_mfma_f32_16x16x32_bf16(af[mf], bfr[nf], acc[mf][nf], 0,0,0);
    __syncthreads();
  }
#pragma unroll
  for (int mf = 0; mf < 4; ++mf){
    int mb = wm*64 + mf*16 + lhi*4;
#pragma unroll
    for (int nf = 0; nf < 2; ++nf){
      int n = n0 + wn*32 + nf*16 + l15;
      float bv = pb[n];
#pragma unroll
      for (int r = 0; r < 4; ++r)
        y[((size_t)bl*N_ + rows[mb + r])*C_ + n] = f2bf(acc[mf][nf][r] + bv);
    }
  }
}

// ---------------- residual + LN2 -> ln2t (B,C,N) [== d_out] ----------------
__global__ __launch_bounds__(256) void k_ln2(const float* __restrict__ x,
    const unsigned short* __restrict__ y, const float* __restrict__ w,
    const float* __restrict__ bias, float* __restrict__ ln2t, int b_off){
  int blk = blockIdx.x;
  int bl = blk >> 8;
  int b  = b_off + bl;
  int n0 = (blk & 255) * 64;
  int t  = threadIdx.x;
  int tok = t & 63, q = t >> 6;
  __shared__ float tile[64][C_+1];
  __shared__ float red[8][64];
  __shared__ float wls[C_], bls[C_];
  if (t < C_){ wls[t] = w[t]; bls[t] = bias[t]; }
  const unsigned* yb = reinterpret_cast<const unsigned*>(y + ((size_t)bl*N_ + n0)*C_);
#pragma unroll
  for (int i = 0; i < 24; ++i){
    int li = t + 256*i;
    unsigned u = yb[li];
    int tk = li / 96, c2 = li % 96;
    tile[tk][2*c2]   = bf2f((unsigned short)(u & 0xffffu));
    tile[tk][2*c2+1] = bf2f((unsigned short)(u >> 16));
  }
  __syncthreads();
  const float* xb = x + (size_t)b*C_*N_ + n0;
  float sum = 0.f, sq = 0.f;
#pragma unroll
  for (int i = 0; i < 48; ++i){
    int c = q + 4*i;
    float v = xb[(size_t)c*N_ + tok] + tile[tok][c];
    tile[tok][c] = v;
    sum += v; sq += v*v;
  }
  red[q][tok] = sum; red[4+q][tok] = sq;
  __syncthreads();
  if (q == 0){
    float s  = red[0][tok]+red[1][tok]+red[2][tok]+red[3][tok];
    float s2 = red[4][tok]+red[5][tok]+red[6][tok]+red[7][tok];
    float mu = s*(1.f/C_);
    float rstd = rsqrtf(s2*(1.f/C_) - mu*mu + 1e-5f);
    red[0][tok] = mu; red[1][tok] = rstd;
  }
  __syncthreads();
  float* ob = ln2t + (size_t)b*C_*N_ + n0;
  float mu = red[0][tok], rstd = red[1][tok];
#pragma unroll
  for (int i = 0; i < 48; ++i){
    int c = q + 4*i;
    ob[(size_t)c*N_ + tok] = (tile[tok][c]-mu)*rstd*wls[c] + bls[c];
  }
}

// ------- fc1 MFMA: block = 128-token m-tile x 384-hid half, loop 6 n-tiles -------
__global__ __launch_bounds__(256) void k_fc1(const float* __restrict__ ln2t,
    const float* __restrict__ wgt, const float* __restrict__ bias,
    unsigned short* __restrict__ h1, int b_off){
  int bid = blockIdx.x;
  int bl  = bid >> 8;                  // slot-local batch
  int rem = bid & 255;
  int m0  = (rem >> 1) * 128;
  int nh  = (rem & 1) * 6;             // n-tile half
  int t = threadIdx.x, lane = t & 63;
  int wv = t >> 6, wm = wv & 1, wn = wv >> 1;
  int l15 = lane & 15, lhi = lane >> 4;
  __shared__ unsigned short Al[128][200];
  __shared__ unsigned short Bl[64][200];
  const float* a = ln2t + (size_t)(b_off+bl)*C_*N_ + m0;
  unsigned short* hb = h1 + (size_t)bl*HID_*N_;
  {
    int m = t & 127, half = t >> 7;
#pragma unroll
    for (int i = 0; i < 48; ++i){
      int p = half + 2*i;                    // 0..95
      float v0 = a[(size_t)(2*p)*N_ + m];
      float v1 = a[(size_t)(2*p+1)*N_ + m];
      *reinterpret_cast<unsigned*>(&Al[m][2*p]) = cvtpk(v0, v1);
    }
  }
  for (int nt = 0; nt < 6; ++nt){
    int n0 = (nh + nt)*64;
    __syncthreads();
    {
      int n = t >> 2;
      const float* bsrc = wgt + (size_t)(n0+n)*C_;
#pragma unroll
      for (int i = 0; i < 12; ++i){
        int q = (t & 3) + 4*i;               // 0..47 float4 segs
        float4 v = *reinterpret_cast<const float4*>(bsrc + 4*q);
        *reinterpret_cast<uint2*>(&Bl[n][4*q]) =
            make_uint2(cvtpk(v.x, v.y), cvtpk(v.z, v.w));
      }
    }
    __syncthreads();
    f32x4 acc[4][2] = {};
#pragma unroll
    for (int ks = 0; ks < 6; ++ks){
      bf16x8 af[4], bfr[2];
#pragma unroll
      for (int mf = 0; mf < 4; ++mf)
        af[mf] = *reinterpret_cast<const bf16x8*>(&Al[wm*64 + mf*16 + l15][ks*32 + lhi*8]);
#pragma unroll
      for (int nf = 0; nf < 2; ++nf)
        bfr[nf] = *reinterpret_cast<const bf16x8*>(&Bl[wn*32 + nf*16 + l15][ks*32 + lhi*8]);
#pragma unroll
      for (int mf = 0; mf < 4; ++mf)
#pragma unroll
        for (int nf = 0; nf < 2; ++nf)
          acc[mf][nf] = __builtin_amdgcn_mfma_f32_16x16x32_bf16(af[mf], bfr[nf], acc[mf][nf], 0,0,0);
    }
#pragma unroll
    for (int mf = 0; mf < 4; ++mf){
      int mb = m0 + wm*64 + mf*16 + lhi*4;
#pragma unroll
      for (int nf = 0; nf < 2; ++nf){
        int n = n0 + wn*32 + nf*16 + l15;
        float bv = bias[n];
        uint2 pk;
        pk.x = cvtpk(acc[mf][nf][0] + bv, acc[mf][nf][1] + bv);
        pk.y = cvtpk(acc[mf][nf][2] + bv, acc[mf][nf][3] + bv);
        *reinterpret_cast<uint2*>(&hb[(size_t)n*N_ + mb]) = pk;
      }
    }
  }
}

// ------- fused depthwise3x3+GELU+fc2+residual: block = 1 image row x 192 ch -------
// 512 thr, 51.7KB LDS; single Ht buffer, 2 barriers/chunk, reg-prefetched h1
__global__ __launch_bounds__(512) void k_fc2f(const unsigned short* __restrict__ h1,
    const float* __restrict__ dw, const float* __restrict__ wgt,
    const float* __restrict__ bias, float* __restrict__ out, int b_off){
  int nwg = gridDim.x;
  int cpx = nwg >> 3;
  int bid = (blockIdx.x & 7)*cpx + (blockIdx.x >> 3);  // contiguous rows per XCD
  int bl  = bid >> 7;            // slot-local batch
  int r   = bid & 127;           // image row
  int b   = b_off + bl;
  int t = threadIdx.x, lane = t & 63, wv = t >> 6;
  int wm = wv & 1, wn = wv >> 1;
  int l15 = lane & 15, lhi = lane >> 4;
  __shared__ unsigned short Ht[32][3][136];     // 26.1KB; ch-stride 816B (51x16B)
  __shared__ unsigned short Alc[128][40];       // 10.2KB
  __shared__ unsigned short Bl[192][40];        // 15.4KB
  const unsigned short* h1b = h1 + (size_t)bl*HID_*N_;
  f32x4 acc[4][3] = {};
  int cch = t & 31, j0 = (t >> 5) * 8;          // conv: channel, col base
  // ---- hoisted per-thread staging state ----
  const unsigned short* gp[3]; unsigned short* lp[3]; bool gok[3];
#pragma unroll
  for (int i = 0; i < 3; ++i){
    int li = t + 512*i;                         // 0..1535
    int ch = li / 48, rm = li % 48, dy = rm >> 4, seg = rm & 15;
    int rr = r - 1 + dy;
    gok[i] = (rr >= 0 && rr < H_);
    gp[i] = h1b + (size_t)ch*N_ + (gok[i] ? rr : 0)*W_ + seg*8;
    lp[i] = &Ht[ch][dy][seg*8];
  }
  const float* wgp[3]; unsigned short* blp[3];
#pragma unroll
  for (int i = 0; i < 3; ++i){
    int row = (t >> 3) + 64*i, seg = t & 7;
    wgp[i] = wgt + (size_t)row*HID_ + seg*4;
    blp[i] = &Bl[row][seg*4];
  }
  const float* dwp = dw + (size_t)cch*9;        // advance +288 per chunk
  uint4 hr[3];
  auto hload = [&](){
#pragma unroll
    for (int i = 0; i < 3; ++i)
      hr[i] = gok[i] ? *reinterpret_cast<const uint4*>(gp[i]) : make_uint4(0u,0u,0u,0u);
#pragma unroll
    for (int i = 0; i < 3; ++i) gp[i] += 32*N_;
  };
  // prologue: chunk 0 into Ht, prefetch chunk 1 into regs
  hload();
#pragma unroll
  for (int i = 0; i < 3; ++i) *reinterpret_cast<uint4*>(lp[i]) = hr[i];
  hload();
  for (int c24 = 0; c24 < 24; ++c24){
    __syncthreads();                  // A: Ht(c) visible; prev MFMA done
    // stage Bl direct from global (L2-hot weights)
#pragma unroll
    for (int i = 0; i < 3; ++i){
      float4 v = *reinterpret_cast<const float4*>(wgp[i]);
      wgp[i] += 32;
      *reinterpret_cast<uint2*>(blp[i]) =
          make_uint2(cvtpk(v.x, v.y), cvtpk(v.z, v.w));
    }
    // conv 3x3 + fast GELU from Ht -> Alc; dw direct (broadcast-hot)
    {
      float w9[9];
#pragma unroll
      for (int i = 0; i < 9; ++i) w9[i] = dwp[i];
      dwp += 288;
      const unsigned short* hp = &Ht[cch][0][j0];
      float s[8] = {0.f,0.f,0.f,0.f,0.f,0.f,0.f,0.f};
#pragma unroll
      for (int dy = 0; dy < 3; ++dy){
        const unsigned short* rp = hp + dy*136;
        bf16x8 mid = *reinterpret_cast<const bf16x8*>(rp);
        float v[10];
        v[0] = (j0 > 0)   ? bf2f(rp[-1]) : 0.f;
        v[9] = (j0 < 120) ? bf2f(rp[8])  : 0.f;
#pragma unroll
        for (int j = 0; j < 8; ++j) v[1+j] = bf2f((unsigned short)mid[j]);
        float wa = w9[3*dy], wb = w9[3*dy+1], wc = w9[3*dy+2];
#pragma unroll
        for (int j = 0; j < 8; ++j)
          s[j] += v[j]*wa + v[j+1]*wb + v[j+2]*wc;
      }
#pragma unroll
      for (int j = 0; j < 8; ++j)
        Alc[j0+j][cch] = f2bf(gelu_fast(s[j]));
    }
    __syncthreads();                  // B: Alc+Bl visible; Ht reads complete
    // write prefetched chunk c+1 into Ht (dead now); prefetch c+2
    if (c24 < 23){
#pragma unroll
      for (int i = 0; i < 3; ++i)
        *reinterpret_cast<uint4*>(lp[i]) = hr[i];
      if (c24 < 22) hload();
    }
    // MFMA: wave = 64-tok half (wm) x 48-ch quarter (wn)
    bf16x8 af[4], bfr[3];
#pragma unroll
    for (int mf = 0; mf < 4; ++mf)
      af[mf] = *reinterpret_cast<const bf16x8*>(&Alc[wm*64 + mf*16 + l15][lhi*8]);
#pragma unroll
    for (int nf = 0; nf < 3; ++nf)
      bfr[nf] = *reinterpret_cast<const bf16x8*>(&Bl[wn*48 + nf*16 + l15][lhi*8]);
    __builtin_amdgcn_s_setprio(1);
#pragma unroll
    for (int mf = 0; mf < 4; ++mf)
#pragma unroll
      for (int nf = 0; nf < 3; ++nf)
        acc[mf][nf] = __builtin_amdgcn_mfma_f32_16x16x32_bf16(af[mf], bfr[nf], acc[mf][nf], 0,0,0);
    __builtin_amdgcn_s_setprio(0);
  }
  // epilogue: += bias + residual (out holds ln2t)
#pragma unroll
  for (int mf = 0; mf < 4; ++mf){
    int tok = r*W_ + wm*64 + mf*16 + lhi*4;
#pragma unroll
    for (int nf = 0; nf < 3; ++nf){
      int oc = wn*48 + nf*16 + l15;
      float bv = bias[oc];
      size_t off = ((size_t)b*C_ + oc)*N_ + tok;
      float4 rr = *reinterpret_cast<const float4*>(out + off);
      float4 v = make_float4(rr.x + acc[mf][nf][0] + bv, rr.y + acc[mf][nf][1] + bv,
                             rr.z + acc[mf][nf][2] + bv, rr.w + acc[mf][nf][3] + bv);
      *reinterpret_cast<float4*>(out + off) = v;
    }
  }
}

extern "C" void kernel_launch(void* const* d_in, const int* in_sizes, int n_in,
                              void* d_out, int out_size, void* d_ws, size_t ws_size,
                              hipStream_t stream) {
  const float*    x      = (const float*)d_in[0];
  const unsigned* idx    = (const unsigned*)d_in[1];
  const float*    ln1_w  = (const float*)d_in[2];
  const float*    ln1_b  = (const float*)d_in[3];
  const float*    qkv_w  = (const float*)d_in[4];
  const float*    proj_w = (const float*)d_in[5];
  const float*    proj_b = (const float*)d_in[6];
  const float*    ln2_w  = (const float*)d_in[7];
  const float*    ln2_b  = (const float*)d_in[8];
  const float*    fc1_w  = (const float*)d_in[9];
  const float*    fc1_b  = (const float*)d_in[10];
  const float*    dw_w   = (const float*)d_in[11];
  const float*    fc2_w  = (const float*)d_in[12];
  const float*    fc2_b  = (const float*)d_in[13];
  float* out = (float*)d_out;          // doubles as ln2t (B,C,N) f32

  const size_t SZY = (size_t)N_*C_*2;              // y bf16: 6.29 MB/batch
  const size_t SZQ = (size_t)K_*3*C_*2;            // 2.36
  const size_t SZA = (size_t)K_*C_*2;              // 0.79 (unused slot, layout kept)
  const size_t SZO = (size_t)NC_*HEADS_*K_*HD_*4;  // 3.15/batch
  const size_t SZH = (size_t)HID_*N_*2;            // 25.17/batch
  int nb = (ws_size >= (size_t)B_*SZH) ? B_ : 1;   // deterministic

  char* ws = (char*)d_ws;
  unsigned short* y16  = (unsigned short*)ws;
  unsigned short* qkvb = (unsigned short*)(ws + (size_t)nb*SZY);
  float*          po   = (float*)(ws + (size_t)nb*(SZY+SZQ+SZA));
  float*          pml  = (float*)(ws + (size_t)nb*(SZY+SZQ+SZA+SZO));
  unsigned short* h1s  = (unsigned short*)ws;      // MLP phase (front dead): nb slots

  for (int b0 = 0; b0 < B_; b0 += nb){
    k_ln1   <<<nb*256,             256, 0, stream>>>(x, ln1_w, ln1_b, y16, b0);
    k_qkv   <<<nb*16*9,            256, 0, stream>>>(y16, idx, qkv_w, qkvb, b0);
    k_attn  <<<nb*HEADS_*32*NC_,   256, 0, stream>>>(qkvb, po, pml, nb);
    k_proj  <<<nb*16*3,            256, 0, stream>>>(po, pml, idx, proj_w, proj_b, y16, b0, nb);
    k_ln2   <<<nb*256,             256, 0, stream>>>(x, y16, ln2_w, ln2_b, out, b0);
    k_fc1   <<<nb*256,             256, 0, stream>>>(out, fc1_w, fc1_b, h1s, b0);
    k_fc2f  <<<nb*128,             512, 0, stream>>>(h1s, dw_w, fc2_w, fc2_b, out, b0);
  }
}